// Round 5
// baseline (232.214 us; speedup 1.0000x reference)
//
#include <hip/hip_runtime.h>
#include <cstdint>

#define Bb 4
#define Lseq 4096
#define Hh 1024
#define Nst 64
constexpr float LN_EPS = 1e-5f;

typedef _Float16 f16x8 __attribute__((ext_vector_type(8)));
typedef _Float16 f16x4 __attribute__((ext_vector_type(4)));
typedef float f32x4v __attribute__((ext_vector_type(4)));

typedef const __attribute__((address_space(1))) void* gas_vp;
typedef __attribute__((address_space(3))) void* las_vp;

// XOR-swizzle within a 64x64 f16 matrix: elem e=(row*64+col) stored at
// e ^ ((row&7)<<3)  (byte ^= ((row&7)<<4)). Written pre-swizzled by k_pre so
// identity global->LDS staging (global_load_lds) lands the swizzled layout;
// fragment reads in k_chunk apply the same XOR -> conflict-free ds_read_b128.
__device__ __forceinline__ int swz(int e) { return e ^ (((e >> 6) & 7) << 3); }

// ---------------------------------------------------------------------------
// K0+K1 fused: precompute (blocks 0..1023) overlaps transpose (blocks 1024+).
// Precompute is transcendental/VALU-bound, transpose is HBM-bound.
// sK now computed in parallel over all 256 threads (tau x 16-n group +
// 2-step shfl_xor reduce) instead of a 64-iter serial loop on 64 lanes.
// ---------------------------------------------------------------------------
__global__ __launch_bounds__(256) void k_pre_trans(
    const float* __restrict__ x, float* __restrict__ xt,
    const float* __restrict__ logA, const float* __restrict__ Aim,
    const float* __restrict__ Cre, const float* __restrict__ Cim,
    const float* __restrict__ logdt, _Float16* __restrict__ mats,
    float* __restrict__ wwR, float* __restrict__ wwI) {
    __shared__ float tile[64 * 65];               // transpose path (16.6KB)
    __shared__ float sdAr[64], sdAi[64], scR[64], scI[64], sK[64];
    const int tid = threadIdx.x;

    if (blockIdx.x < Hh) {
        // ---------------- precompute path ----------------
        const int h = blockIdx.x;
        _Float16* g = mats + (size_t)h * 20480;

        if (tid < 64) {
            const int n = tid, idx = h * 64 + n;
            const float ar = -__expf(logA[idx]), ai = Aim[idx];
            const float dt = __expf(logdt[h]);
            const float dAr = dt * ar, dAi = dt * ai;
            const float em = __expf(dAr);
            const float wr = em * __cosf(dAi), wi = em * __sinf(dAi);
            const float Er = wr - 1.0f, Ei = wi;
            const float cr = Cre[idx], ci = Cim[idx];
            const float nr = cr * Er - ci * Ei, ni = cr * Ei + ci * Er;
            const float invd = 1.0f / (ar * ar + ai * ai);
            const float CtR = (nr * ar + ni * ai) * invd;
            const float CtI = (ni * ar - nr * ai) * invd;
            sdAr[n] = dAr; sdAi[n] = dAi;
            scR[n] = 2.0f * CtR; scI[n] = 2.0f * CtI;
            const float e64 = __expf(dAr * 64.0f), a64 = dAi * 64.0f;
            wwR[idx] = e64 * __cosf(a64);
            wwI[idx] = e64 * __sinf(a64);
        }
        __syncthreads();

        // K[tau] partials: tau = tid>>2, each of 4 lanes sums 16 n's,
        // then shfl_xor(1,2) reduce within the aligned 4-lane group.
        {
            const int tau = tid >> 2, ns0 = (tid & 3) * 16;
            const float ftau = (float)tau;
            float sum = 0.0f;
#pragma unroll
            for (int j = 0; j < 16; ++j) {
                const int n = ns0 + j;
                const float ee = __expf(sdAr[n] * ftau), ang = sdAi[n] * ftau;
                sum += ee * (scR[n] * __cosf(ang) - scI[n] * __sinf(ang));
            }
            sum += __shfl_xor(sum, 1);
            sum += __shfl_xor(sum, 2);
            if ((tid & 3) == 0) sK[tau] = sum;
        }

        for (int e = tid; e < 4096; e += 256) {
            const int row = e >> 6, colj = e & 63;
            const int es = swz(e);
            {
                const float p = (float)(63 - colj);
                const float ee = __expf(sdAr[row] * p), ang = sdAi[row] * p;
                g[es]        = (_Float16)(ee * __cosf(ang));
                g[4096 + es] = (_Float16)(ee * __sinf(ang));
            }
            {
                const int n = colj;
                const float q = (float)(row + 1);
                const float ee = __expf(sdAr[n] * q), ang = sdAi[n] * q;
                const float wRq = ee * __cosf(ang), wIq = ee * __sinf(ang);
                g[12288 + es] = (_Float16)(scR[n] * wRq - scI[n] * wIq);
                g[16384 + es] = (_Float16)(-(scR[n] * wIq + scI[n] * wRq));
            }
        }
        __syncthreads();
        for (int e = tid; e < 4096; e += 256) {
            const int t = e >> 6, j = e & 63;
            g[8192 + swz(e)] = (j <= t) ? (_Float16)sK[t - j] : (_Float16)0.0f;
        }
    } else {
        // ---------------- transpose path (f32 -> f32) ----------------
        const int tb = blockIdx.x - Hh;
        const int h0 = (tb & 15) * 64;
        const int l0 = ((tb >> 4) & 63) * 64;
        const int b  = tb >> 10;
        const int c = tid & 15, r = tid >> 4;

        const float* src = x + ((size_t)(b * Lseq + l0 + r)) * Hh + h0 + 4 * c;
#pragma unroll
        for (int it = 0; it < 4; ++it) {
            const float4 v = *(const float4*)(src + (size_t)it * 16 * Hh);
            const int l = it * 16 + r;
            tile[(4 * c + 0) * 65 + l] = v.x;
            tile[(4 * c + 1) * 65 + l] = v.y;
            tile[(4 * c + 2) * 65 + l] = v.z;
            tile[(4 * c + 3) * 65 + l] = v.w;
        }
        __syncthreads();
        float* dst = xt + ((size_t)(b * Hh + h0 + r)) * Lseq + l0 + 4 * c;
#pragma unroll
        for (int it = 0; it < 4; ++it) {
            const float* trow = tile + (it * 16 + r) * 65 + 4 * c;
            float4 o;
            o.x = trow[0]; o.y = trow[1]; o.z = trow[2]; o.w = trow[3];
            *(float4*)(dst + (size_t)it * 16 * Lseq) = o;
        }
    }
}

// ---------------------------------------------------------------------------
// K2: chunked block-scan via MFMA. 512 threads / 2 batches per block,
// grid (2, Hh), 2 blocks/CU. f32 ws (R2 memory behavior: dword loads/stores,
// no sub-dword ECC-RMW stores). Kept from R4: Kogge-Stone shuffle scan.
// ---------------------------------------------------------------------------
#define MR0 0        // U_re   f16 [64][64] stride 128B, XOR-swizzled
#define MI0 8192     // U_im
#define MM1 16384    // M1
#define MPR 24576    // P_re
#define MPI 32768    // P_im_neg
#define USB 40960    // 2 x { uR/S_R [64][68], uI/S_I [64][68] } stride 136B
#define WPT 75776    // lwpR [6][64], lwpI [6][64]  (ends at 78848)

// row0 is a multiple of 16 at every use, so (row0+col)&7 == col&7
#define MFRAG(base, row0, kk) \
    (*(const f16x8*)(sm + (((base) + ((row0) + col) * 128 + ((kk) + qd * 8) * 2) ^ ((col & 7) << 4))))

static __device__ __forceinline__ f16x8 ufrag(const unsigned char* sm, int off) {
    union { f16x8 v; f16x4 h[2]; } u;
    u.h[0] = *(const f16x4*)(sm + off);      // 8B aligned
    u.h[1] = *(const f16x4*)(sm + off + 8);
    return u.v;
}

__global__ __launch_bounds__(512, 4) void k_chunk(
    float* __restrict__ xt, const _Float16* __restrict__ mats,
    const float* __restrict__ wwR, const float* __restrict__ wwI,
    const float* __restrict__ Dp) {
    __shared__ __align__(16) unsigned char sm[78848];
    float* lwpR = (float*)(sm + WPT);           // [6][64]
    float* lwpI = (float*)(sm + WPT + 1536);    // [6][64]

    const int tid = threadIdx.x, lane = tid & 63, wv = tid >> 6;
    const int grp = wv >> 2;          // 0..1: which batch of this block's pair
    const int wb  = wv & 3;           // row-band wave 0..3
    const int h = blockIdx.y;
    const int b = blockIdx.x * 2 + grp;   // batch 0..3
    const _Float16* g = mats + (size_t)h * 20480;
    const int col = lane & 15, qd = lane >> 4;
    const int band = wb * 16;
    const int uRo = USB + grp * 17408;
    const int uIo = uRo + 8704;

    // ---- async stage: 40KB mats, identity global->LDS (pre-swizzled) ----
#pragma unroll
    for (int it = 0; it < 5; ++it) {
        const int blk = it * 8 + wv;          // 1KB block, 0..39
        __builtin_amdgcn_global_load_lds(
            (gas_vp)((const uint4*)g + blk * 64 + lane),
            (las_vp)(sm + blk * 1024), 16, 0, 0);
    }

    const float Dp1 = 1.0f + Dp[h];
    float* xr = xt + ((size_t)b * Hh + h) * Lseq;

    // ---- phase-1 x loads issued NOW: latency overlaps the mats stage ----
    float4 xv0[2], xv1[2];
#pragma unroll
    for (int kh2 = 0; kh2 < 2; ++kh2) {
        const float* xp = xr + (band + col) * 64 + kh2 * 32 + qd * 8;
        xv0[kh2] = *(const float4*)(xp);
        xv1[kh2] = *(const float4*)(xp + 4);
    }

    // ---- w64^(2^k) tables by repeated complex squaring (lanes 0..63) ----
    if (tid < 64) {
        float wR = wwR[h * 64 + tid], wI = wwI[h * 64 + tid];
#pragma unroll
        for (int k = 0; k < 6; ++k) {
            lwpR[k * 64 + tid] = wR;
            lwpI[k * 64 + tid] = wI;
            const float nwR = fmaf(wR, wR, -wI * wI);
            wI = 2.0f * wR * wI;
            wR = nwR;
        }
    }

    f16x8 axk[2];
#pragma unroll
    for (int kh2 = 0; kh2 < 2; ++kh2) {
        f16x8 a;
        a[0] = (_Float16)xv0[kh2].x; a[1] = (_Float16)xv0[kh2].y;
        a[2] = (_Float16)xv0[kh2].z; a[3] = (_Float16)xv0[kh2].w;
        a[4] = (_Float16)xv1[kh2].x; a[5] = (_Float16)xv1[kh2].y;
        a[6] = (_Float16)xv1[kh2].z; a[7] = (_Float16)xv1[kh2].w;
        axk[kh2] = a;
    }
    __syncthreads();  // mats staged (vmcnt drain) + tables visible

    // ---- phase 1: u = X @ U^T (complex) ----
    f32x4v aR[4] = {}, aI[4] = {};
    __builtin_amdgcn_s_setprio(1);
#pragma unroll
    for (int kh2 = 0; kh2 < 2; ++kh2) {
        const int kk = kh2 * 32;
#pragma unroll
        for (int nt = 0; nt < 4; ++nt) {
            aR[nt] = __builtin_amdgcn_mfma_f32_16x16x32_f16(
                axk[kh2], MFRAG(MR0, nt * 16, kk), aR[nt], 0, 0, 0);
            aI[nt] = __builtin_amdgcn_mfma_f32_16x16x32_f16(
                axk[kh2], MFRAG(MI0, nt * 16, kk), aI[nt], 0, 0, 0);
        }
    }
    __builtin_amdgcn_s_setprio(0);
#pragma unroll
    for (int nt = 0; nt < 4; ++nt)
#pragma unroll
        for (int rg = 0; rg < 4; ++rg) {
            const int cc = band + qd * 4 + rg, n = nt * 16 + col;
            *(_Float16*)(sm + uRo + cc * 136 + n * 2) = (_Float16)aR[nt][rg];
            *(_Float16*)(sm + uIo + cc * 136 + n * 2) = (_Float16)aI[nt][rg];
        }
    __syncthreads();  // u visible

    // ---- phase 2: Kogge-Stone shuffle scan over chunks. lane = chunk c;
    //      each wave owns 16 n. Inclusive I[c] = u[c] + w*I[c-1] via 6
    //      shfl_up steps; exclusive S[c] = I[c-1] via one more shfl_up. ----
    {
        const int c = lane;
#pragma unroll 8
        for (int nn = 0; nn < 16; ++nn) {
            const int n = band + nn;
            float sR = (float)*(const _Float16*)(sm + uRo + c * 136 + n * 2);
            float sI = (float)*(const _Float16*)(sm + uIo + c * 136 + n * 2);
#pragma unroll
            for (int k = 0; k < 6; ++k) {
                const float wr = lwpR[k * 64 + n], wi = lwpI[k * 64 + n];
                const float tR = __shfl_up(sR, 1 << k);
                const float tI = __shfl_up(sI, 1 << k);
                if (c >= (1 << k)) {
                    sR = fmaf(wr, tR, fmaf(-wi, tI, sR));
                    sI = fmaf(wr, tI, fmaf(wi, tR, sI));
                }
            }
            float eR = __shfl_up(sR, 1), eI = __shfl_up(sI, 1);
            if (c == 0) { eR = 0.0f; eI = 0.0f; }
            *(_Float16*)(sm + uRo + c * 136 + n * 2) = (_Float16)eR;
            *(_Float16*)(sm + uIo + c * 136 + n * 2) = (_Float16)eI;
        }
    }
    __syncthreads();  // S visible

    // ---- hoist epilogue x reads: latency hides under phase-3 MFMAs ----
    float xold[4][4];
#pragma unroll
    for (int tt = 0; tt < 4; ++tt)
#pragma unroll
        for (int rg = 0; rg < 4; ++rg)
            xold[tt][rg] = xr[(band + qd * 4 + rg) * 64 + tt * 16 + col];

    // ---- phase 3: y = X@M1^T + SR@PR^T + SI@PIneg^T ----
    f32x4v acc[4] = {};
    __builtin_amdgcn_s_setprio(1);
#pragma unroll
    for (int kh2 = 0; kh2 < 2; ++kh2) {
        const int kk = kh2 * 32;
#pragma unroll
        for (int tt = 0; tt < 4; ++tt)
            acc[tt] = __builtin_amdgcn_mfma_f32_16x16x32_f16(
                axk[kh2], MFRAG(MM1, tt * 16, kk), acc[tt], 0, 0, 0);
    }
#pragma unroll
    for (int kh2 = 0; kh2 < 2; ++kh2) {
        const int kk = kh2 * 32;
        const f16x8 as = ufrag(sm, uRo + (band + col) * 136 + (kk + qd * 8) * 2);
#pragma unroll
        for (int tt = 0; tt < 4; ++tt)
            acc[tt] = __builtin_amdgcn_mfma_f32_16x16x32_f16(
                as, MFRAG(MPR, tt * 16, kk), acc[tt], 0, 0, 0);
    }
#pragma unroll
    for (int kh2 = 0; kh2 < 2; ++kh2) {
        const int kk = kh2 * 32;
        const f16x8 az = ufrag(sm, uIo + (band + col) * 136 + (kk + qd * 8) * 2);
#pragma unroll
        for (int tt = 0; tt < 4; ++tt)
            acc[tt] = __builtin_amdgcn_mfma_f32_16x16x32_f16(
                az, MFRAG(MPI, tt * 16, kk), acc[tt], 0, 0, 0);
    }
    __builtin_amdgcn_s_setprio(0);

    // ---- epilogue: r = x*(1+D) + y, write-only (f32 dword stores) ----
#pragma unroll
    for (int tt = 0; tt < 4; ++tt)
#pragma unroll
        for (int rg = 0; rg < 4; ++rg) {
            const int l = (band + qd * 4 + rg) * 64 + tt * 16 + col;
            xr[l] = fmaf(xold[tt][rg], Dp1, acc[tt][rg]);
        }
}

// ---------------------------------------------------------------------------
// K3: single-pass LayerNorm + transpose back: rt [B,H,L] -> out [B,L,H].
// float4 reads along L, float4 writes along H, shuffle-butterfly partials.
// ---------------------------------------------------------------------------
__global__ __launch_bounds__(512, 2) void k_ln(const float* __restrict__ rt,
                                               float* __restrict__ out,
                                               const float* __restrict__ lnw,
                                               const float* __restrict__ lnb) {
    __shared__ float tile[16 * 1028];
    __shared__ float ps[8 * 16], pq[8 * 16];
    __shared__ float mm[16], rs[16];
    const int b  = blockIdx.y;
    const int l0 = blockIdx.x * 16;
    const int tid = threadIdx.x;
    const int lq = tid & 3;        // l-quad: handles l = lq*4 .. lq*4+3
    const int hr = tid >> 2;       // 0..127 base row
    const int lane = tid & 63, wvv = tid >> 6;

    const float* base = rt + (size_t)b * Hh * Lseq + l0 + lq * 4;

    float s0 = 0, s1 = 0, s2 = 0, s3 = 0, q0 = 0, q1 = 0, q2 = 0, q3 = 0;
#pragma unroll
    for (int p = 0; p < 8; ++p) {
        const int row = hr + p * 128;
        const float4 v = *(const float4*)(base + (size_t)row * Lseq);
        float* tw = tile + lq * 4 * 1028 + row;
        tw[0] = v.x; tw[1028] = v.y; tw[2056] = v.z; tw[3084] = v.w;
        s0 += v.x; q0 = fmaf(v.x, v.x, q0);
        s1 += v.y; q1 = fmaf(v.y, v.y, q1);
        s2 += v.z; q2 = fmaf(v.z, v.z, q2);
        s3 += v.w; q3 = fmaf(v.w, v.w, q3);
    }
#pragma unroll
    for (int d = 4; d <= 32; d <<= 1) {
        s0 += __shfl_xor(s0, d); q0 += __shfl_xor(q0, d);
        s1 += __shfl_xor(s1, d); q1 += __shfl_xor(q1, d);
        s2 += __shfl_xor(s2, d); q2 += __shfl_xor(q2, d);
        s3 += __shfl_xor(s3, d); q3 += __shfl_xor(q3, d);
    }
    if ((lane >> 2) == 0) {   // lanes 0..3, one per lq
        float* pp = ps + wvv * 16 + lq * 4;
        float* qq = pq + wvv * 16 + lq * 4;
        pp[0] = s0; pp[1] = s1; pp[2] = s2; pp[3] = s3;
        qq[0] = q0; qq[1] = q1; qq[2] = q2; qq[3] = q3;
    }
    __syncthreads();
    if (tid < 16) {
        float s = 0.f, q = 0.f;
#pragma unroll
        for (int w = 0; w < 8; ++w) { s += ps[w * 16 + tid]; q += pq[w * 16 + tid]; }
        const float mu  = s * (1.0f / Hh);
        const float var = fmaf(-mu, mu, q * (1.0f / Hh));
        mm[tid] = mu;
        rs[tid] = rsqrtf(var + LN_EPS);
    }
    __syncthreads();

    const int hq = tid & 255, lsel = tid >> 8;
    const float4 wv4 = *(const float4*)(lnw + hq * 4);
    const float4 bv4 = *(const float4*)(lnb + hq * 4);
    float* obase = out + ((size_t)b * Lseq + l0) * Hh + hq * 4;
#pragma unroll
    for (int pl = 0; pl < 8; ++pl) {
        const int l = pl * 2 + lsel;
        const float mu = mm[l], rsg = rs[l];
        const float4 v = *(const float4*)(tile + l * 1028 + hq * 4);
        float4 o;
        o.x = fmaf((v.x - mu) * rsg, wv4.x, bv4.x);
        o.y = fmaf((v.y - mu) * rsg, wv4.y, bv4.y);
        o.z = fmaf((v.z - mu) * rsg, wv4.z, bv4.z);
        o.w = fmaf((v.w - mu) * rsg, wv4.w, bv4.w);
        *(float4*)(obase + (size_t)l * Hh) = o;
    }
}

// ---------------------------------------------------------------------------
extern "C" void kernel_launch(void* const* d_in, const int* in_sizes, int n_in,
                              void* d_out, int out_size, void* d_ws, size_t ws_size,
                              hipStream_t stream) {
    const float* x     = (const float*)d_in[0];
    const float* logA  = (const float*)d_in[1];
    const float* Aim   = (const float*)d_in[2];
    const float* Cre   = (const float*)d_in[3];
    const float* Cim   = (const float*)d_in[4];
    const float* logdt = (const float*)d_in[5];
    const float* Dp    = (const float*)d_in[6];
    const float* lnw   = (const float*)d_in[7];
    const float* lnb   = (const float*)d_in[8];
    float* out = (float*)d_out;
    float* ws  = (float*)d_ws;  // 64 MiB: xt/r f32 [B,H,L]

    _Float16* mats = (_Float16*)d_out;                          // 40 MiB
    float* wwR = (float*)((char*)d_out + 41943040);             // 256 KiB
    float* wwI = (float*)((char*)d_out + 42205184);             // 256 KiB

    // precompute blocks (0..1023) overlap transpose blocks (1024..5119)
    k_pre_trans<<<dim3(Hh + (Hh / 64) * (Lseq / 64) * Bb), 256, 0, stream>>>(
        x, ws, logA, Aim, Cre, Cim, logdt, mats, wwR, wwI);
    k_chunk<<<dim3(2, Hh), 512, 0, stream>>>(ws, mats, wwR, wwI, Dp);
    k_ln<<<dim3(Lseq / 16, Bb), 512, 0, stream>>>(ws, out, lnw, lnb);
}

// Round 7
// 204.807 us; speedup vs baseline: 1.1338x; 1.1338x over previous
//
#include <hip/hip_runtime.h>
#include <cstdint>

#define Bb 4
#define Lseq 4096
#define Hh 1024
#define Nst 64
constexpr float LN_EPS = 1e-5f;

typedef _Float16 f16x8 __attribute__((ext_vector_type(8)));
typedef _Float16 f16x4 __attribute__((ext_vector_type(4)));
typedef float f32x4v __attribute__((ext_vector_type(4)));

typedef const __attribute__((address_space(1))) void* gas_vp;
typedef __attribute__((address_space(3))) void* las_vp;

// XOR-swizzle within a 64x64 f16 matrix: elem e=(row*64+col) stored at
// e ^ ((row&7)<<3). Written pre-swizzled by k_pre so identity global->LDS
// staging lands the swizzled layout; fragment reads apply the same XOR.
__device__ __forceinline__ int swz(int e) { return e ^ (((e >> 6) & 7) << 3); }

// ---------------------------------------------------------------------------
// K0+K1 fused: precompute (blocks 0..1023) overlaps transpose (blocks 1024+).
// Transpose writes xt as f16 via f16x4 (8B stores; no sub-dword traffic).
// ---------------------------------------------------------------------------
__global__ __launch_bounds__(256) void k_pre_trans(
    const float* __restrict__ x, _Float16* __restrict__ xt,
    const float* __restrict__ logA, const float* __restrict__ Aim,
    const float* __restrict__ Cre, const float* __restrict__ Cim,
    const float* __restrict__ logdt, _Float16* __restrict__ mats,
    float* __restrict__ wwR, float* __restrict__ wwI) {
    __shared__ float tile[64 * 65];               // transpose path (16.6KB)
    __shared__ float sdAr[64], sdAi[64], scR[64], scI[64], sK[64];
    const int tid = threadIdx.x;

    if (blockIdx.x < Hh) {
        // ---------------- precompute path ----------------
        const int h = blockIdx.x;
        _Float16* g = mats + (size_t)h * 20480;

        if (tid < 64) {
            const int n = tid, idx = h * 64 + n;
            const float ar = -__expf(logA[idx]), ai = Aim[idx];
            const float dt = __expf(logdt[h]);
            const float dAr = dt * ar, dAi = dt * ai;
            const float em = __expf(dAr);
            const float wr = em * __cosf(dAi), wi = em * __sinf(dAi);
            const float Er = wr - 1.0f, Ei = wi;
            const float cr = Cre[idx], ci = Cim[idx];
            const float nr = cr * Er - ci * Ei, ni = cr * Ei + ci * Er;
            const float invd = 1.0f / (ar * ar + ai * ai);
            const float CtR = (nr * ar + ni * ai) * invd;
            const float CtI = (ni * ar - nr * ai) * invd;
            sdAr[n] = dAr; sdAi[n] = dAi;
            scR[n] = 2.0f * CtR; scI[n] = 2.0f * CtI;
            const float e64 = __expf(dAr * 64.0f), a64 = dAi * 64.0f;
            wwR[idx] = e64 * __cosf(a64);
            wwI[idx] = e64 * __sinf(a64);
        }
        __syncthreads();

        // K[tau] partials: tau = tid>>2, each of 4 lanes sums 16 n's,
        // then shfl_xor(1,2) reduce within the aligned 4-lane group.
        {
            const int tau = tid >> 2, ns0 = (tid & 3) * 16;
            const float ftau = (float)tau;
            float sum = 0.0f;
#pragma unroll
            for (int j = 0; j < 16; ++j) {
                const int n = ns0 + j;
                const float ee = __expf(sdAr[n] * ftau), ang = sdAi[n] * ftau;
                sum += ee * (scR[n] * __cosf(ang) - scI[n] * __sinf(ang));
            }
            sum += __shfl_xor(sum, 1);
            sum += __shfl_xor(sum, 2);
            if ((tid & 3) == 0) sK[tau] = sum;
        }

        for (int e = tid; e < 4096; e += 256) {
            const int row = e >> 6, colj = e & 63;
            const int es = swz(e);
            {
                const float p = (float)(63 - colj);
                const float ee = __expf(sdAr[row] * p), ang = sdAi[row] * p;
                g[es]        = (_Float16)(ee * __cosf(ang));
                g[4096 + es] = (_Float16)(ee * __sinf(ang));
            }
            {
                const int n = colj;
                const float q = (float)(row + 1);
                const float ee = __expf(sdAr[n] * q), ang = sdAi[n] * q;
                const float wRq = ee * __cosf(ang), wIq = ee * __sinf(ang);
                g[12288 + es] = (_Float16)(scR[n] * wRq - scI[n] * wIq);
                g[16384 + es] = (_Float16)(-(scR[n] * wIq + scI[n] * wRq));
            }
        }
        __syncthreads();
        for (int e = tid; e < 4096; e += 256) {
            const int t = e >> 6, j = e & 63;
            g[8192 + swz(e)] = (j <= t) ? (_Float16)sK[t - j] : (_Float16)0.0f;
        }
    } else {
        // ---------------- transpose path (f32 in, f16 out) ----------------
        const int tb = blockIdx.x - Hh;
        const int h0 = (tb & 15) * 64;
        const int l0 = ((tb >> 4) & 63) * 64;
        const int b  = tb >> 10;
        const int c = tid & 15, r = tid >> 4;

        const float* src = x + ((size_t)(b * Lseq + l0 + r)) * Hh + h0 + 4 * c;
#pragma unroll
        for (int it = 0; it < 4; ++it) {
            const float4 v = *(const float4*)(src + (size_t)it * 16 * Hh);
            const int l = it * 16 + r;
            tile[(4 * c + 0) * 65 + l] = v.x;
            tile[(4 * c + 1) * 65 + l] = v.y;
            tile[(4 * c + 2) * 65 + l] = v.z;
            tile[(4 * c + 3) * 65 + l] = v.w;
        }
        __syncthreads();
        _Float16* dst = xt + ((size_t)(b * Hh + h0 + r)) * Lseq + l0 + 4 * c;
#pragma unroll
        for (int it = 0; it < 4; ++it) {
            const float* trow = tile + (it * 16 + r) * 65 + 4 * c;
            f16x4 o;
            o[0] = (_Float16)trow[0]; o[1] = (_Float16)trow[1];
            o[2] = (_Float16)trow[2]; o[3] = (_Float16)trow[3];
            *(f16x4*)(dst + (size_t)it * 16 * Lseq) = o;
        }
    }
}

// ---------------------------------------------------------------------------
// K2: chunked block-scan via MFMA. 512 threads / 2 batches per block,
// grid (2, Hh), 2 blocks/CU. R2-proven structure (async mats stage, serial
// scan, setprio) with:
//  - xt f16 input (f16x8 phase-1 loads, 16B) and r f16 output written via
//    LDS bounce -> two coalesced f16x8 (16B) stores/lane. NO sub-dword
//    global accesses (the R4 regression class).
//  - X@M1 MFMA cluster hoisted before the u-barrier: matrix pipe overlaps
//    the barrier wait + serial scan (identical accumulation order to R2).
//  - epilogue x term = two f16x8 loads (L1-hit; replaces 16 scalar dwords).
// ---------------------------------------------------------------------------
#define MR0 0        // U_re   f16 [64][64] stride 128B, XOR-swizzled
#define MI0 8192     // U_im
#define MM1 16384    // M1
#define MPR 24576    // P_re
#define MPI 32768    // P_im_neg
#define USB 40960    // 2 x { S_R [64][68], S_I [64][68] } stride 136B

// row0 is a multiple of 16 at every use, so (row0+col)&7 == col&7
#define MFRAG(base, row0, kk) \
    (*(const f16x8*)(sm + (((base) + ((row0) + col) * 128 + ((kk) + qd * 8) * 2) ^ ((col & 7) << 4))))

static __device__ __forceinline__ f16x8 ufrag(const unsigned char* sm, int off) {
    union { f16x8 v; f16x4 h[2]; } u;
    u.h[0] = *(const f16x4*)(sm + off);      // 8B aligned
    u.h[1] = *(const f16x4*)(sm + off + 8);
    return u.v;
}

__global__ __launch_bounds__(512, 4) void k_chunk(
    const _Float16* __restrict__ xt, _Float16* __restrict__ rt,
    const _Float16* __restrict__ mats,
    const float* __restrict__ wwR, const float* __restrict__ wwI,
    const float* __restrict__ Dp) {
    __shared__ __align__(16) unsigned char sm[75776];

    const int tid = threadIdx.x, lane = tid & 63, wv = tid >> 6;
    const int grp = wv >> 2;          // 0..1: which batch of this block's pair
    const int wb  = wv & 3;           // row-band wave 0..3
    const int h = blockIdx.y;
    const int b = blockIdx.x * 2 + grp;   // batch 0..3
    const _Float16* g = mats + (size_t)h * 20480;
    const int col = lane & 15, qd = lane >> 4;
    const int band = wb * 16;
    const int uRo = USB + grp * 17408;
    const int uIo = uRo + 8704;

    // ---- async stage: 40KB mats, identity global->LDS (pre-swizzled) ----
#pragma unroll
    for (int it = 0; it < 5; ++it) {
        const int blk = it * 8 + wv;          // 1KB block, 0..39
        __builtin_amdgcn_global_load_lds(
            (gas_vp)((const uint4*)g + blk * 64 + lane),
            (las_vp)(sm + blk * 1024), 16, 0, 0);
    }

    const float Dp1 = 1.0f + Dp[h];
    const _Float16* xr = xt + ((size_t)b * Hh + h) * Lseq;
    _Float16* rr = rt + ((size_t)b * Hh + h) * Lseq;

    // ---- phase-1 fragment loads + epilogue x loads (latency under stage) --
    f16x8 axk[2];
#pragma unroll
    for (int kh2 = 0; kh2 < 2; ++kh2)
        axk[kh2] = *(const f16x8*)(xr + (band + col) * 64 + kh2 * 32 + qd * 8);
    // epilogue lane mapping: half h2 -> row = h2*8 + (lane>>3), tau0 = (lane&7)*8
    f16x8 xep[2];
#pragma unroll
    for (int h2 = 0; h2 < 2; ++h2)
        xep[h2] = *(const f16x8*)(xr + (band + h2 * 8 + (lane >> 3)) * 64 +
                                  (lane & 7) * 8);

    float swR = 0.0f, swI = 0.0f;
    if (lane < 16) {
        swR = wwR[h * 64 + band + lane];
        swI = wwI[h * 64 + band + lane];
    }
    __syncthreads();  // mats staged (vmcnt drain also covers x loads)

    // ---- phase 1: u = X @ U^T (complex) ----
    f32x4v aR[4] = {}, aI[4] = {};
    f32x4v acc[4] = {};
    __builtin_amdgcn_s_setprio(1);
#pragma unroll
    for (int kh2 = 0; kh2 < 2; ++kh2) {
        const int kk = kh2 * 32;
#pragma unroll
        for (int nt = 0; nt < 4; ++nt) {
            aR[nt] = __builtin_amdgcn_mfma_f32_16x16x32_f16(
                axk[kh2], MFRAG(MR0, nt * 16, kk), aR[nt], 0, 0, 0);
            aI[nt] = __builtin_amdgcn_mfma_f32_16x16x32_f16(
                axk[kh2], MFRAG(MI0, nt * 16, kk), aI[nt], 0, 0, 0);
        }
    }
    // X@M1 hoisted: independent of the scan, overlaps barrier + scan below
#pragma unroll
    for (int kh2 = 0; kh2 < 2; ++kh2) {
        const int kk = kh2 * 32;
#pragma unroll
        for (int tt = 0; tt < 4; ++tt)
            acc[tt] = __builtin_amdgcn_mfma_f32_16x16x32_f16(
                axk[kh2], MFRAG(MM1, tt * 16, kk), acc[tt], 0, 0, 0);
    }
    __builtin_amdgcn_s_setprio(0);
#pragma unroll
    for (int nt = 0; nt < 4; ++nt)
#pragma unroll
        for (int rg = 0; rg < 4; ++rg) {
            const int cc = band + qd * 4 + rg, n = nt * 16 + col;
            *(_Float16*)(sm + uRo + cc * 136 + n * 2) = (_Float16)aR[nt][rg];
            *(_Float16*)(sm + uIo + cc * 136 + n * 2) = (_Float16)aI[nt][rg];
        }
    __syncthreads();  // u visible

    // ---- phase 2: chunk-level scan, in-place u->S; wave owns 16 n ----
    if (lane < 16) {
        const int n = band + lane;
        float sR = 0.0f, sI = 0.0f;
        for (int c = 0; c < 64; ++c) {
            _Float16* pR = (_Float16*)(sm + uRo + c * 136 + n * 2);
            _Float16* pI = (_Float16*)(sm + uIo + c * 136 + n * 2);
            const float uRv = (float)*pR;
            const float uIv = (float)*pI;
            *pR = (_Float16)sR;
            *pI = (_Float16)sI;
            const float nR = fmaf(swR, sR, fmaf(-swI, sI, uRv));
            sI = fmaf(swR, sI, fmaf(swI, sR, uIv));
            sR = nR;
        }
    }
    __syncthreads();  // S visible

    // ---- phase 3: acc += SR@PR^T + SI@PIneg^T (M1 part already done) ----
    __builtin_amdgcn_s_setprio(1);
#pragma unroll
    for (int kh2 = 0; kh2 < 2; ++kh2) {
        const int kk = kh2 * 32;
        const f16x8 as = ufrag(sm, uRo + (band + col) * 136 + (kk + qd * 8) * 2);
#pragma unroll
        for (int tt = 0; tt < 4; ++tt)
            acc[tt] = __builtin_amdgcn_mfma_f32_16x16x32_f16(
                as, MFRAG(MPR, tt * 16, kk), acc[tt], 0, 0, 0);
    }
#pragma unroll
    for (int kh2 = 0; kh2 < 2; ++kh2) {
        const int kk = kh2 * 32;
        const f16x8 az = ufrag(sm, uIo + (band + col) * 136 + (kk + qd * 8) * 2);
#pragma unroll
        for (int tt = 0; tt < 4; ++tt)
            acc[tt] = __builtin_amdgcn_mfma_f32_16x16x32_f16(
                az, MFRAG(MPI, tt * 16, kk), acc[tt], 0, 0, 0);
    }
    __builtin_amdgcn_s_setprio(0);

    // ---- epilogue via LDS bounce (wave-local; reuses own S slice):
    // f32 staging rows 0..7 in S_R slice, rows 8..15 in S_I slice,
    // stride 272B. Then each lane reads 2x(row, 8-tau) chunks, fuses
    // r = x*(1+D) + y, stores two coalesced f16x8 (16B). ----
#pragma unroll
    for (int tt = 0; tt < 4; ++tt)
#pragma unroll
        for (int rg = 0; rg < 4; ++rg) {
            const int row = qd * 4 + rg;
            const int base = (row < 8) ? uRo + band * 136 + row * 272
                                       : uIo + band * 136 + (row - 8) * 272;
            *(float*)(sm + base + (tt * 16 + col) * 4) = acc[tt][rg];
        }
    // per-wave DS ordering makes the writes visible to this wave's reads
#pragma unroll
    for (int h2 = 0; h2 < 2; ++h2) {
        const int row = h2 * 8 + (lane >> 3);
        const int tau0 = (lane & 7) * 8;
        const int base = (row < 8) ? uRo + band * 136 + row * 272
                                   : uIo + band * 136 + (row - 8) * 272;
        const float4 y0 = *(const float4*)(sm + base + tau0 * 4);
        const float4 y1 = *(const float4*)(sm + base + tau0 * 4 + 16);
        const f16x8 xv = xep[h2];
        f16x8 o;
        o[0] = (_Float16)fmaf((float)xv[0], Dp1, y0.x);
        o[1] = (_Float16)fmaf((float)xv[1], Dp1, y0.y);
        o[2] = (_Float16)fmaf((float)xv[2], Dp1, y0.z);
        o[3] = (_Float16)fmaf((float)xv[3], Dp1, y0.w);
        o[4] = (_Float16)fmaf((float)xv[4], Dp1, y1.x);
        o[5] = (_Float16)fmaf((float)xv[5], Dp1, y1.y);
        o[6] = (_Float16)fmaf((float)xv[6], Dp1, y1.z);
        o[7] = (_Float16)fmaf((float)xv[7], Dp1, y1.w);
        *(f16x8*)(rr + (band + row) * 64 + tau0) = o;
    }
}

// ---------------------------------------------------------------------------
// K3: single-pass LayerNorm + transpose back: rt f16 [B,H,L] -> out [B,L,H].
// f16x4 reads along L, float4 writes along H, shuffle-butterfly partials.
// ---------------------------------------------------------------------------
__global__ __launch_bounds__(512, 2) void k_ln(const _Float16* __restrict__ rt,
                                               float* __restrict__ out,
                                               const float* __restrict__ lnw,
                                               const float* __restrict__ lnb) {
    __shared__ float tile[16 * 1028];
    __shared__ float ps[8 * 16], pq[8 * 16];
    __shared__ float mm[16], rs[16];
    const int b  = blockIdx.y;
    const int l0 = blockIdx.x * 16;
    const int tid = threadIdx.x;
    const int lq = tid & 3;        // l-quad: handles l = lq*4 .. lq*4+3
    const int hr = tid >> 2;       // 0..127 base row
    const int lane = tid & 63, wvv = tid >> 6;

    const _Float16* base = rt + (size_t)b * Hh * Lseq + l0 + lq * 4;

    float s0 = 0, s1 = 0, s2 = 0, s3 = 0, q0 = 0, q1 = 0, q2 = 0, q3 = 0;
#pragma unroll
    for (int p = 0; p < 8; ++p) {
        const int row = hr + p * 128;
        const f16x4 v = *(const f16x4*)(base + (size_t)row * Lseq);
        const float vx = (float)v[0], vy = (float)v[1];
        const float vz = (float)v[2], vw = (float)v[3];
        float* tw = tile + lq * 4 * 1028 + row;
        tw[0] = vx; tw[1028] = vy; tw[2056] = vz; tw[3084] = vw;
        s0 += vx; q0 = fmaf(vx, vx, q0);
        s1 += vy; q1 = fmaf(vy, vy, q1);
        s2 += vz; q2 = fmaf(vz, vz, q2);
        s3 += vw; q3 = fmaf(vw, vw, q3);
    }
#pragma unroll
    for (int d = 4; d <= 32; d <<= 1) {
        s0 += __shfl_xor(s0, d); q0 += __shfl_xor(q0, d);
        s1 += __shfl_xor(s1, d); q1 += __shfl_xor(q1, d);
        s2 += __shfl_xor(s2, d); q2 += __shfl_xor(q2, d);
        s3 += __shfl_xor(s3, d); q3 += __shfl_xor(q3, d);
    }
    if ((lane >> 2) == 0) {   // lanes 0..3, one per lq
        float* pp = ps + wvv * 16 + lq * 4;
        float* qq = pq + wvv * 16 + lq * 4;
        pp[0] = s0; pp[1] = s1; pp[2] = s2; pp[3] = s3;
        qq[0] = q0; qq[1] = q1; qq[2] = q2; qq[3] = q3;
    }
    __syncthreads();
    if (tid < 16) {
        float s = 0.f, q = 0.f;
#pragma unroll
        for (int w = 0; w < 8; ++w) { s += ps[w * 16 + tid]; q += pq[w * 16 + tid]; }
        const float mu  = s * (1.0f / Hh);
        const float var = fmaf(-mu, mu, q * (1.0f / Hh));
        mm[tid] = mu;
        rs[tid] = rsqrtf(var + LN_EPS);
    }
    __syncthreads();

    const int hq = tid & 255, lsel = tid >> 8;
    const float4 wv4 = *(const float4*)(lnw + hq * 4);
    const float4 bv4 = *(const float4*)(lnb + hq * 4);
    float* obase = out + ((size_t)b * Lseq + l0) * Hh + hq * 4;
#pragma unroll
    for (int pl = 0; pl < 8; ++pl) {
        const int l = pl * 2 + lsel;
        const float mu = mm[l], rsg = rs[l];
        const float4 v = *(const float4*)(tile + l * 1028 + hq * 4);
        float4 o;
        o.x = fmaf((v.x - mu) * rsg, wv4.x, bv4.x);
        o.y = fmaf((v.y - mu) * rsg, wv4.y, bv4.y);
        o.z = fmaf((v.z - mu) * rsg, wv4.z, bv4.z);
        o.w = fmaf((v.w - mu) * rsg, wv4.w, bv4.w);
        *(float4*)(obase + (size_t)l * Hh) = o;
    }
}

// ---------------------------------------------------------------------------
extern "C" void kernel_launch(void* const* d_in, const int* in_sizes, int n_in,
                              void* d_out, int out_size, void* d_ws, size_t ws_size,
                              hipStream_t stream) {
    const float* x     = (const float*)d_in[0];
    const float* logA  = (const float*)d_in[1];
    const float* Aim   = (const float*)d_in[2];
    const float* Cre   = (const float*)d_in[3];
    const float* Cim   = (const float*)d_in[4];
    const float* logdt = (const float*)d_in[5];
    const float* Dp    = (const float*)d_in[6];
    const float* lnw   = (const float*)d_in[7];
    const float* lnb   = (const float*)d_in[8];
    float* out = (float*)d_out;

    _Float16* xt = (_Float16*)d_ws;                        // 32 MiB f16 [B,H,L]
    _Float16* rt = xt + (size_t)Bb * Hh * Lseq;            // 32 MiB f16 [B,H,L]

    _Float16* mats = (_Float16*)d_out;                     // 40 MiB
    float* wwR = (float*)((char*)d_out + 41943040);        // 256 KiB
    float* wwI = (float*)((char*)d_out + 42205184);        // 256 KiB

    // precompute blocks (0..1023) overlap transpose blocks (1024..5119)
    k_pre_trans<<<dim3(Hh + (Hh / 64) * (Lseq / 64) * Bb), 256, 0, stream>>>(
        x, xt, logA, Aim, Cre, Cim, logdt, mats, wwR, wwI);
    k_chunk<<<dim3(2, Hh), 512, 0, stream>>>(xt, rt, mats, wwR, wwI, Dp);
    k_ln<<<dim3(Lseq / 16, Bb), 512, 0, stream>>>(rt, out, lnw, lnb);
}

// Round 8
// 202.693 us; speedup vs baseline: 1.1456x; 1.0104x over previous
//
#include <hip/hip_runtime.h>
#include <cstdint>

#define Bb 4
#define Lseq 4096
#define Hh 1024
#define Nst 64
constexpr float LN_EPS = 1e-5f;

typedef _Float16 f16x8 __attribute__((ext_vector_type(8)));
typedef _Float16 f16x4 __attribute__((ext_vector_type(4)));
typedef float f32x4v __attribute__((ext_vector_type(4)));

typedef const __attribute__((address_space(1))) void* gas_vp;
typedef __attribute__((address_space(3))) void* las_vp;

// XOR-swizzle within a 64x64 f16 matrix: elem e=(row*64+col) stored at
// e ^ ((row&7)<<3). P written pre-swizzled by k_pre (identity global->LDS
// staging); U/M1 generated in-kernel directly at swizzled offsets.
__device__ __forceinline__ int swz(int e) { return e ^ (((e >> 6) & 7) << 3); }

__device__ __forceinline__ void cmul(float& zR, float& zI, float bR, float bI) {
    const float tR = fmaf(zR, bR, -zI * bI);
    zI = fmaf(zR, bI, zI * bR);
    zR = tR;
}

// ---------------------------------------------------------------------------
// K0+K1 fused: precompute (blocks 0..1023) overlaps transpose (blocks 1024+).
// Precompute now emits ONLY: P_re/P_imneg mats (16KB/h, pre-swizzled) +
// small tables (w1 = exp(dA), w64 = exp(64 dA), K[0..63] per h). U and M1
// are generated inside k_chunk from the tables (geometric sequences).
// ---------------------------------------------------------------------------
__global__ __launch_bounds__(256) void k_pre_trans(
    const float* __restrict__ x, _Float16* __restrict__ xt,
    const float* __restrict__ logA, const float* __restrict__ Aim,
    const float* __restrict__ Cre, const float* __restrict__ Cim,
    const float* __restrict__ logdt, _Float16* __restrict__ mats,
    float* __restrict__ wwR, float* __restrict__ wwI,
    float* __restrict__ w1R, float* __restrict__ w1I,
    float* __restrict__ ktab) {
    __shared__ float tile[64 * 65];               // transpose path (16.6KB)
    __shared__ float sdAr[64], sdAi[64], scR[64], scI[64];
    const int tid = threadIdx.x;

    if (blockIdx.x < Hh) {
        // ---------------- precompute path ----------------
        const int h = blockIdx.x;
        _Float16* g2 = mats + (size_t)h * 8192;   // P_re | P_imneg

        if (tid < 64) {
            const int n = tid, idx = h * 64 + n;
            const float ar = -__expf(logA[idx]), ai = Aim[idx];
            const float dt = __expf(logdt[h]);
            const float dAr = dt * ar, dAi = dt * ai;
            const float em = __expf(dAr);
            const float wr = em * __cosf(dAi), wi = em * __sinf(dAi);
            const float Er = wr - 1.0f, Ei = wi;
            const float cr = Cre[idx], ci = Cim[idx];
            const float nr = cr * Er - ci * Ei, ni = cr * Ei + ci * Er;
            const float invd = 1.0f / (ar * ar + ai * ai);
            const float CtR = (nr * ar + ni * ai) * invd;
            const float CtI = (ni * ar - nr * ai) * invd;
            sdAr[n] = dAr; sdAi[n] = dAi;
            scR[n] = 2.0f * CtR; scI[n] = 2.0f * CtI;
            w1R[idx] = wr;  w1I[idx] = wi;        // w = exp(dA)
            const float e64 = __expf(dAr * 64.0f), a64 = dAi * 64.0f;
            wwR[idx] = e64 * __cosf(a64);         // w^64 (scan weight)
            wwI[idx] = e64 * __sinf(a64);
        }
        __syncthreads();

        // K[tau] -> global ktab: tau = tid>>2, each of 4 lanes sums 16 n's,
        // then shfl_xor(1,2) reduce within the aligned 4-lane group.
        {
            const int tau = tid >> 2, ns0 = (tid & 3) * 16;
            const float ftau = (float)tau;
            float sum = 0.0f;
#pragma unroll
            for (int j = 0; j < 16; ++j) {
                const int n = ns0 + j;
                const float ee = __expf(sdAr[n] * ftau), ang = sdAi[n] * ftau;
                sum += ee * (scR[n] * __cosf(ang) - scI[n] * __sinf(ang));
            }
            sum += __shfl_xor(sum, 1);
            sum += __shfl_xor(sum, 2);
            if ((tid & 3) == 0) ktab[h * 64 + tau] = sum;
        }

        // P mats only: P[t][n] = Ct_n w_n^(t+1), pre-swizzled
        for (int e = tid; e < 4096; e += 256) {
            const int row = e >> 6, n = e & 63;
            const int es = swz(e);
            const float q = (float)(row + 1);
            const float ee = __expf(sdAr[n] * q), ang = sdAi[n] * q;
            const float wRq = ee * __cosf(ang), wIq = ee * __sinf(ang);
            g2[es]        = (_Float16)(scR[n] * wRq - scI[n] * wIq);
            g2[4096 + es] = (_Float16)(-(scR[n] * wIq + scI[n] * wRq));
        }
    } else {
        // ---------------- transpose path (f32 in, f16 out) ----------------
        const int tb = blockIdx.x - Hh;
        const int h0 = (tb & 15) * 64;
        const int l0 = ((tb >> 4) & 63) * 64;
        const int b  = tb >> 10;
        const int c = tid & 15, r = tid >> 4;

        const float* src = x + ((size_t)(b * Lseq + l0 + r)) * Hh + h0 + 4 * c;
#pragma unroll
        for (int it = 0; it < 4; ++it) {
            const float4 v = *(const float4*)(src + (size_t)it * 16 * Hh);
            const int l = it * 16 + r;
            tile[(4 * c + 0) * 65 + l] = v.x;
            tile[(4 * c + 1) * 65 + l] = v.y;
            tile[(4 * c + 2) * 65 + l] = v.z;
            tile[(4 * c + 3) * 65 + l] = v.w;
        }
        __syncthreads();
        _Float16* dst = xt + ((size_t)(b * Hh + h0 + r)) * Lseq + l0 + 4 * c;
#pragma unroll
        for (int it = 0; it < 4; ++it) {
            const float* trow = tile + (it * 16 + r) * 65 + 4 * c;
            f16x4 o;
            o[0] = (_Float16)trow[0]; o[1] = (_Float16)trow[1];
            o[2] = (_Float16)trow[2]; o[3] = (_Float16)trow[3];
            *(f16x4*)(dst + (size_t)it * 16 * Lseq) = o;
        }
    }
}

// ---------------------------------------------------------------------------
// K2: chunked block-scan via MFMA. 512 threads / 2 batches per block,
// grid (2, Hh), 2 blocks/CU. R7-proven structure, with the mats stage cut
// 40KB -> 16KB: U (geometric rows, binary powering from w1) and M1
// (tril-Toeplitz of ktab) generated in-registers -> swizzled LDS; only
// P_re/P_imneg staged from global via async global_load_lds.
// ---------------------------------------------------------------------------
#define MR0 0        // U_re   f16 [64][64] stride 128B, XOR-swizzled
#define MI0 8192     // U_im
#define MM1 16384    // M1
#define MPR 24576    // P_re   (staged)
#define MPI 32768    // P_im_neg (staged)
#define USB 40960    // 2 x { S_R [64][68], S_I [64][68] } stride 136B

// row0 is a multiple of 16 at every use, so (row0+col)&7 == col&7
#define MFRAG(base, row0, kk) \
    (*(const f16x8*)(sm + (((base) + ((row0) + col) * 128 + ((kk) + qd * 8) * 2) ^ ((col & 7) << 4))))

static __device__ __forceinline__ f16x8 ufrag(const unsigned char* sm, int off) {
    union { f16x8 v; f16x4 h[2]; } u;
    u.h[0] = *(const f16x4*)(sm + off);      // 8B aligned
    u.h[1] = *(const f16x4*)(sm + off + 8);
    return u.v;
}

__global__ __launch_bounds__(512, 4) void k_chunk(
    const _Float16* __restrict__ xt, _Float16* __restrict__ rt,
    const _Float16* __restrict__ mats,
    const float* __restrict__ wwR, const float* __restrict__ wwI,
    const float* __restrict__ w1R, const float* __restrict__ w1I,
    const float* __restrict__ ktab, const float* __restrict__ Dp) {
    __shared__ __align__(16) unsigned char sm[75776];

    const int tid = threadIdx.x, lane = tid & 63, wv = tid >> 6;
    const int grp = wv >> 2;          // 0..1: which batch of this block's pair
    const int wb  = wv & 3;           // row-band wave 0..3
    const int h = blockIdx.y;
    const int b = blockIdx.x * 2 + grp;   // batch 0..3
    const _Float16* gp = mats + (size_t)h * 8192;   // P only
    const int col = lane & 15, qd = lane >> 4;
    const int band = wb * 16;
    const int uRo = USB + grp * 17408;
    const int uIo = uRo + 8704;

    // ---- async stage: 16KB P mats, identity global->LDS (pre-swizzled) ----
#pragma unroll
    for (int it = 0; it < 2; ++it) {
        const int chunk = it * 512 + tid;   // 16B units, 0..1023
        __builtin_amdgcn_global_load_lds(
            (gas_vp)((const uint4*)gp + chunk),
            (las_vp)(sm + MPR + chunk * 16), 16, 0, 0);
    }

    const float Dp1 = 1.0f + Dp[h];
    const _Float16* xr = xt + ((size_t)b * Hh + h) * Lseq;
    _Float16* rr = rt + ((size_t)b * Hh + h) * Lseq;

    // ---- phase-1 fragment loads + epilogue x loads (latency under gen) ----
    f16x8 axk[2];
#pragma unroll
    for (int kh2 = 0; kh2 < 2; ++kh2)
        axk[kh2] = *(const f16x8*)(xr + (band + col) * 64 + kh2 * 32 + qd * 8);
    f16x8 xep[2];
#pragma unroll
    for (int h2 = 0; h2 < 2; ++h2)
        xep[h2] = *(const f16x8*)(xr + (band + h2 * 8 + (lane >> 3)) * 64 +
                                  (lane & 7) * 8);

    float swR = 0.0f, swI = 0.0f;
    if (lane < 16) {
        swR = wwR[h * 64 + band + lane];
        swI = wwI[h * 64 + band + lane];
    }

    // ---- generate U (w^p geometric rows) into swizzled LDS ----
    {
        const int n = tid >> 3, oct = tid & 7;
        const float wR = w1R[h * 64 + n], wI = w1I[h * 64 + n];
        const float w2R = fmaf(wR, wR, -wI * wI),     w2I = 2.0f * wR * wI;
        const float w4R = fmaf(w2R, w2R, -w2I * w2I), w4I = 2.0f * w2R * w2I;
        const float w8R = fmaf(w4R, w4R, -w4I * w4I), w8I = 2.0f * w4R * w4I;
        const int k = 7 - oct;                        // z = (w^8)^k
        float zR = 1.0f, zI = 0.0f;
        if (k & 1) cmul(zR, zI, w8R, w8I);
        const float w16R = fmaf(w8R, w8R, -w8I * w8I), w16I = 2.0f * w8R * w8I;
        if (k & 2) cmul(zR, zI, w16R, w16I);
        const float w32R = fmaf(w16R, w16R, -w16I * w16I),
                    w32I = 2.0f * w16R * w16I;
        if (k & 4) cmul(zR, zI, w32R, w32I);
        // octet elems: v[j] = w^(63-8*oct-j); j=7 -> z, then multiply up
        f16x8 ur, ui;
        ur[7] = (_Float16)zR; ui[7] = (_Float16)zI;
#pragma unroll
        for (int j = 6; j >= 0; --j) {
            cmul(zR, zI, wR, wI);
            ur[j] = (_Float16)zR; ui[j] = (_Float16)zI;
        }
        const int sb = n * 128 + ((oct ^ (n & 7)) << 4);
        *(f16x8*)(sm + MR0 + sb) = ur;
        *(f16x8*)(sm + MI0 + sb) = ui;
    }

    // ---- generate M1 (tril Toeplitz of K) into swizzled LDS ----
    {
        const int t = tid >> 3, oct = tid & 7;
        f16x8 m1;
#pragma unroll
        for (int i = 0; i < 8; ++i) {
            const int j = oct * 8 + i;
            float v = 0.0f;
            if (j <= t) v = ktab[h * 64 + (t - j)];
            m1[i] = (_Float16)v;
        }
        const int sb = t * 128 + ((oct ^ (t & 7)) << 4);
        *(f16x8*)(sm + MM1 + sb) = m1;
    }
    __syncthreads();  // U/M1 LDS + P staged (vmcnt drain) + x ready

    // ---- phase 1: u = X @ U^T (complex) + hoisted X@M1 ----
    f32x4v aR[4] = {}, aI[4] = {};
    f32x4v acc[4] = {};
    __builtin_amdgcn_s_setprio(1);
#pragma unroll
    for (int kh2 = 0; kh2 < 2; ++kh2) {
        const int kk = kh2 * 32;
#pragma unroll
        for (int nt = 0; nt < 4; ++nt) {
            aR[nt] = __builtin_amdgcn_mfma_f32_16x16x32_f16(
                axk[kh2], MFRAG(MR0, nt * 16, kk), aR[nt], 0, 0, 0);
            aI[nt] = __builtin_amdgcn_mfma_f32_16x16x32_f16(
                axk[kh2], MFRAG(MI0, nt * 16, kk), aI[nt], 0, 0, 0);
        }
    }
    // X@M1 hoisted: independent of the scan, overlaps barrier + scan below
#pragma unroll
    for (int kh2 = 0; kh2 < 2; ++kh2) {
        const int kk = kh2 * 32;
#pragma unroll
        for (int tt = 0; tt < 4; ++tt)
            acc[tt] = __builtin_amdgcn_mfma_f32_16x16x32_f16(
                axk[kh2], MFRAG(MM1, tt * 16, kk), acc[tt], 0, 0, 0);
    }
    __builtin_amdgcn_s_setprio(0);
#pragma unroll
    for (int nt = 0; nt < 4; ++nt)
#pragma unroll
        for (int rg = 0; rg < 4; ++rg) {
            const int cc = band + qd * 4 + rg, n = nt * 16 + col;
            *(_Float16*)(sm + uRo + cc * 136 + n * 2) = (_Float16)aR[nt][rg];
            *(_Float16*)(sm + uIo + cc * 136 + n * 2) = (_Float16)aI[nt][rg];
        }
    __syncthreads();  // u visible

    // ---- phase 2: chunk-level scan, in-place u->S; wave owns 16 n ----
    if (lane < 16) {
        const int n = band + lane;
        float sR = 0.0f, sI = 0.0f;
        for (int c = 0; c < 64; ++c) {
            _Float16* pR = (_Float16*)(sm + uRo + c * 136 + n * 2);
            _Float16* pI = (_Float16*)(sm + uIo + c * 136 + n * 2);
            const float uRv = (float)*pR;
            const float uIv = (float)*pI;
            *pR = (_Float16)sR;
            *pI = (_Float16)sI;
            const float nR = fmaf(swR, sR, fmaf(-swI, sI, uRv));
            sI = fmaf(swR, sI, fmaf(swI, sR, uIv));
            sR = nR;
        }
    }
    __syncthreads();  // S visible

    // ---- phase 3: acc += SR@PR^T + SI@PIneg^T ----
    __builtin_amdgcn_s_setprio(1);
#pragma unroll
    for (int kh2 = 0; kh2 < 2; ++kh2) {
        const int kk = kh2 * 32;
        const f16x8 as = ufrag(sm, uRo + (band + col) * 136 + (kk + qd * 8) * 2);
#pragma unroll
        for (int tt = 0; tt < 4; ++tt)
            acc[tt] = __builtin_amdgcn_mfma_f32_16x16x32_f16(
                as, MFRAG(MPR, tt * 16, kk), acc[tt], 0, 0, 0);
    }
#pragma unroll
    for (int kh2 = 0; kh2 < 2; ++kh2) {
        const int kk = kh2 * 32;
        const f16x8 az = ufrag(sm, uIo + (band + col) * 136 + (kk + qd * 8) * 2);
#pragma unroll
        for (int tt = 0; tt < 4; ++tt)
            acc[tt] = __builtin_amdgcn_mfma_f32_16x16x32_f16(
                az, MFRAG(MPI, tt * 16, kk), acc[tt], 0, 0, 0);
    }
    __builtin_amdgcn_s_setprio(0);

    // ---- epilogue via LDS bounce (wave-local; reuses own S slice):
    // f32 staging rows 0..7 in S_R slice, rows 8..15 in S_I slice,
    // stride 272B; then two coalesced f16x8 stores per lane. ----
#pragma unroll
    for (int tt = 0; tt < 4; ++tt)
#pragma unroll
        for (int rg = 0; rg < 4; ++rg) {
            const int row = qd * 4 + rg;
            const int base = (row < 8) ? uRo + band * 136 + row * 272
                                       : uIo + band * 136 + (row - 8) * 272;
            *(float*)(sm + base + (tt * 16 + col) * 4) = acc[tt][rg];
        }
#pragma unroll
    for (int h2 = 0; h2 < 2; ++h2) {
        const int row = h2 * 8 + (lane >> 3);
        const int tau0 = (lane & 7) * 8;
        const int base = (row < 8) ? uRo + band * 136 + row * 272
                                   : uIo + band * 136 + (row - 8) * 272;
        const float4 y0 = *(const float4*)(sm + base + tau0 * 4);
        const float4 y1 = *(const float4*)(sm + base + tau0 * 4 + 16);
        const f16x8 xv = xep[h2];
        f16x8 o;
        o[0] = (_Float16)fmaf((float)xv[0], Dp1, y0.x);
        o[1] = (_Float16)fmaf((float)xv[1], Dp1, y0.y);
        o[2] = (_Float16)fmaf((float)xv[2], Dp1, y0.z);
        o[3] = (_Float16)fmaf((float)xv[3], Dp1, y0.w);
        o[4] = (_Float16)fmaf((float)xv[4], Dp1, y1.x);
        o[5] = (_Float16)fmaf((float)xv[5], Dp1, y1.y);
        o[6] = (_Float16)fmaf((float)xv[6], Dp1, y1.z);
        o[7] = (_Float16)fmaf((float)xv[7], Dp1, y1.w);
        *(f16x8*)(rr + (band + row) * 64 + tau0) = o;
    }
}

// ---------------------------------------------------------------------------
// K3: single-pass LayerNorm + transpose back: rt f16 [B,H,L] -> out [B,L,H].
// f16x4 reads along L, float4 writes along H, shuffle-butterfly partials.
// ---------------------------------------------------------------------------
__global__ __launch_bounds__(512, 2) void k_ln(const _Float16* __restrict__ rt,
                                               float* __restrict__ out,
                                               const float* __restrict__ lnw,
                                               const float* __restrict__ lnb) {
    __shared__ float tile[16 * 1028];
    __shared__ float ps[8 * 16], pq[8 * 16];
    __shared__ float mm[16], rs[16];
    const int b  = blockIdx.y;
    const int l0 = blockIdx.x * 16;
    const int tid = threadIdx.x;
    const int lq = tid & 3;        // l-quad: handles l = lq*4 .. lq*4+3
    const int hr = tid >> 2;       // 0..127 base row
    const int lane = tid & 63, wvv = tid >> 6;

    const _Float16* base = rt + (size_t)b * Hh * Lseq + l0 + lq * 4;

    float s0 = 0, s1 = 0, s2 = 0, s3 = 0, q0 = 0, q1 = 0, q2 = 0, q3 = 0;
#pragma unroll
    for (int p = 0; p < 8; ++p) {
        const int row = hr + p * 128;
        const f16x4 v = *(const f16x4*)(base + (size_t)row * Lseq);
        const float vx = (float)v[0], vy = (float)v[1];
        const float vz = (float)v[2], vw = (float)v[3];
        float* tw = tile + lq * 4 * 1028 + row;
        tw[0] = vx; tw[1028] = vy; tw[2056] = vz; tw[3084] = vw;
        s0 += vx; q0 = fmaf(vx, vx, q0);
        s1 += vy; q1 = fmaf(vy, vy, q1);
        s2 += vz; q2 = fmaf(vz, vz, q2);
        s3 += vw; q3 = fmaf(vw, vw, q3);
    }
#pragma unroll
    for (int d = 4; d <= 32; d <<= 1) {
        s0 += __shfl_xor(s0, d); q0 += __shfl_xor(q0, d);
        s1 += __shfl_xor(s1, d); q1 += __shfl_xor(q1, d);
        s2 += __shfl_xor(s2, d); q2 += __shfl_xor(q2, d);
        s3 += __shfl_xor(s3, d); q3 += __shfl_xor(q3, d);
    }
    if ((lane >> 2) == 0) {   // lanes 0..3, one per lq
        float* pp = ps + wvv * 16 + lq * 4;
        float* qq = pq + wvv * 16 + lq * 4;
        pp[0] = s0; pp[1] = s1; pp[2] = s2; pp[3] = s3;
        qq[0] = q0; qq[1] = q1; qq[2] = q2; qq[3] = q3;
    }
    __syncthreads();
    if (tid < 16) {
        float s = 0.f, q = 0.f;
#pragma unroll
        for (int w = 0; w < 8; ++w) { s += ps[w * 16 + tid]; q += pq[w * 16 + tid]; }
        const float mu  = s * (1.0f / Hh);
        const float var = fmaf(-mu, mu, q * (1.0f / Hh));
        mm[tid] = mu;
        rs[tid] = rsqrtf(var + LN_EPS);
    }
    __syncthreads();

    const int hq = tid & 255, lsel = tid >> 8;
    const float4 wv4 = *(const float4*)(lnw + hq * 4);
    const float4 bv4 = *(const float4*)(lnb + hq * 4);
    float* obase = out + ((size_t)b * Lseq + l0) * Hh + hq * 4;
#pragma unroll
    for (int pl = 0; pl < 8; ++pl) {
        const int l = pl * 2 + lsel;
        const float mu = mm[l], rsg = rs[l];
        const float4 v = *(const float4*)(tile + l * 1028 + hq * 4);
        float4 o;
        o.x = fmaf((v.x - mu) * rsg, wv4.x, bv4.x);
        o.y = fmaf((v.y - mu) * rsg, wv4.y, bv4.y);
        o.z = fmaf((v.z - mu) * rsg, wv4.z, bv4.z);
        o.w = fmaf((v.w - mu) * rsg, wv4.w, bv4.w);
        *(float4*)(obase + (size_t)l * Hh) = o;
    }
}

// ---------------------------------------------------------------------------
extern "C" void kernel_launch(void* const* d_in, const int* in_sizes, int n_in,
                              void* d_out, int out_size, void* d_ws, size_t ws_size,
                              hipStream_t stream) {
    const float* x     = (const float*)d_in[0];
    const float* logA  = (const float*)d_in[1];
    const float* Aim   = (const float*)d_in[2];
    const float* Cre   = (const float*)d_in[3];
    const float* Cim   = (const float*)d_in[4];
    const float* logdt = (const float*)d_in[5];
    const float* Dp    = (const float*)d_in[6];
    const float* lnw   = (const float*)d_in[7];
    const float* lnb   = (const float*)d_in[8];
    float* out = (float*)d_out;

    _Float16* xt = (_Float16*)d_ws;                        // 32 MiB f16 [B,H,L]
    _Float16* rt = xt + (size_t)Bb * Hh * Lseq;            // 32 MiB f16 [B,H,L]

    _Float16* mats = (_Float16*)d_out;                     // 16 MiB (P only)
    char* tb = (char*)d_out + 16777216;
    float* wwR  = (float*)(tb);                            // 256 KiB each
    float* wwI  = (float*)(tb + 262144);
    float* w1R  = (float*)(tb + 2 * 262144);
    float* w1I  = (float*)(tb + 3 * 262144);
    float* ktab = (float*)(tb + 4 * 262144);

    // precompute blocks (0..1023) overlap transpose blocks (1024..5119)
    k_pre_trans<<<dim3(Hh + (Hh / 64) * (Lseq / 64) * Bb), 256, 0, stream>>>(
        x, xt, logA, Aim, Cre, Cim, logdt, mats, wwR, wwI, w1R, w1I, ktab);
    k_chunk<<<dim3(2, Hh), 512, 0, stream>>>(xt, rt, mats, wwR, wwI,
                                             w1R, w1I, ktab, Dp);
    k_ln<<<dim3(Lseq / 16, Bb), 512, 0, stream>>>(rt, out, lnw, lnb);
}

// Round 9
// 187.280 us; speedup vs baseline: 1.2399x; 1.0823x over previous
//
#include <hip/hip_runtime.h>
#include <cstdint>

#define Bb 4
#define Lseq 4096
#define Hh 1024
#define Nst 64
constexpr float LN_EPS = 1e-5f;

typedef _Float16 f16x8 __attribute__((ext_vector_type(8)));
typedef _Float16 f16x4 __attribute__((ext_vector_type(4)));
typedef float f32x4v __attribute__((ext_vector_type(4)));

typedef const __attribute__((address_space(1))) void* gas_vp;
typedef __attribute__((address_space(3))) void* las_vp;

// XOR-swizzle within a 64x64 f16 matrix: elem e=(row*64+col) stored at
// e ^ ((row&7)<<3). P written pre-swizzled by k_pre (identity global->LDS
// staging); U/M1 generated in-kernel directly at swizzled offsets.
__device__ __forceinline__ int swz(int e) { return e ^ (((e >> 6) & 7) << 3); }

__device__ __forceinline__ void cmul(float& zR, float& zI, float bR, float bI) {
    const float tR = fmaf(zR, bR, -zI * bI);
    zI = fmaf(zR, bI, zI * bR);
    zR = tR;
}

// ---------------------------------------------------------------------------
// K0+K1 fused: precompute (blocks 0..1023) overlaps transpose (blocks 1024+).
// Precompute emits: P_re/P_imneg mats (16KB/h, pre-swizzled) + small tables
// (w1, w64, K[0..63] per h). U and M1 are generated inside k_chunk.
// ---------------------------------------------------------------------------
__global__ __launch_bounds__(256) void k_pre_trans(
    const float* __restrict__ x, _Float16* __restrict__ xt,
    const float* __restrict__ logA, const float* __restrict__ Aim,
    const float* __restrict__ Cre, const float* __restrict__ Cim,
    const float* __restrict__ logdt, _Float16* __restrict__ mats,
    float* __restrict__ wwR, float* __restrict__ wwI,
    float* __restrict__ w1R, float* __restrict__ w1I,
    float* __restrict__ ktab) {
    __shared__ float tile[64 * 65];               // transpose path (16.6KB)
    __shared__ float sdAr[64], sdAi[64], scR[64], scI[64];
    const int tid = threadIdx.x;

    if (blockIdx.x < Hh) {
        // ---------------- precompute path ----------------
        const int h = blockIdx.x;
        _Float16* g2 = mats + (size_t)h * 8192;   // P_re | P_imneg

        if (tid < 64) {
            const int n = tid, idx = h * 64 + n;
            const float ar = -__expf(logA[idx]), ai = Aim[idx];
            const float dt = __expf(logdt[h]);
            const float dAr = dt * ar, dAi = dt * ai;
            const float em = __expf(dAr);
            const float wr = em * __cosf(dAi), wi = em * __sinf(dAi);
            const float Er = wr - 1.0f, Ei = wi;
            const float cr = Cre[idx], ci = Cim[idx];
            const float nr = cr * Er - ci * Ei, ni = cr * Ei + ci * Er;
            const float invd = 1.0f / (ar * ar + ai * ai);
            const float CtR = (nr * ar + ni * ai) * invd;
            const float CtI = (ni * ar - nr * ai) * invd;
            sdAr[n] = dAr; sdAi[n] = dAi;
            scR[n] = 2.0f * CtR; scI[n] = 2.0f * CtI;
            w1R[idx] = wr;  w1I[idx] = wi;        // w = exp(dA)
            const float e64 = __expf(dAr * 64.0f), a64 = dAi * 64.0f;
            wwR[idx] = e64 * __cosf(a64);         // w^64 (scan weight)
            wwI[idx] = e64 * __sinf(a64);
        }
        __syncthreads();

        // K[tau] -> global ktab: tau = tid>>2, each of 4 lanes sums 16 n's,
        // then shfl_xor(1,2) reduce within the aligned 4-lane group.
        {
            const int tau = tid >> 2, ns0 = (tid & 3) * 16;
            const float ftau = (float)tau;
            float sum = 0.0f;
#pragma unroll
            for (int j = 0; j < 16; ++j) {
                const int n = ns0 + j;
                const float ee = __expf(sdAr[n] * ftau), ang = sdAi[n] * ftau;
                sum += ee * (scR[n] * __cosf(ang) - scI[n] * __sinf(ang));
            }
            sum += __shfl_xor(sum, 1);
            sum += __shfl_xor(sum, 2);
            if ((tid & 3) == 0) ktab[h * 64 + tau] = sum;
        }

        // P mats only: P[t][n] = Ct_n w_n^(t+1), pre-swizzled
        for (int e = tid; e < 4096; e += 256) {
            const int row = e >> 6, n = e & 63;
            const int es = swz(e);
            const float q = (float)(row + 1);
            const float ee = __expf(sdAr[n] * q), ang = sdAi[n] * q;
            const float wRq = ee * __cosf(ang), wIq = ee * __sinf(ang);
            g2[es]        = (_Float16)(scR[n] * wRq - scI[n] * wIq);
            g2[4096 + es] = (_Float16)(-(scR[n] * wIq + scI[n] * wRq));
        }
    } else {
        // ---------------- transpose path (f32 in, f16 out) ----------------
        const int tb = blockIdx.x - Hh;
        const int h0 = (tb & 15) * 64;
        const int l0 = ((tb >> 4) & 63) * 64;
        const int b  = tb >> 10;
        const int c = tid & 15, r = tid >> 4;

        const float* src = x + ((size_t)(b * Lseq + l0 + r)) * Hh + h0 + 4 * c;
#pragma unroll
        for (int it = 0; it < 4; ++it) {
            const float4 v = *(const float4*)(src + (size_t)it * 16 * Hh);
            const int l = it * 16 + r;
            tile[(4 * c + 0) * 65 + l] = v.x;
            tile[(4 * c + 1) * 65 + l] = v.y;
            tile[(4 * c + 2) * 65 + l] = v.z;
            tile[(4 * c + 3) * 65 + l] = v.w;
        }
        __syncthreads();
        _Float16* dst = xt + ((size_t)(b * Hh + h0 + r)) * Lseq + l0 + 4 * c;
#pragma unroll
        for (int it = 0; it < 4; ++it) {
            const float* trow = tile + (it * 16 + r) * 65 + 4 * c;
            f16x4 o;
            o[0] = (_Float16)trow[0]; o[1] = (_Float16)trow[1];
            o[2] = (_Float16)trow[2]; o[3] = (_Float16)trow[3];
            *(f16x4*)(dst + (size_t)it * 16 * Lseq) = o;
        }
    }
}

// ---------------------------------------------------------------------------
// K2: chunked block-scan via MFMA. 512 threads / 2 batches per block,
// grid (2, Hh), 2 blocks/CU. R8 structure; ONLY change: rt is written in
// l-tiled layout [B][L/32][H][32] f16 so k_ln's h-scan reads are fully
// coalesced (1KB contiguous per wave) instead of 32B-granule scatter.
// ---------------------------------------------------------------------------
#define MR0 0        // U_re   f16 [64][64] stride 128B, XOR-swizzled
#define MI0 8192     // U_im
#define MM1 16384    // M1
#define MPR 24576    // P_re   (staged)
#define MPI 32768    // P_im_neg (staged)
#define USB 40960    // 2 x { S_R [64][68], S_I [64][68] } stride 136B

// row0 is a multiple of 16 at every use, so (row0+col)&7 == col&7
#define MFRAG(base, row0, kk) \
    (*(const f16x8*)(sm + (((base) + ((row0) + col) * 128 + ((kk) + qd * 8) * 2) ^ ((col & 7) << 4))))

static __device__ __forceinline__ f16x8 ufrag(const unsigned char* sm, int off) {
    union { f16x8 v; f16x4 h[2]; } u;
    u.h[0] = *(const f16x4*)(sm + off);      // 8B aligned
    u.h[1] = *(const f16x4*)(sm + off + 8);
    return u.v;
}

__global__ __launch_bounds__(512, 4) void k_chunk(
    const _Float16* __restrict__ xt, _Float16* __restrict__ rt,
    const _Float16* __restrict__ mats,
    const float* __restrict__ wwR, const float* __restrict__ wwI,
    const float* __restrict__ w1R, const float* __restrict__ w1I,
    const float* __restrict__ ktab, const float* __restrict__ Dp) {
    __shared__ __align__(16) unsigned char sm[75776];

    const int tid = threadIdx.x, lane = tid & 63, wv = tid >> 6;
    const int grp = wv >> 2;          // 0..1: which batch of this block's pair
    const int wb  = wv & 3;           // row-band wave 0..3
    const int h = blockIdx.y;
    const int b = blockIdx.x * 2 + grp;   // batch 0..3
    const _Float16* gp = mats + (size_t)h * 8192;   // P only
    const int col = lane & 15, qd = lane >> 4;
    const int band = wb * 16;
    const int uRo = USB + grp * 17408;
    const int uIo = uRo + 8704;

    // ---- async stage: 16KB P mats, identity global->LDS (pre-swizzled) ----
#pragma unroll
    for (int it = 0; it < 2; ++it) {
        const int chunk = it * 512 + tid;   // 16B units, 0..1023
        __builtin_amdgcn_global_load_lds(
            (gas_vp)((const uint4*)gp + chunk),
            (las_vp)(sm + MPR + chunk * 16), 16, 0, 0);
    }

    const float Dp1 = 1.0f + Dp[h];
    const _Float16* xr = xt + ((size_t)b * Hh + h) * Lseq;

    // ---- phase-1 fragment loads + epilogue x loads (latency under gen) ----
    f16x8 axk[2];
#pragma unroll
    for (int kh2 = 0; kh2 < 2; ++kh2)
        axk[kh2] = *(const f16x8*)(xr + (band + col) * 64 + kh2 * 32 + qd * 8);
    f16x8 xep[2];
#pragma unroll
    for (int h2 = 0; h2 < 2; ++h2)
        xep[h2] = *(const f16x8*)(xr + (band + h2 * 8 + (lane >> 3)) * 64 +
                                  (lane & 7) * 8);

    float swR = 0.0f, swI = 0.0f;
    if (lane < 16) {
        swR = wwR[h * 64 + band + lane];
        swI = wwI[h * 64 + band + lane];
    }

    // ---- generate U (w^p geometric rows) into swizzled LDS ----
    {
        const int n = tid >> 3, oct = tid & 7;
        const float wR = w1R[h * 64 + n], wI = w1I[h * 64 + n];
        const float w2R = fmaf(wR, wR, -wI * wI),     w2I = 2.0f * wR * wI;
        const float w4R = fmaf(w2R, w2R, -w2I * w2I), w4I = 2.0f * w2R * w2I;
        const float w8R = fmaf(w4R, w4R, -w4I * w4I), w8I = 2.0f * w4R * w4I;
        const int k = 7 - oct;                        // z = (w^8)^k
        float zR = 1.0f, zI = 0.0f;
        if (k & 1) cmul(zR, zI, w8R, w8I);
        const float w16R = fmaf(w8R, w8R, -w8I * w8I), w16I = 2.0f * w8R * w8I;
        if (k & 2) cmul(zR, zI, w16R, w16I);
        const float w32R = fmaf(w16R, w16R, -w16I * w16I),
                    w32I = 2.0f * w16R * w16I;
        if (k & 4) cmul(zR, zI, w32R, w32I);
        // octet elems: v[j] = w^(63-8*oct-j); j=7 -> z, then multiply up
        f16x8 ur, ui;
        ur[7] = (_Float16)zR; ui[7] = (_Float16)zI;
#pragma unroll
        for (int j = 6; j >= 0; --j) {
            cmul(zR, zI, wR, wI);
            ur[j] = (_Float16)zR; ui[j] = (_Float16)zI;
        }
        const int sb = n * 128 + ((oct ^ (n & 7)) << 4);
        *(f16x8*)(sm + MR0 + sb) = ur;
        *(f16x8*)(sm + MI0 + sb) = ui;
    }

    // ---- generate M1 (tril Toeplitz of K) into swizzled LDS ----
    {
        const int t = tid >> 3, oct = tid & 7;
        f16x8 m1;
#pragma unroll
        for (int i = 0; i < 8; ++i) {
            const int j = oct * 8 + i;
            float v = 0.0f;
            if (j <= t) v = ktab[h * 64 + (t - j)];
            m1[i] = (_Float16)v;
        }
        const int sb = t * 128 + ((oct ^ (t & 7)) << 4);
        *(f16x8*)(sm + MM1 + sb) = m1;
    }
    __syncthreads();  // U/M1 LDS + P staged (vmcnt drain) + x ready

    // ---- phase 1: u = X @ U^T (complex) + hoisted X@M1 ----
    f32x4v aR[4] = {}, aI[4] = {};
    f32x4v acc[4] = {};
    __builtin_amdgcn_s_setprio(1);
#pragma unroll
    for (int kh2 = 0; kh2 < 2; ++kh2) {
        const int kk = kh2 * 32;
#pragma unroll
        for (int nt = 0; nt < 4; ++nt) {
            aR[nt] = __builtin_amdgcn_mfma_f32_16x16x32_f16(
                axk[kh2], MFRAG(MR0, nt * 16, kk), aR[nt], 0, 0, 0);
            aI[nt] = __builtin_amdgcn_mfma_f32_16x16x32_f16(
                axk[kh2], MFRAG(MI0, nt * 16, kk), aI[nt], 0, 0, 0);
        }
    }
    // X@M1 hoisted: independent of the scan, overlaps barrier + scan below
#pragma unroll
    for (int kh2 = 0; kh2 < 2; ++kh2) {
        const int kk = kh2 * 32;
#pragma unroll
        for (int tt = 0; tt < 4; ++tt)
            acc[tt] = __builtin_amdgcn_mfma_f32_16x16x32_f16(
                axk[kh2], MFRAG(MM1, tt * 16, kk), acc[tt], 0, 0, 0);
    }
    __builtin_amdgcn_s_setprio(0);
#pragma unroll
    for (int nt = 0; nt < 4; ++nt)
#pragma unroll
        for (int rg = 0; rg < 4; ++rg) {
            const int cc = band + qd * 4 + rg, n = nt * 16 + col;
            *(_Float16*)(sm + uRo + cc * 136 + n * 2) = (_Float16)aR[nt][rg];
            *(_Float16*)(sm + uIo + cc * 136 + n * 2) = (_Float16)aI[nt][rg];
        }
    __syncthreads();  // u visible

    // ---- phase 2: chunk-level scan, in-place u->S; wave owns 16 n ----
    if (lane < 16) {
        const int n = band + lane;
        float sR = 0.0f, sI = 0.0f;
        for (int c = 0; c < 64; ++c) {
            _Float16* pR = (_Float16*)(sm + uRo + c * 136 + n * 2);
            _Float16* pI = (_Float16*)(sm + uIo + c * 136 + n * 2);
            const float uRv = (float)*pR;
            const float uIv = (float)*pI;
            *pR = (_Float16)sR;
            *pI = (_Float16)sI;
            const float nR = fmaf(swR, sR, fmaf(-swI, sI, uRv));
            sI = fmaf(swR, sI, fmaf(swI, sR, uIv));
            sR = nR;
        }
    }
    __syncthreads();  // S visible

    // ---- phase 3: acc += SR@PR^T + SI@PIneg^T ----
    __builtin_amdgcn_s_setprio(1);
#pragma unroll
    for (int kh2 = 0; kh2 < 2; ++kh2) {
        const int kk = kh2 * 32;
        const f16x8 as = ufrag(sm, uRo + (band + col) * 136 + (kk + qd * 8) * 2);
#pragma unroll
        for (int tt = 0; tt < 4; ++tt)
            acc[tt] = __builtin_amdgcn_mfma_f32_16x16x32_f16(
                as, MFRAG(MPR, tt * 16, kk), acc[tt], 0, 0, 0);
    }
#pragma unroll
    for (int kh2 = 0; kh2 < 2; ++kh2) {
        const int kk = kh2 * 32;
        const f16x8 az = ufrag(sm, uIo + (band + col) * 136 + (kk + qd * 8) * 2);
#pragma unroll
        for (int tt = 0; tt < 4; ++tt)
            acc[tt] = __builtin_amdgcn_mfma_f32_16x16x32_f16(
                az, MFRAG(MPI, tt * 16, kk), acc[tt], 0, 0, 0);
    }
    __builtin_amdgcn_s_setprio(0);

    // ---- epilogue via LDS bounce (wave-local; reuses own S slice):
    // f32 staging rows 0..7 in S_R slice, rows 8..15 in S_I slice,
    // stride 272B; then two coalesced f16x8 stores per lane into the
    // l-tiled rt layout [B][L/32][H][32]. ----
#pragma unroll
    for (int tt = 0; tt < 4; ++tt)
#pragma unroll
        for (int rg = 0; rg < 4; ++rg) {
            const int row = qd * 4 + rg;
            const int base = (row < 8) ? uRo + band * 136 + row * 272
                                       : uIo + band * 136 + (row - 8) * 272;
            *(float*)(sm + base + (tt * 16 + col) * 4) = acc[tt][rg];
        }
#pragma unroll
    for (int h2 = 0; h2 < 2; ++h2) {
        const int row = h2 * 8 + (lane >> 3);
        const int tau0 = (lane & 7) * 8;
        const int base = (row < 8) ? uRo + band * 136 + row * 272
                                   : uIo + band * 136 + (row - 8) * 272;
        const float4 y0 = *(const float4*)(sm + base + tau0 * 4);
        const float4 y1 = *(const float4*)(sm + base + tau0 * 4 + 16);
        const f16x8 xv = xep[h2];
        f16x8 o;
        o[0] = (_Float16)fmaf((float)xv[0], Dp1, y0.x);
        o[1] = (_Float16)fmaf((float)xv[1], Dp1, y0.y);
        o[2] = (_Float16)fmaf((float)xv[2], Dp1, y0.z);
        o[3] = (_Float16)fmaf((float)xv[3], Dp1, y0.w);
        o[4] = (_Float16)fmaf((float)xv[4], Dp1, y1.x);
        o[5] = (_Float16)fmaf((float)xv[5], Dp1, y1.y);
        o[6] = (_Float16)fmaf((float)xv[6], Dp1, y1.z);
        o[7] = (_Float16)fmaf((float)xv[7], Dp1, y1.w);
        // l = (band+row)*64 + tau0 -> lt = c*2 + (tau0>>5), li = tau0&31
        const int c = band + row;
        const int lt2 = c * 2 + (tau0 >> 5);
        const int li = tau0 & 31;
        *(f16x8*)(rt + (((size_t)b * 128 + lt2) * 1024 + h) * 32 + li) = o;
    }
}

// ---------------------------------------------------------------------------
// K3: LayerNorm + transpose back from l-tiled rt [B][L/32][H][32] f16.
// Pass 1: fully-coalesced reads (1KB contiguous per wave: 4 lanes x 16B per
// h), stage LDS tile [l][h] + 8 per-l register sums, shfl_xor(4..32) reduce.
// Pass 2: f16x4 LDS reads along h, normalize, 256B-contiguous float4 writes.
// LDS 66KB + partials -> 2 blocks/CU.
// ---------------------------------------------------------------------------
#define HPAD 1032
__global__ __launch_bounds__(512, 2) void k_ln(const _Float16* __restrict__ rt,
                                               float* __restrict__ out,
                                               const float* __restrict__ lnw,
                                               const float* __restrict__ lnb) {
    __shared__ _Float16 tile[32 * HPAD];          // [l][h], 66048B
    __shared__ float ps[8][32], pq[8][32];
    __shared__ float mm[32], rs[32];
    const int b  = blockIdx.y;
    const int lt = blockIdx.x;                    // 32-l tile index
    const int tid = threadIdx.x;
    const int lane = tid & 63, wvv = tid >> 6;
    const int oct = tid & 3;                      // li-octet: li = oct*8..+7
    const int hloc = tid >> 2;                    // 0..127

    const _Float16* base = rt + ((size_t)b * 128 + lt) * 1024 * 32;

    float s[8] = {}, q[8] = {};
#pragma unroll
    for (int p = 0; p < 8; ++p) {
        const int h = p * 128 + hloc;
        const f16x8 v = *(const f16x8*)(base + h * 32 + oct * 8);
#pragma unroll
        for (int j = 0; j < 8; ++j) {
            const float f = (float)v[j];
            tile[(oct * 8 + j) * HPAD + h] = v[j];
            s[j] += f;
            q[j] = fmaf(f, f, q[j]);
        }
    }
    // reduce across lanes sharing oct (stride 4): d = 4,8,16,32
#pragma unroll
    for (int d = 4; d <= 32; d <<= 1) {
#pragma unroll
        for (int j = 0; j < 8; ++j) {
            s[j] += __shfl_xor(s[j], d);
            q[j] += __shfl_xor(q[j], d);
        }
    }
    if ((lane >> 2) == 0) {   // lanes 0..3, one per oct
#pragma unroll
        for (int j = 0; j < 8; ++j) {
            ps[wvv][oct * 8 + j] = s[j];
            pq[wvv][oct * 8 + j] = q[j];
        }
    }
    __syncthreads();
    if (tid < 32) {
        float ss = 0.f, qq = 0.f;
#pragma unroll
        for (int w = 0; w < 8; ++w) { ss += ps[w][tid]; qq += pq[w][tid]; }
        const float mu  = ss * (1.0f / Hh);
        const float var = fmaf(-mu, mu, qq * (1.0f / Hh));
        mm[tid] = mu;
        rs[tid] = rsqrtf(var + LN_EPS);
    }
    __syncthreads();

    // pass 2: thread t -> l = t>>4 (0..31), hq0 = t&15
    const int l = tid >> 4, hq0 = tid & 15;
    const float mu = mm[l], rsg = rs[l];
    float* obase = out + ((size_t)(b * Lseq + lt * 32 + l)) * Hh;
#pragma unroll
    for (int p = 0; p < 16; ++p) {
        const int hh = (p * 16 + hq0) * 4;
        const f16x4 v = *(const f16x4*)(&tile[l * HPAD + hh]);
        const float4 w4 = *(const float4*)(lnw + hh);
        const float4 b4 = *(const float4*)(lnb + hh);
        float4 o;
        o.x = fmaf(((float)v[0] - mu) * rsg, w4.x, b4.x);
        o.y = fmaf(((float)v[1] - mu) * rsg, w4.y, b4.y);
        o.z = fmaf(((float)v[2] - mu) * rsg, w4.z, b4.z);
        o.w = fmaf(((float)v[3] - mu) * rsg, w4.w, b4.w);
        *(float4*)(obase + hh) = o;
    }
}

// ---------------------------------------------------------------------------
extern "C" void kernel_launch(void* const* d_in, const int* in_sizes, int n_in,
                              void* d_out, int out_size, void* d_ws, size_t ws_size,
                              hipStream_t stream) {
    const float* x     = (const float*)d_in[0];
    const float* logA  = (const float*)d_in[1];
    const float* Aim   = (const float*)d_in[2];
    const float* Cre   = (const float*)d_in[3];
    const float* Cim   = (const float*)d_in[4];
    const float* logdt = (const float*)d_in[5];
    const float* Dp    = (const float*)d_in[6];
    const float* lnw   = (const float*)d_in[7];
    const float* lnb   = (const float*)d_in[8];
    float* out = (float*)d_out;

    _Float16* xt = (_Float16*)d_ws;                        // 32 MiB f16 [B,H,L]
    _Float16* rt = xt + (size_t)Bb * Hh * Lseq;            // 32 MiB f16 tiled

    _Float16* mats = (_Float16*)d_out;                     // 16 MiB (P only)
    char* tb = (char*)d_out + 16777216;
    float* wwR  = (float*)(tb);                            // 256 KiB each
    float* wwI  = (float*)(tb + 262144);
    float* w1R  = (float*)(tb + 2 * 262144);
    float* w1I  = (float*)(tb + 3 * 262144);
    float* ktab = (float*)(tb + 4 * 262144);

    // precompute blocks (0..1023) overlap transpose blocks (1024..5119)
    k_pre_trans<<<dim3(Hh + (Hh / 64) * (Lseq / 64) * Bb), 256, 0, stream>>>(
        x, xt, logA, Aim, Cre, Cim, logdt, mats, wwR, wwI, w1R, w1I, ktab);
    k_chunk<<<dim3(2, Hh), 512, 0, stream>>>(xt, rt, mats, wwR, wwI,
                                             w1R, w1I, ktab, Dp);
    k_ln<<<dim3(Lseq / 32, Bb), 512, 0, stream>>>(rt, out, lnw, lnb);
}

// Round 10
// 183.865 us; speedup vs baseline: 1.2630x; 1.0186x over previous
//
#include <hip/hip_runtime.h>
#include <cstdint>

#define Bb 4
#define Lseq 4096
#define Hh 1024
#define Nst 64
constexpr float LN_EPS = 1e-5f;

typedef _Float16 f16x8 __attribute__((ext_vector_type(8)));
typedef _Float16 f16x4 __attribute__((ext_vector_type(4)));
typedef float f32x4v __attribute__((ext_vector_type(4)));

typedef const __attribute__((address_space(1))) void* gas_vp;
typedef __attribute__((address_space(3))) void* las_vp;

// XOR-swizzle within a 64x64 f16 matrix: elem e=(row*64+col) stored at
// e ^ ((row&7)<<3). P written pre-swizzled by k_pre (identity global->LDS
// staging); U/M1 generated in-kernel directly at swizzled offsets.
__device__ __forceinline__ int swz(int e) { return e ^ (((e >> 6) & 7) << 3); }

__device__ __forceinline__ void cmul(float& zR, float& zI, float bR, float bI) {
    const float tR = fmaf(zR, bR, -zI * bI);
    zI = fmaf(zR, bI, zI * bR);
    zR = tR;
}

// ---------------------------------------------------------------------------
// K0+K1 fused: precompute (blocks 0..1023) overlaps transpose (blocks 1024+).
// Precompute emits: P_re/P_imneg mats (16KB/h, pre-swizzled) + small tables
// (w1, w64, K[0..63] per h). P is built via its geometric recurrence in t
// (~12 cmul per octet, NO per-element transcendentals) into the idle
// transpose LDS tile, then stored as f16x8 16B writes (no sub-dword ECC-RMW
// global stores). U and M1 are generated inside k_chunk.
// ---------------------------------------------------------------------------
__global__ __launch_bounds__(256) void k_pre_trans(
    const float* __restrict__ x, _Float16* __restrict__ xt,
    const float* __restrict__ logA, const float* __restrict__ Aim,
    const float* __restrict__ Cre, const float* __restrict__ Cim,
    const float* __restrict__ logdt, _Float16* __restrict__ mats,
    float* __restrict__ wwR, float* __restrict__ wwI,
    float* __restrict__ w1R, float* __restrict__ w1I,
    float* __restrict__ ktab) {
    __shared__ float tile[64 * 65];               // transpose OR P staging
    __shared__ float sdAr[64], sdAi[64], scR[64], scI[64];
    __shared__ float sw1R[64], sw1I[64];
    const int tid = threadIdx.x;

    if (blockIdx.x < Hh) {
        // ---------------- precompute path ----------------
        const int h = blockIdx.x;
        _Float16* g2 = mats + (size_t)h * 8192;   // P_re | P_imneg

        if (tid < 64) {
            const int n = tid, idx = h * 64 + n;
            const float ar = -__expf(logA[idx]), ai = Aim[idx];
            const float dt = __expf(logdt[h]);
            const float dAr = dt * ar, dAi = dt * ai;
            const float em = __expf(dAr);
            const float wr = em * __cosf(dAi), wi = em * __sinf(dAi);
            const float Er = wr - 1.0f, Ei = wi;
            const float cr = Cre[idx], ci = Cim[idx];
            const float nr = cr * Er - ci * Ei, ni = cr * Ei + ci * Er;
            const float invd = 1.0f / (ar * ar + ai * ai);
            const float CtR = (nr * ar + ni * ai) * invd;
            const float CtI = (ni * ar - nr * ai) * invd;
            sdAr[n] = dAr; sdAi[n] = dAi;
            scR[n] = 2.0f * CtR; scI[n] = 2.0f * CtI;
            sw1R[n] = wr; sw1I[n] = wi;
            w1R[idx] = wr;  w1I[idx] = wi;        // w = exp(dA)
            const float e64 = __expf(dAr * 64.0f), a64 = dAi * 64.0f;
            wwR[idx] = e64 * __cosf(a64);         // w^64 (scan weight)
            wwI[idx] = e64 * __sinf(a64);
        }
        __syncthreads();

        // K[tau] -> global ktab: tau = tid>>2, each of 4 lanes sums 16 n's,
        // then shfl_xor(1,2) reduce within the aligned 4-lane group.
        {
            const int tau = tid >> 2, ns0 = (tid & 3) * 16;
            const float ftau = (float)tau;
            float sum = 0.0f;
#pragma unroll
            for (int j = 0; j < 16; ++j) {
                const int n = ns0 + j;
                const float ee = __expf(sdAr[n] * ftau), ang = sdAi[n] * ftau;
                sum += ee * (scR[n] * __cosf(ang) - scI[n] * __sinf(ang));
            }
            sum += __shfl_xor(sum, 1);
            sum += __shfl_xor(sum, 2);
            if ((tid & 3) == 0) ktab[h * 64 + tau] = sum;
        }

        // ---- P phase A: geometric recurrence in t, into LDS staging ----
        // P[t][n] = Ct_n * w_n^(t+1). Octet o: n = o&63, t in [8k, 8k+8).
        _Float16* pst = (_Float16*)tile;          // [64t][64n] re | imneg
#pragma unroll
        for (int oo = 0; oo < 2; ++oo) {
            const int o = oo * 256 + tid;
            const int n = o & 63, k = o >> 6;
            const float wR = sw1R[n], wI = sw1I[n];
            const float w2R = fmaf(wR, wR, -wI * wI),     w2I = 2.0f * wR * wI;
            const float w4R = fmaf(w2R, w2R, -w2I * w2I), w4I = 2.0f * w2R * w2I;
            const float w8R = fmaf(w4R, w4R, -w4I * w4I), w8I = 2.0f * w4R * w4I;
            float zR = 1.0f, zI = 0.0f;           // w^(8k)
            if (k & 1) cmul(zR, zI, w8R, w8I);
            const float w16R = fmaf(w8R, w8R, -w8I * w8I),
                        w16I = 2.0f * w8R * w8I;
            if (k & 2) cmul(zR, zI, w16R, w16I);
            const float w32R = fmaf(w16R, w16R, -w16I * w16I),
                        w32I = 2.0f * w16R * w16I;
            if (k & 4) cmul(zR, zI, w32R, w32I);
            float pR = scR[n], pI = scI[n];       // Ct
            cmul(pR, pI, zR, zI);                 // Ct * w^(8k)
            cmul(pR, pI, wR, wI);                 // Ct * w^(8k+1)
#pragma unroll
            for (int j = 0; j < 8; ++j) {
                const int t = k * 8 + j;
                pst[t * 64 + n]        = (_Float16)pR;
                pst[4096 + t * 64 + n] = (_Float16)(-pI);
                cmul(pR, pI, wR, wI);
            }
        }
        __syncthreads();
        // ---- P phase B: vectorized swizzled stores (16B, contiguous) ----
#pragma unroll
        for (int oo = 0; oo < 2; ++oo) {
            const int o = oo * 256 + tid;         // row-octet index
            const int t = o >> 3, j8 = (o & 7) * 8;
            const int e = t * 64 + j8;
            const int es = e ^ ((t & 7) << 3);
            *(f16x8*)(g2 + es)        = *(const f16x8*)(pst + e);
            *(f16x8*)(g2 + 4096 + es) = *(const f16x8*)(pst + 4096 + e);
        }
    } else {
        // ---------------- transpose path (f32 in, f16 out) ----------------
        const int tb = blockIdx.x - Hh;
        const int h0 = (tb & 15) * 64;
        const int l0 = ((tb >> 4) & 63) * 64;
        const int b  = tb >> 10;
        const int c = tid & 15, r = tid >> 4;

        const float* src = x + ((size_t)(b * Lseq + l0 + r)) * Hh + h0 + 4 * c;
#pragma unroll
        for (int it = 0; it < 4; ++it) {
            const float4 v = *(const float4*)(src + (size_t)it * 16 * Hh);
            const int l = it * 16 + r;
            tile[(4 * c + 0) * 65 + l] = v.x;
            tile[(4 * c + 1) * 65 + l] = v.y;
            tile[(4 * c + 2) * 65 + l] = v.z;
            tile[(4 * c + 3) * 65 + l] = v.w;
        }
        __syncthreads();
        _Float16* dst = xt + ((size_t)(b * Hh + h0 + r)) * Lseq + l0 + 4 * c;
#pragma unroll
        for (int it = 0; it < 4; ++it) {
            const float* trow = tile + (it * 16 + r) * 65 + 4 * c;
            f16x4 o;
            o[0] = (_Float16)trow[0]; o[1] = (_Float16)trow[1];
            o[2] = (_Float16)trow[2]; o[3] = (_Float16)trow[3];
            *(f16x4*)(dst + (size_t)it * 16 * Lseq) = o;
        }
    }
}

// ---------------------------------------------------------------------------
// K2: chunked block-scan via MFMA. 512 threads / 2 batches per block,
// grid (2, Hh), 2 blocks/CU. R9 structure; ONLY change: phase-2 scan is a
// 64-lane 3-step scheme (vs 16-lane 64-step serial): lane = (cg, nn) owns
// chunks [cg*16,(cg+1)*16) x n = band+nn. Step 1: read-only 16-step group
// total. Step 2: 2-step weighted shfl_up KS across the 4 groups (ww^16,
// ww^32). Step 3: 16-step exclusive write pass. Chain ~2x shorter; each
// (c,n) element is RMW'd by exactly ONE lane (no cross-lane hazard).
// ---------------------------------------------------------------------------
#define MR0 0        // U_re   f16 [64][64] stride 128B, XOR-swizzled
#define MI0 8192     // U_im
#define MM1 16384    // M1
#define MPR 24576    // P_re   (staged)
#define MPI 32768    // P_im_neg (staged)
#define USB 40960    // 2 x { S_R [64][68], S_I [64][68] } stride 136B

// row0 is a multiple of 16 at every use, so (row0+col)&7 == col&7
#define MFRAG(base, row0, kk) \
    (*(const f16x8*)(sm + (((base) + ((row0) + col) * 128 + ((kk) + qd * 8) * 2) ^ ((col & 7) << 4))))

static __device__ __forceinline__ f16x8 ufrag(const unsigned char* sm, int off) {
    union { f16x8 v; f16x4 h[2]; } u;
    u.h[0] = *(const f16x4*)(sm + off);      // 8B aligned
    u.h[1] = *(const f16x4*)(sm + off + 8);
    return u.v;
}

__global__ __launch_bounds__(512, 4) void k_chunk(
    const _Float16* __restrict__ xt, _Float16* __restrict__ rt,
    const _Float16* __restrict__ mats,
    const float* __restrict__ wwR, const float* __restrict__ wwI,
    const float* __restrict__ w1R, const float* __restrict__ w1I,
    const float* __restrict__ ktab, const float* __restrict__ Dp) {
    __shared__ __align__(16) unsigned char sm[75776];

    const int tid = threadIdx.x, lane = tid & 63, wv = tid >> 6;
    const int grp = wv >> 2;          // 0..1: which batch of this block's pair
    const int wb  = wv & 3;           // row-band wave 0..3
    const int h = blockIdx.y;
    const int b = blockIdx.x * 2 + grp;   // batch 0..3
    const _Float16* gp = mats + (size_t)h * 8192;   // P only
    const int col = lane & 15, qd = lane >> 4;
    const int band = wb * 16;
    const int uRo = USB + grp * 17408;
    const int uIo = uRo + 8704;

    // ---- async stage: 16KB P mats, identity global->LDS (pre-swizzled) ----
#pragma unroll
    for (int it = 0; it < 2; ++it) {
        const int chunk = it * 512 + tid;   // 16B units, 0..1023
        __builtin_amdgcn_global_load_lds(
            (gas_vp)((const uint4*)gp + chunk),
            (las_vp)(sm + MPR + chunk * 16), 16, 0, 0);
    }

    const float Dp1 = 1.0f + Dp[h];
    const _Float16* xr = xt + ((size_t)b * Hh + h) * Lseq;

    // ---- phase-1 fragment loads + epilogue x loads (latency under gen) ----
    f16x8 axk[2];
#pragma unroll
    for (int kh2 = 0; kh2 < 2; ++kh2)
        axk[kh2] = *(const f16x8*)(xr + (band + col) * 64 + kh2 * 32 + qd * 8);
    f16x8 xep[2];
#pragma unroll
    for (int h2 = 0; h2 < 2; ++h2)
        xep[h2] = *(const f16x8*)(xr + (band + h2 * 8 + (lane >> 3)) * 64 +
                                  (lane & 7) * 8);

    // scan weight ww = w^64 for this lane's n = band + (lane&15); all lanes
    const float swR = wwR[h * 64 + band + (lane & 15)];
    const float swI = wwI[h * 64 + band + (lane & 15)];

    // ---- generate U (w^p geometric rows) into swizzled LDS ----
    {
        const int n = tid >> 3, oct = tid & 7;
        const float wR = w1R[h * 64 + n], wI = w1I[h * 64 + n];
        const float w2R = fmaf(wR, wR, -wI * wI),     w2I = 2.0f * wR * wI;
        const float w4R = fmaf(w2R, w2R, -w2I * w2I), w4I = 2.0f * w2R * w2I;
        const float w8R = fmaf(w4R, w4R, -w4I * w4I), w8I = 2.0f * w4R * w4I;
        const int k = 7 - oct;                        // z = (w^8)^k
        float zR = 1.0f, zI = 0.0f;
        if (k & 1) cmul(zR, zI, w8R, w8I);
        const float w16R = fmaf(w8R, w8R, -w8I * w8I), w16I = 2.0f * w8R * w8I;
        if (k & 2) cmul(zR, zI, w16R, w16I);
        const float w32R = fmaf(w16R, w16R, -w16I * w16I),
                    w32I = 2.0f * w16R * w16I;
        if (k & 4) cmul(zR, zI, w32R, w32I);
        // octet elems: v[j] = w^(63-8*oct-j); j=7 -> z, then multiply up
        f16x8 ur, ui;
        ur[7] = (_Float16)zR; ui[7] = (_Float16)zI;
#pragma unroll
        for (int j = 6; j >= 0; --j) {
            cmul(zR, zI, wR, wI);
            ur[j] = (_Float16)zR; ui[j] = (_Float16)zI;
        }
        const int sb = n * 128 + ((oct ^ (n & 7)) << 4);
        *(f16x8*)(sm + MR0 + sb) = ur;
        *(f16x8*)(sm + MI0 + sb) = ui;
    }

    // ---- generate M1 (tril Toeplitz of K) into swizzled LDS ----
    {
        const int t = tid >> 3, oct = tid & 7;
        f16x8 m1;
#pragma unroll
        for (int i = 0; i < 8; ++i) {
            const int j = oct * 8 + i;
            float v = 0.0f;
            if (j <= t) v = ktab[h * 64 + (t - j)];
            m1[i] = (_Float16)v;
        }
        const int sb = t * 128 + ((oct ^ (t & 7)) << 4);
        *(f16x8*)(sm + MM1 + sb) = m1;
    }
    __syncthreads();  // U/M1 LDS + P staged (vmcnt drain) + x ready

    // ---- phase 1: u = X @ U^T (complex) + hoisted X@M1 ----
    f32x4v aR[4] = {}, aI[4] = {};
    f32x4v acc[4] = {};
    __builtin_amdgcn_s_setprio(1);
#pragma unroll
    for (int kh2 = 0; kh2 < 2; ++kh2) {
        const int kk = kh2 * 32;
#pragma unroll
        for (int nt = 0; nt < 4; ++nt) {
            aR[nt] = __builtin_amdgcn_mfma_f32_16x16x32_f16(
                axk[kh2], MFRAG(MR0, nt * 16, kk), aR[nt], 0, 0, 0);
            aI[nt] = __builtin_amdgcn_mfma_f32_16x16x32_f16(
                axk[kh2], MFRAG(MI0, nt * 16, kk), aI[nt], 0, 0, 0);
        }
    }
    // X@M1 hoisted: results not consumed until epilogue, so the matrix pipe
    // chews on it across the barrier + scan below
#pragma unroll
    for (int kh2 = 0; kh2 < 2; ++kh2) {
        const int kk = kh2 * 32;
#pragma unroll
        for (int tt = 0; tt < 4; ++tt)
            acc[tt] = __builtin_amdgcn_mfma_f32_16x16x32_f16(
                axk[kh2], MFRAG(MM1, tt * 16, kk), acc[tt], 0, 0, 0);
    }
    __builtin_amdgcn_s_setprio(0);
#pragma unroll
    for (int nt = 0; nt < 4; ++nt)
#pragma unroll
        for (int rg = 0; rg < 4; ++rg) {
            const int cc = band + qd * 4 + rg, n = nt * 16 + col;
            *(_Float16*)(sm + uRo + cc * 136 + n * 2) = (_Float16)aR[nt][rg];
            *(_Float16*)(sm + uIo + cc * 136 + n * 2) = (_Float16)aI[nt][rg];
        }
    __syncthreads();  // u visible

    // ---- phase 2: 64-lane 3-step scan; lane owns (cg = lane>>4 chunk
    //      group, nn = lane&15 -> n = band+nn). Exclusive S in-place. ----
    {
        const int nn = lane & 15, cg = lane >> 4;
        const int n = band + nn;
        const int c0 = cg * 16;
        // W16 = ww^16, W32 = ww^32 (4-5 squarings)
        const float W2R = fmaf(swR, swR, -swI * swI), W2I = 2.0f * swR * swI;
        const float W4R = fmaf(W2R, W2R, -W2I * W2I), W4I = 2.0f * W2R * W2I;
        const float W8R = fmaf(W4R, W4R, -W4I * W4I), W8I = 2.0f * W4R * W4I;
        const float W16R = fmaf(W8R, W8R, -W8I * W8I), W16I = 2.0f * W8R * W8I;
        const float W32R = fmaf(W16R, W16R, -W16I * W16I),
                    W32I = 2.0f * W16R * W16I;
        // step 1: group total (read-only)
        float tRv = 0.0f, tIv = 0.0f;
#pragma unroll
        for (int i = 0; i < 16; ++i) {
            const int c = c0 + i;
            const float uRv = (float)*(const _Float16*)(sm + uRo + c * 136 + n * 2);
            const float uIv = (float)*(const _Float16*)(sm + uIo + c * 136 + n * 2);
            const float nR = fmaf(swR, tRv, fmaf(-swI, tIv, uRv));
            tIv = fmaf(swR, tIv, fmaf(swI, tRv, uIv));
            tRv = nR;
        }
        // step 2: weighted KS across cg groups (within this wave)
        float GR = tRv, GI = tIv;
        float xR = __shfl_up(GR, 16), xI = __shfl_up(GI, 16);
        if (cg >= 1) {
            const float t2 = fmaf(W16R, xR, fmaf(-W16I, xI, GR));
            GI = fmaf(W16R, xI, fmaf(W16I, xR, GI));
            GR = t2;
        }
        xR = __shfl_up(GR, 32); xI = __shfl_up(GI, 32);
        if (cg >= 2) {
            const float t2 = fmaf(W32R, xR, fmaf(-W32I, xI, GR));
            GI = fmaf(W32R, xI, fmaf(W32I, xR, GI));
            GR = t2;
        }
        const float pR = __shfl_up(GR, 16), pI = __shfl_up(GI, 16);
        float sR = (cg == 0) ? 0.0f : pR;
        float sI = (cg == 0) ? 0.0f : pI;
        // step 3: exclusive write + advance (each element owned by this lane)
#pragma unroll
        for (int i = 0; i < 16; ++i) {
            const int c = c0 + i;
            _Float16* qR = (_Float16*)(sm + uRo + c * 136 + n * 2);
            _Float16* qI = (_Float16*)(sm + uIo + c * 136 + n * 2);
            const float uRv = (float)*qR;
            const float uIv = (float)*qI;
            *qR = (_Float16)sR;
            *qI = (_Float16)sI;
            const float nR = fmaf(swR, sR, fmaf(-swI, sI, uRv));
            sI = fmaf(swR, sI, fmaf(swI, sR, uIv));
            sR = nR;
        }
    }
    __syncthreads();  // S visible

    // ---- phase 3: acc += SR@PR^T + SI@PIneg^T ----
    __builtin_amdgcn_s_setprio(1);
#pragma unroll
    for (int kh2 = 0; kh2 < 2; ++kh2) {
        const int kk = kh2 * 32;
        const f16x8 as = ufrag(sm, uRo + (band + col) * 136 + (kk + qd * 8) * 2);
#pragma unroll
        for (int tt = 0; tt < 4; ++tt)
            acc[tt] = __builtin_amdgcn_mfma_f32_16x16x32_f16(
                as, MFRAG(MPR, tt * 16, kk), acc[tt], 0, 0, 0);
    }
#pragma unroll
    for (int kh2 = 0; kh2 < 2; ++kh2) {
        const int kk = kh2 * 32;
        const f16x8 az = ufrag(sm, uIo + (band + col) * 136 + (kk + qd * 8) * 2);
#pragma unroll
        for (int tt = 0; tt < 4; ++tt)
            acc[tt] = __builtin_amdgcn_mfma_f32_16x16x32_f16(
                az, MFRAG(MPI, tt * 16, kk), acc[tt], 0, 0, 0);
    }
    __builtin_amdgcn_s_setprio(0);

    // ---- epilogue via LDS bounce (wave-local; reuses own S slice):
    // f32 staging rows 0..7 in S_R slice, rows 8..15 in S_I slice,
    // stride 272B; then two coalesced f16x8 stores per lane into the
    // l-tiled rt layout [B][L/32][H][32]. ----
#pragma unroll
    for (int tt = 0; tt < 4; ++tt)
#pragma unroll
        for (int rg = 0; rg < 4; ++rg) {
            const int row = qd * 4 + rg;
            const int base = (row < 8) ? uRo + band * 136 + row * 272
                                       : uIo + band * 136 + (row - 8) * 272;
            *(float*)(sm + base + (tt * 16 + col) * 4) = acc[tt][rg];
        }
#pragma unroll
    for (int h2 = 0; h2 < 2; ++h2) {
        const int row = h2 * 8 + (lane >> 3);
        const int tau0 = (lane & 7) * 8;
        const int base = (row < 8) ? uRo + band * 136 + row * 272
                                   : uIo + band * 136 + (row - 8) * 272;
        const float4 y0 = *(const float4*)(sm + base + tau0 * 4);
        const float4 y1 = *(const float4*)(sm + base + tau0 * 4 + 16);
        const f16x8 xv = xep[h2];
        f16x8 o;
        o[0] = (_Float16)fmaf((float)xv[0], Dp1, y0.x);
        o[1] = (_Float16)fmaf((float)xv[1], Dp1, y0.y);
        o[2] = (_Float16)fmaf((float)xv[2], Dp1, y0.z);
        o[3] = (_Float16)fmaf((float)xv[3], Dp1, y0.w);
        o[4] = (_Float16)fmaf((float)xv[4], Dp1, y1.x);
        o[5] = (_Float16)fmaf((float)xv[5], Dp1, y1.y);
        o[6] = (_Float16)fmaf((float)xv[6], Dp1, y1.z);
        o[7] = (_Float16)fmaf((float)xv[7], Dp1, y1.w);
        // l = (band+row)*64 + tau0 -> lt = c*2 + (tau0>>5), li = tau0&31
        const int c = band + row;
        const int lt2 = c * 2 + (tau0 >> 5);
        const int li = tau0 & 31;
        *(f16x8*)(rt + (((size_t)b * 128 + lt2) * 1024 + h) * 32 + li) = o;
    }
}

// ---------------------------------------------------------------------------
// K3: LayerNorm + transpose back from l-tiled rt [B][L/32][H][32] f16.
// Pass 1: fully-coalesced reads (1KB contiguous per wave), stage LDS tile
// [l][h] + 8 per-l register sums, shfl_xor(4..32) reduce. Pass 2: f16x4 LDS
// reads along h, normalize, 256B-contiguous float4 writes. 2 blocks/CU.
// ---------------------------------------------------------------------------
#define HPAD 1032
__global__ __launch_bounds__(512, 2) void k_ln(const _Float16* __restrict__ rt,
                                               float* __restrict__ out,
                                               const float* __restrict__ lnw,
                                               const float* __restrict__ lnb) {
    __shared__ _Float16 tile[32 * HPAD];          // [l][h], 66048B
    __shared__ float ps[8][32], pq[8][32];
    __shared__ float mm[32], rs[32];
    const int b  = blockIdx.y;
    const int lt = blockIdx.x;                    // 32-l tile index
    const int tid = threadIdx.x;
    const int lane = tid & 63, wvv = tid >> 6;
    const int oct = tid & 3;                      // li-octet: li = oct*8..+7
    const int hloc = tid >> 2;                    // 0..127

    const _Float16* base = rt + ((size_t)b * 128 + lt) * 1024 * 32;

    float s[8] = {}, q[8] = {};
#pragma unroll
    for (int p = 0; p < 8; ++p) {
        const int h = p * 128 + hloc;
        const f16x8 v = *(const f16x8*)(base + h * 32 + oct * 8);
#pragma unroll
        for (int j = 0; j < 8; ++j) {
            const float f = (float)v[j];
            tile[(oct * 8 + j) * HPAD + h] = v[j];
            s[j] += f;
            q[j] = fmaf(f, f, q[j]);
        }
    }
    // reduce across lanes sharing oct (stride 4): d = 4,8,16,32
#pragma unroll
    for (int d = 4; d <= 32; d <<= 1) {
#pragma unroll
        for (int j = 0; j < 8; ++j) {
            s[j] += __shfl_xor(s[j], d);
            q[j] += __shfl_xor(q[j], d);
        }
    }
    if ((lane >> 2) == 0) {   // lanes 0..3, one per oct
#pragma unroll
        for (int j = 0; j < 8; ++j) {
            ps[wvv][oct * 8 + j] = s[j];
            pq[wvv][oct * 8 + j] = q[j];
        }
    }
    __syncthreads();
    if (tid < 32) {
        float ss = 0.f, qq = 0.f;
#pragma unroll
        for (int w = 0; w < 8; ++w) { ss += ps[w][tid]; qq += pq[w][tid]; }
        const float mu  = ss * (1.0f / Hh);
        const float var = fmaf(-mu, mu, qq * (1.0f / Hh));
        mm[tid] = mu;
        rs[tid] = rsqrtf(var + LN_EPS);
    }
    __syncthreads();

    // pass 2: thread t -> l = t>>4 (0..31), hq0 = t&15
    const int l = tid >> 4, hq0 = tid & 15;
    const float mu = mm[l], rsg = rs[l];
    float* obase = out + ((size_t)(b * Lseq + lt * 32 + l)) * Hh;
#pragma unroll
    for (int p = 0; p < 16; ++p) {
        const int hh = (p * 16 + hq0) * 4;
        const f16x4 v = *(const f16x4*)(&tile[l * HPAD + hh]);
        const float4 w4 = *(const float4*)(lnw + hh);
        const float4 b4 = *(const float4*)(lnb + hh);
        float4 o;
        o.x = fmaf(((float)v[0] - mu) * rsg, w4.x, b4.x);
        o.y = fmaf(((float)v[1] - mu) * rsg, w4.y, b4.y);
        o.z = fmaf(((float)v[2] - mu) * rsg, w4.z, b4.z);
        o.w = fmaf(((float)v[3] - mu) * rsg, w4.w, b4.w);
        *(float4*)(obase + hh) = o;
    }
}

// ---------------------------------------------------------------------------
extern "C" void kernel_launch(void* const* d_in, const int* in_sizes, int n_in,
                              void* d_out, int out_size, void* d_ws, size_t ws_size,
                              hipStream_t stream) {
    const float* x     = (const float*)d_in[0];
    const float* logA  = (const float*)d_in[1];
    const float* Aim   = (const float*)d_in[2];
    const float* Cre   = (const float*)d_in[3];
    const float* Cim   = (const float*)d_in[4];
    const float* logdt = (const float*)d_in[5];
    const float* Dp    = (const float*)d_in[6];
    const float* lnw   = (const float*)d_in[7];
    const float* lnb   = (const float*)d_in[8];
    float* out = (float*)d_out;

    _Float16* xt = (_Float16*)d_ws;                        // 32 MiB f16 [B,H,L]
    _Float16* rt = xt + (size_t)Bb * Hh * Lseq;            // 32 MiB f16 tiled

    _Float16* mats = (_Float16*)d_out;                     // 16 MiB (P only)
    char* tb = (char*)d_out + 16777216;
    float* wwR  = (float*)(tb);                            // 256 KiB each
    float* wwI  = (float*)(tb + 262144);
    float* w1R  = (float*)(tb + 2 * 262144);
    float* w1I  = (float*)(tb + 3 * 262144);
    float* ktab = (float*)(tb + 4 * 262144);

    // precompute blocks (0..1023) overlap transpose blocks (1024..5119)
    k_pre_trans<<<dim3(Hh + (Hh / 64) * (Lseq / 64) * Bb), 256, 0, stream>>>(
        x, xt, logA, Aim, Cre, Cim, logdt, mats, wwR, wwI, w1R, w1I, ktab);
    k_chunk<<<dim3(2, Hh), 512, 0, stream>>>(xt, rt, mats, wwR, wwI,
                                             w1R, w1I, ktab, Dp);
    k_ln<<<dim3(Lseq / 32, Bb), 512, 0, stream>>>(rt, out, lnw, lnb);
}

// Round 11
// 181.291 us; speedup vs baseline: 1.2809x; 1.0142x over previous
//
#include <hip/hip_runtime.h>
#include <cstdint>

#define Bb 4
#define Lseq 4096
#define Hh 1024
#define Nst 64
constexpr float LN_EPS = 1e-5f;

typedef _Float16 f16x8 __attribute__((ext_vector_type(8)));
typedef _Float16 f16x4 __attribute__((ext_vector_type(4)));
typedef float f32x4v __attribute__((ext_vector_type(4)));

typedef const __attribute__((address_space(1))) void* gas_vp;
typedef __attribute__((address_space(3))) void* las_vp;

// XOR-swizzle within a 64x64 f16 matrix: elem e=(row*64+col) stored at
// e ^ ((row&7)<<3). P written pre-swizzled by k_pre (identity global->LDS
// staging); U/M1 generated in-kernel directly at swizzled offsets.
__device__ __forceinline__ int swz(int e) { return e ^ (((e >> 6) & 7) << 3); }

__device__ __forceinline__ void cmul(float& zR, float& zI, float bR, float bI) {
    const float tR = fmaf(zR, bR, -zI * bI);
    zI = fmaf(zR, bI, zI * bR);
    zR = tR;
}

// ---------------------------------------------------------------------------
// K0+K1 fused: precompute (blocks 0..1023) overlaps transpose (blocks 1024+).
// Precompute emits: P_re/P_imneg mats (16KB/h, pre-swizzled) + small tables
// (w1, w64, K[0..63] per h). P built via geometric recurrence in t (no
// per-element transcendentals), stored as 16B f16x8 writes. U and M1 are
// generated inside k_chunk.
// ---------------------------------------------------------------------------
__global__ __launch_bounds__(256) void k_pre_trans(
    const float* __restrict__ x, _Float16* __restrict__ xt,
    const float* __restrict__ logA, const float* __restrict__ Aim,
    const float* __restrict__ Cre, const float* __restrict__ Cim,
    const float* __restrict__ logdt, _Float16* __restrict__ mats,
    float* __restrict__ wwR, float* __restrict__ wwI,
    float* __restrict__ w1R, float* __restrict__ w1I,
    float* __restrict__ ktab) {
    __shared__ float tile[64 * 65];               // transpose OR P staging
    __shared__ float sdAr[64], sdAi[64], scR[64], scI[64];
    __shared__ float sw1R[64], sw1I[64];
    const int tid = threadIdx.x;

    if (blockIdx.x < Hh) {
        // ---------------- precompute path ----------------
        const int h = blockIdx.x;
        _Float16* g2 = mats + (size_t)h * 8192;   // P_re | P_imneg

        if (tid < 64) {
            const int n = tid, idx = h * 64 + n;
            const float ar = -__expf(logA[idx]), ai = Aim[idx];
            const float dt = __expf(logdt[h]);
            const float dAr = dt * ar, dAi = dt * ai;
            const float em = __expf(dAr);
            const float wr = em * __cosf(dAi), wi = em * __sinf(dAi);
            const float Er = wr - 1.0f, Ei = wi;
            const float cr = Cre[idx], ci = Cim[idx];
            const float nr = cr * Er - ci * Ei, ni = cr * Ei + ci * Er;
            const float invd = 1.0f / (ar * ar + ai * ai);
            const float CtR = (nr * ar + ni * ai) * invd;
            const float CtI = (ni * ar - nr * ai) * invd;
            sdAr[n] = dAr; sdAi[n] = dAi;
            scR[n] = 2.0f * CtR; scI[n] = 2.0f * CtI;
            sw1R[n] = wr; sw1I[n] = wi;
            w1R[idx] = wr;  w1I[idx] = wi;        // w = exp(dA)
            const float e64 = __expf(dAr * 64.0f), a64 = dAi * 64.0f;
            wwR[idx] = e64 * __cosf(a64);         // w^64 (scan weight)
            wwI[idx] = e64 * __sinf(a64);
        }
        __syncthreads();

        // K[tau] -> global ktab: tau = tid>>2, each of 4 lanes sums 16 n's,
        // then shfl_xor(1,2) reduce within the aligned 4-lane group.
        {
            const int tau = tid >> 2, ns0 = (tid & 3) * 16;
            const float ftau = (float)tau;
            float sum = 0.0f;
#pragma unroll
            for (int j = 0; j < 16; ++j) {
                const int n = ns0 + j;
                const float ee = __expf(sdAr[n] * ftau), ang = sdAi[n] * ftau;
                sum += ee * (scR[n] * __cosf(ang) - scI[n] * __sinf(ang));
            }
            sum += __shfl_xor(sum, 1);
            sum += __shfl_xor(sum, 2);
            if ((tid & 3) == 0) ktab[h * 64 + tau] = sum;
        }

        // ---- P phase A: geometric recurrence in t, into LDS staging ----
        // P[t][n] = Ct_n * w_n^(t+1). Octet o: n = o&63, t in [8k, 8k+8).
        _Float16* pst = (_Float16*)tile;          // [64t][64n] re | imneg
#pragma unroll
        for (int oo = 0; oo < 2; ++oo) {
            const int o = oo * 256 + tid;
            const int n = o & 63, k = o >> 6;
            const float wR = sw1R[n], wI = sw1I[n];
            const float w2R = fmaf(wR, wR, -wI * wI),     w2I = 2.0f * wR * wI;
            const float w4R = fmaf(w2R, w2R, -w2I * w2I), w4I = 2.0f * w2R * w2I;
            const float w8R = fmaf(w4R, w4R, -w4I * w4I), w8I = 2.0f * w4R * w4I;
            float zR = 1.0f, zI = 0.0f;           // w^(8k)
            if (k & 1) cmul(zR, zI, w8R, w8I);
            const float w16R = fmaf(w8R, w8R, -w8I * w8I),
                        w16I = 2.0f * w8R * w8I;
            if (k & 2) cmul(zR, zI, w16R, w16I);
            const float w32R = fmaf(w16R, w16R, -w16I * w16I),
                        w32I = 2.0f * w16R * w16I;
            if (k & 4) cmul(zR, zI, w32R, w32I);
            float pR = scR[n], pI = scI[n];       // Ct
            cmul(pR, pI, zR, zI);                 // Ct * w^(8k)
            cmul(pR, pI, wR, wI);                 // Ct * w^(8k+1)
#pragma unroll
            for (int j = 0; j < 8; ++j) {
                const int t = k * 8 + j;
                pst[t * 64 + n]        = (_Float16)pR;
                pst[4096 + t * 64 + n] = (_Float16)(-pI);
                cmul(pR, pI, wR, wI);
            }
        }
        __syncthreads();
        // ---- P phase B: vectorized swizzled stores (16B, contiguous) ----
#pragma unroll
        for (int oo = 0; oo < 2; ++oo) {
            const int o = oo * 256 + tid;         // row-octet index
            const int t = o >> 3, j8 = (o & 7) * 8;
            const int e = t * 64 + j8;
            const int es = e ^ ((t & 7) << 3);
            *(f16x8*)(g2 + es)        = *(const f16x8*)(pst + e);
            *(f16x8*)(g2 + 4096 + es) = *(const f16x8*)(pst + 4096 + e);
        }
    } else {
        // ---------------- transpose path (f32 in, f16 out) ----------------
        const int tb = blockIdx.x - Hh;
        const int h0 = (tb & 15) * 64;
        const int l0 = ((tb >> 4) & 63) * 64;
        const int b  = tb >> 10;
        const int c = tid & 15, r = tid >> 4;

        const float* src = x + ((size_t)(b * Lseq + l0 + r)) * Hh + h0 + 4 * c;
#pragma unroll
        for (int it = 0; it < 4; ++it) {
            const float4 v = *(const float4*)(src + (size_t)it * 16 * Hh);
            const int l = it * 16 + r;
            tile[(4 * c + 0) * 65 + l] = v.x;
            tile[(4 * c + 1) * 65 + l] = v.y;
            tile[(4 * c + 2) * 65 + l] = v.z;
            tile[(4 * c + 3) * 65 + l] = v.w;
        }
        __syncthreads();
        // store pass: 8 l-octets x 32 h-rows -> 2x 16B f16x8 stores/thread
        const int c8 = tid & 7, r32 = tid >> 3;
        _Float16* dst = xt + ((size_t)(b * Hh + h0 + r32)) * Lseq + l0 + 8 * c8;
#pragma unroll
        for (int it = 0; it < 2; ++it) {
            const float* trow = tile + (it * 32 + r32) * 65 + 8 * c8;
            f16x8 o;
#pragma unroll
            for (int j = 0; j < 8; ++j) o[j] = (_Float16)trow[j];
            *(f16x8*)(dst + (size_t)it * 32 * Lseq) = o;
        }
    }
}

// ---------------------------------------------------------------------------
// K2: chunked block-scan via MFMA. 512 threads / 2 batches per block,
// grid (2, Hh), 2 blocks/CU. R10 structure; ONLY change: u/S LDS columns are
// ROTATED by 16*((c>>4)&3) (mod 64). The 3-step scan's bank index is
// (2c + n/2) mod 32, in which the chunk-group bits of c vanish -> 4 groups
// collided on the same 8-bank set (3.28M conflicts). The rotation shifts
// each group by 8 banks -> disjoint sets, conflict-free. Rotation is
// wave-uniform (= 16*wb) in phase-1 writes and phase-3 fragment reads.
// ---------------------------------------------------------------------------
#define MR0 0        // U_re   f16 [64][64] stride 128B, XOR-swizzled
#define MI0 8192     // U_im
#define MM1 16384    // M1
#define MPR 24576    // P_re   (staged)
#define MPI 32768    // P_im_neg (staged)
#define USB 40960    // 2 x { S_R [64][68], S_I [64][68] } stride 136B

// row0 is a multiple of 16 at every use, so (row0+col)&7 == col&7
#define MFRAG(base, row0, kk) \
    (*(const f16x8*)(sm + (((base) + ((row0) + col) * 128 + ((kk) + qd * 8) * 2) ^ ((col & 7) << 4))))

static __device__ __forceinline__ f16x8 ufrag(const unsigned char* sm, int off) {
    union { f16x8 v; f16x4 h[2]; } u;
    u.h[0] = *(const f16x4*)(sm + off);      // 8B aligned
    u.h[1] = *(const f16x4*)(sm + off + 8);
    return u.v;
}

__global__ __launch_bounds__(512, 4) void k_chunk(
    const _Float16* __restrict__ xt, _Float16* __restrict__ rt,
    const _Float16* __restrict__ mats,
    const float* __restrict__ wwR, const float* __restrict__ wwI,
    const float* __restrict__ w1R, const float* __restrict__ w1I,
    const float* __restrict__ ktab, const float* __restrict__ Dp) {
    __shared__ __align__(16) unsigned char sm[75776];

    const int tid = threadIdx.x, lane = tid & 63, wv = tid >> 6;
    const int grp = wv >> 2;          // 0..1: which batch of this block's pair
    const int wb  = wv & 3;           // row-band wave 0..3
    const int h = blockIdx.y;
    const int b = blockIdx.x * 2 + grp;   // batch 0..3
    const _Float16* gp = mats + (size_t)h * 8192;   // P only
    const int col = lane & 15, qd = lane >> 4;
    const int band = wb * 16;
    const int uRo = USB + grp * 17408;
    const int uIo = uRo + 8704;

    // ---- async stage: 16KB P mats, identity global->LDS (pre-swizzled) ----
#pragma unroll
    for (int it = 0; it < 2; ++it) {
        const int chunk = it * 512 + tid;   // 16B units, 0..1023
        __builtin_amdgcn_global_load_lds(
            (gas_vp)((const uint4*)gp + chunk),
            (las_vp)(sm + MPR + chunk * 16), 16, 0, 0);
    }

    const float Dp1 = 1.0f + Dp[h];
    const _Float16* xr = xt + ((size_t)b * Hh + h) * Lseq;

    // ---- phase-1 fragment loads + epilogue x loads (latency under gen) ----
    f16x8 axk[2];
#pragma unroll
    for (int kh2 = 0; kh2 < 2; ++kh2)
        axk[kh2] = *(const f16x8*)(xr + (band + col) * 64 + kh2 * 32 + qd * 8);
    f16x8 xep[2];
#pragma unroll
    for (int h2 = 0; h2 < 2; ++h2)
        xep[h2] = *(const f16x8*)(xr + (band + h2 * 8 + (lane >> 3)) * 64 +
                                  (lane & 7) * 8);

    // scan weight ww = w^64 for this lane's n = band + (lane&15); all lanes
    const float swR = wwR[h * 64 + band + (lane & 15)];
    const float swI = wwI[h * 64 + band + (lane & 15)];

    // ---- generate U (w^p geometric rows) into swizzled LDS ----
    {
        const int n = tid >> 3, oct = tid & 7;
        const float wR = w1R[h * 64 + n], wI = w1I[h * 64 + n];
        const float w2R = fmaf(wR, wR, -wI * wI),     w2I = 2.0f * wR * wI;
        const float w4R = fmaf(w2R, w2R, -w2I * w2I), w4I = 2.0f * w2R * w2I;
        const float w8R = fmaf(w4R, w4R, -w4I * w4I), w8I = 2.0f * w4R * w4I;
        const int k = 7 - oct;                        // z = (w^8)^k
        float zR = 1.0f, zI = 0.0f;
        if (k & 1) cmul(zR, zI, w8R, w8I);
        const float w16R = fmaf(w8R, w8R, -w8I * w8I), w16I = 2.0f * w8R * w8I;
        if (k & 2) cmul(zR, zI, w16R, w16I);
        const float w32R = fmaf(w16R, w16R, -w16I * w16I),
                    w32I = 2.0f * w16R * w16I;
        if (k & 4) cmul(zR, zI, w32R, w32I);
        // octet elems: v[j] = w^(63-8*oct-j); j=7 -> z, then multiply up
        f16x8 ur, ui;
        ur[7] = (_Float16)zR; ui[7] = (_Float16)zI;
#pragma unroll
        for (int j = 6; j >= 0; --j) {
            cmul(zR, zI, wR, wI);
            ur[j] = (_Float16)zR; ui[j] = (_Float16)zI;
        }
        const int sb = n * 128 + ((oct ^ (n & 7)) << 4);
        *(f16x8*)(sm + MR0 + sb) = ur;
        *(f16x8*)(sm + MI0 + sb) = ui;
    }

    // ---- generate M1 (tril Toeplitz of K) into swizzled LDS ----
    {
        const int t = tid >> 3, oct = tid & 7;
        f16x8 m1;
#pragma unroll
        for (int i = 0; i < 8; ++i) {
            const int j = oct * 8 + i;
            float v = 0.0f;
            if (j <= t) v = ktab[h * 64 + (t - j)];
            m1[i] = (_Float16)v;
        }
        const int sb = t * 128 + ((oct ^ (t & 7)) << 4);
        *(f16x8*)(sm + MM1 + sb) = m1;
    }
    __syncthreads();  // U/M1 LDS + P staged (vmcnt drain) + x ready

    // ---- phase 1: u = X @ U^T (complex) + hoisted X@M1 ----
    f32x4v aR[4] = {}, aI[4] = {};
    f32x4v acc[4] = {};
    __builtin_amdgcn_s_setprio(1);
#pragma unroll
    for (int kh2 = 0; kh2 < 2; ++kh2) {
        const int kk = kh2 * 32;
#pragma unroll
        for (int nt = 0; nt < 4; ++nt) {
            aR[nt] = __builtin_amdgcn_mfma_f32_16x16x32_f16(
                axk[kh2], MFRAG(MR0, nt * 16, kk), aR[nt], 0, 0, 0);
            aI[nt] = __builtin_amdgcn_mfma_f32_16x16x32_f16(
                axk[kh2], MFRAG(MI0, nt * 16, kk), aI[nt], 0, 0, 0);
        }
    }
    // X@M1 hoisted: results not consumed until epilogue, so the matrix pipe
    // chews on it across the barrier + scan below
#pragma unroll
    for (int kh2 = 0; kh2 < 2; ++kh2) {
        const int kk = kh2 * 32;
#pragma unroll
        for (int tt = 0; tt < 4; ++tt)
            acc[tt] = __builtin_amdgcn_mfma_f32_16x16x32_f16(
                axk[kh2], MFRAG(MM1, tt * 16, kk), acc[tt], 0, 0, 0);
    }
    __builtin_amdgcn_s_setprio(0);
    // u write: column rotated by 16*wb (= 16*((cc>>4)&3), wave-uniform)
#pragma unroll
    for (int nt = 0; nt < 4; ++nt)
#pragma unroll
        for (int rg = 0; rg < 4; ++rg) {
            const int cc = band + qd * 4 + rg;
            const int ncol = ((nt * 16 + col) + wb * 16) & 63;
            *(_Float16*)(sm + uRo + cc * 136 + ncol * 2) = (_Float16)aR[nt][rg];
            *(_Float16*)(sm + uIo + cc * 136 + ncol * 2) = (_Float16)aI[nt][rg];
        }
    __syncthreads();  // u visible

    // ---- phase 2: 64-lane 3-step scan; lane owns (cg = lane>>4 chunk
    //      group, nn = lane&15 -> n = band+nn). Exclusive S in-place.
    //      Column rotation (16*cg) puts each cg group on its own 8-bank set.
    {
        const int nn = lane & 15, cg = lane >> 4;
        const int n = band + nn;
        const int ncol = (n + cg * 16) & 63;          // rotation for this cg
        const int c0 = cg * 16;
        // W16 = ww^16, W32 = ww^32 (4-5 squarings)
        const float W2R = fmaf(swR, swR, -swI * swI), W2I = 2.0f * swR * swI;
        const float W4R = fmaf(W2R, W2R, -W2I * W2I), W4I = 2.0f * W2R * W2I;
        const float W8R = fmaf(W4R, W4R, -W4I * W4I), W8I = 2.0f * W4R * W4I;
        const float W16R = fmaf(W8R, W8R, -W8I * W8I), W16I = 2.0f * W8R * W8I;
        const float W32R = fmaf(W16R, W16R, -W16I * W16I),
                    W32I = 2.0f * W16R * W16I;
        // step 1: group total (read-only)
        float tRv = 0.0f, tIv = 0.0f;
#pragma unroll
        for (int i = 0; i < 16; ++i) {
            const int c = c0 + i;
            const float uRv = (float)*(const _Float16*)(sm + uRo + c * 136 + ncol * 2);
            const float uIv = (float)*(const _Float16*)(sm + uIo + c * 136 + ncol * 2);
            const float nR = fmaf(swR, tRv, fmaf(-swI, tIv, uRv));
            tIv = fmaf(swR, tIv, fmaf(swI, tRv, uIv));
            tRv = nR;
        }
        // step 2: weighted KS across cg groups (within this wave)
        float GR = tRv, GI = tIv;
        float xR = __shfl_up(GR, 16), xI = __shfl_up(GI, 16);
        if (cg >= 1) {
            const float t2 = fmaf(W16R, xR, fmaf(-W16I, xI, GR));
            GI = fmaf(W16R, xI, fmaf(W16I, xR, GI));
            GR = t2;
        }
        xR = __shfl_up(GR, 32); xI = __shfl_up(GI, 32);
        if (cg >= 2) {
            const float t2 = fmaf(W32R, xR, fmaf(-W32I, xI, GR));
            GI = fmaf(W32R, xI, fmaf(W32I, xR, GI));
            GR = t2;
        }
        const float pR = __shfl_up(GR, 16), pI = __shfl_up(GI, 16);
        float sR = (cg == 0) ? 0.0f : pR;
        float sI = (cg == 0) ? 0.0f : pI;
        // step 3: exclusive write + advance (each element owned by this lane)
#pragma unroll
        for (int i = 0; i < 16; ++i) {
            const int c = c0 + i;
            _Float16* qR = (_Float16*)(sm + uRo + c * 136 + ncol * 2);
            _Float16* qI = (_Float16*)(sm + uIo + c * 136 + ncol * 2);
            const float uRv = (float)*qR;
            const float uIv = (float)*qI;
            *qR = (_Float16)sR;
            *qI = (_Float16)sI;
            const float nR = fmaf(swR, sR, fmaf(-swI, sI, uRv));
            sI = fmaf(swR, sI, fmaf(swI, sR, uIv));
            sR = nR;
        }
    }
    __syncthreads();  // S visible

    // ---- phase 3: acc += SR@PR^T + SI@PIneg^T (rotated unit index) ----
    __builtin_amdgcn_s_setprio(1);
#pragma unroll
    for (int kh2 = 0; kh2 < 2; ++kh2) {
        const int kk = kh2 * 32;
        const int ubase = ((kk + qd * 8) + wb * 16) & 63;   // rotation = 16*wb
        const f16x8 as = ufrag(sm, uRo + (band + col) * 136 + ubase * 2);
#pragma unroll
        for (int tt = 0; tt < 4; ++tt)
            acc[tt] = __builtin_amdgcn_mfma_f32_16x16x32_f16(
                as, MFRAG(MPR, tt * 16, kk), acc[tt], 0, 0, 0);
    }
#pragma unroll
    for (int kh2 = 0; kh2 < 2; ++kh2) {
        const int kk = kh2 * 32;
        const int ubase = ((kk + qd * 8) + wb * 16) & 63;
        const f16x8 az = ufrag(sm, uIo + (band + col) * 136 + ubase * 2);
#pragma unroll
        for (int tt = 0; tt < 4; ++tt)
            acc[tt] = __builtin_amdgcn_mfma_f32_16x16x32_f16(
                az, MFRAG(MPI, tt * 16, kk), acc[tt], 0, 0, 0);
    }
    __builtin_amdgcn_s_setprio(0);

    // ---- epilogue via LDS bounce (wave-local; reuses own S slice):
    // f32 staging rows 0..7 in S_R slice, rows 8..15 in S_I slice,
    // stride 272B; then two coalesced f16x8 stores per lane into the
    // l-tiled rt layout [B][L/32][H][32]. ----
#pragma unroll
    for (int tt = 0; tt < 4; ++tt)
#pragma unroll
        for (int rg = 0; rg < 4; ++rg) {
            const int row = qd * 4 + rg;
            const int base = (row < 8) ? uRo + band * 136 + row * 272
                                       : uIo + band * 136 + (row - 8) * 272;
            *(float*)(sm + base + (tt * 16 + col) * 4) = acc[tt][rg];
        }
#pragma unroll
    for (int h2 = 0; h2 < 2; ++h2) {
        const int row = h2 * 8 + (lane >> 3);
        const int tau0 = (lane & 7) * 8;
        const int base = (row < 8) ? uRo + band * 136 + row * 272
                                   : uIo + band * 136 + (row - 8) * 272;
        const float4 y0 = *(const float4*)(sm + base + tau0 * 4);
        const float4 y1 = *(const float4*)(sm + base + tau0 * 4 + 16);
        const f16x8 xv = xep[h2];
        f16x8 o;
        o[0] = (_Float16)fmaf((float)xv[0], Dp1, y0.x);
        o[1] = (_Float16)fmaf((float)xv[1], Dp1, y0.y);
        o[2] = (_Float16)fmaf((float)xv[2], Dp1, y0.z);
        o[3] = (_Float16)fmaf((float)xv[3], Dp1, y0.w);
        o[4] = (_Float16)fmaf((float)xv[4], Dp1, y1.x);
        o[5] = (_Float16)fmaf((float)xv[5], Dp1, y1.y);
        o[6] = (_Float16)fmaf((float)xv[6], Dp1, y1.z);
        o[7] = (_Float16)fmaf((float)xv[7], Dp1, y1.w);
        // l = (band+row)*64 + tau0 -> lt = c*2 + (tau0>>5), li = tau0&31
        const int c = band + row;
        const int lt2 = c * 2 + (tau0 >> 5);
        const int li = tau0 & 31;
        *(f16x8*)(rt + (((size_t)b * 128 + lt2) * 1024 + h) * 32 + li) = o;
    }
}

// ---------------------------------------------------------------------------
// K3: LayerNorm + transpose back from l-tiled rt [B][L/32][H][32] f16.
// Pass 1: fully-coalesced reads (1KB contiguous per wave), stage LDS tile
// [l][h] + 8 per-l register sums, shfl_xor(4..32) reduce. Pass 2: f16x4 LDS
// reads along h, normalize, 256B-contiguous float4 writes. 2 blocks/CU.
// ---------------------------------------------------------------------------
#define HPAD 1032
__global__ __launch_bounds__(512, 2) void k_ln(const _Float16* __restrict__ rt,
                                               float* __restrict__ out,
                                               const float* __restrict__ lnw,
                                               const float* __restrict__ lnb) {
    __shared__ _Float16 tile[32 * HPAD];          // [l][h], 66048B
    __shared__ float ps[8][32], pq[8][32];
    __shared__ float mm[32], rs[32];
    const int b  = blockIdx.y;
    const int lt = blockIdx.x;                    // 32-l tile index
    const int tid = threadIdx.x;
    const int lane = tid & 63, wvv = tid >> 6;
    const int oct = tid & 3;                      // li-octet: li = oct*8..+7
    const int hloc = tid >> 2;                    // 0..127

    const _Float16* base = rt + ((size_t)b * 128 + lt) * 1024 * 32;

    float s[8] = {}, q[8] = {};
#pragma unroll
    for (int p = 0; p < 8; ++p) {
        const int h = p * 128 + hloc;
        const f16x8 v = *(const f16x8*)(base + h * 32 + oct * 8);
#pragma unroll
        for (int j = 0; j < 8; ++j) {
            const float f = (float)v[j];
            tile[(oct * 8 + j) * HPAD + h] = v[j];
            s[j] += f;
            q[j] = fmaf(f, f, q[j]);
        }
    }
    // reduce across lanes sharing oct (stride 4): d = 4,8,16,32
#pragma unroll
    for (int d = 4; d <= 32; d <<= 1) {
#pragma unroll
        for (int j = 0; j < 8; ++j) {
            s[j] += __shfl_xor(s[j], d);
            q[j] += __shfl_xor(q[j], d);
        }
    }
    if ((lane >> 2) == 0) {   // lanes 0..3, one per oct
#pragma unroll
        for (int j = 0; j < 8; ++j) {
            ps[wvv][oct * 8 + j] = s[j];
            pq[wvv][oct * 8 + j] = q[j];
        }
    }
    __syncthreads();
    if (tid < 32) {
        float ss = 0.f, qq = 0.f;
#pragma unroll
        for (int w = 0; w < 8; ++w) { ss += ps[w][tid]; qq += pq[w][tid]; }
        const float mu  = ss * (1.0f / Hh);
        const float var = fmaf(-mu, mu, qq * (1.0f / Hh));
        mm[tid] = mu;
        rs[tid] = rsqrtf(var + LN_EPS);
    }
    __syncthreads();

    // pass 2: thread t -> l = t>>4 (0..31), hq0 = t&15
    const int l = tid >> 4, hq0 = tid & 15;
    const float mu = mm[l], rsg = rs[l];
    float* obase = out + ((size_t)(b * Lseq + lt * 32 + l)) * Hh;
#pragma unroll
    for (int p = 0; p < 16; ++p) {
        const int hh = (p * 16 + hq0) * 4;
        const f16x4 v = *(const f16x4*)(&tile[l * HPAD + hh]);
        const float4 w4 = *(const float4*)(lnw + hh);
        const float4 b4 = *(const float4*)(lnb + hh);
        float4 o;
        o.x = fmaf(((float)v[0] - mu) * rsg, w4.x, b4.x);
        o.y = fmaf(((float)v[1] - mu) * rsg, w4.y, b4.y);
        o.z = fmaf(((float)v[2] - mu) * rsg, w4.z, b4.z);
        o.w = fmaf(((float)v[3] - mu) * rsg, w4.w, b4.w);
        *(float4*)(obase + hh) = o;
    }
}

// ---------------------------------------------------------------------------
extern "C" void kernel_launch(void* const* d_in, const int* in_sizes, int n_in,
                              void* d_out, int out_size, void* d_ws, size_t ws_size,
                              hipStream_t stream) {
    const float* x     = (const float*)d_in[0];
    const float* logA  = (const float*)d_in[1];
    const float* Aim   = (const float*)d_in[2];
    const float* Cre   = (const float*)d_in[3];
    const float* Cim   = (const float*)d_in[4];
    const float* logdt = (const float*)d_in[5];
    const float* Dp    = (const float*)d_in[6];
    const float* lnw   = (const float*)d_in[7];
    const float* lnb   = (const float*)d_in[8];
    float* out = (float*)d_out;

    _Float16* xt = (_Float16*)d_ws;                        // 32 MiB f16 [B,H,L]
    _Float16* rt = xt + (size_t)Bb * Hh * Lseq;            // 32 MiB f16 tiled

    _Float16* mats = (_Float16*)d_out;                     // 16 MiB (P only)
    char* tb = (char*)d_out + 16777216;
    float* wwR  = (float*)(tb);                            // 256 KiB each
    float* wwI  = (float*)(tb + 262144);
    float* w1R  = (float*)(tb + 2 * 262144);
    float* w1I  = (float*)(tb + 3 * 262144);
    float* ktab = (float*)(tb + 4 * 262144);

    // precompute blocks (0..1023) overlap transpose blocks (1024..5119)
    k_pre_trans<<<dim3(Hh + (Hh / 64) * (Lseq / 64) * Bb), 256, 0, stream>>>(
        x, xt, logA, Aim, Cre, Cim, logdt, mats, wwR, wwI, w1R, w1I, ktab);
    k_chunk<<<dim3(2, Hh), 512, 0, stream>>>(xt, rt, mats, wwR, wwI,
                                             w1R, w1I, ktab, Dp);
    k_ln<<<dim3(Lseq / 32, Bb), 512, 0, stream>>>(rt, out, lnw, lnb);
}

// Round 12
// 181.187 us; speedup vs baseline: 1.2816x; 1.0006x over previous
//
#include <hip/hip_runtime.h>
#include <cstdint>

#define Bb 4
#define Lseq 4096
#define Hh 1024
#define Nst 64
constexpr float LN_EPS = 1e-5f;

typedef _Float16 f16x8 __attribute__((ext_vector_type(8)));
typedef _Float16 f16x4 __attribute__((ext_vector_type(4)));
typedef float f32x4v __attribute__((ext_vector_type(4)));

typedef const __attribute__((address_space(1))) void* gas_vp;
typedef __attribute__((address_space(3))) void* las_vp;

// XOR-swizzle within a 64x64 f16 matrix: elem e=(row*64+col) stored at
// e ^ ((row&7)<<3). P written pre-swizzled by k_pre (identity global->LDS
// staging); U/M1 generated in-kernel directly at swizzled offsets.
__device__ __forceinline__ int swz(int e) { return e ^ (((e >> 6) & 7) << 3); }

__device__ __forceinline__ void cmul(float& zR, float& zI, float bR, float bI) {
    const float tR = fmaf(zR, bR, -zI * bI);
    zI = fmaf(zR, bI, zI * bR);
    zR = tR;
}

// ---------------------------------------------------------------------------
// K0+K1 fused: precompute (blocks 0..1023) overlaps transpose (blocks 1024+).
// Precompute emits: P_re/P_imneg mats (16KB/h, pre-swizzled) + small tables
// (w1, w64, K[0..63] per h). P built via geometric recurrence in t (no
// per-element transcendentals), stored as 16B f16x8 writes. U and M1 are
// generated inside k_chunk.
// ---------------------------------------------------------------------------
__global__ __launch_bounds__(256) void k_pre_trans(
    const float* __restrict__ x, _Float16* __restrict__ xt,
    const float* __restrict__ logA, const float* __restrict__ Aim,
    const float* __restrict__ Cre, const float* __restrict__ Cim,
    const float* __restrict__ logdt, _Float16* __restrict__ mats,
    float* __restrict__ wwR, float* __restrict__ wwI,
    float* __restrict__ w1R, float* __restrict__ w1I,
    float* __restrict__ ktab) {
    __shared__ float tile[64 * 65];               // transpose OR P staging
    __shared__ float sdAr[64], sdAi[64], scR[64], scI[64];
    __shared__ float sw1R[64], sw1I[64];
    const int tid = threadIdx.x;

    if (blockIdx.x < Hh) {
        // ---------------- precompute path ----------------
        const int h = blockIdx.x;
        _Float16* g2 = mats + (size_t)h * 8192;   // P_re | P_imneg

        if (tid < 64) {
            const int n = tid, idx = h * 64 + n;
            const float ar = -__expf(logA[idx]), ai = Aim[idx];
            const float dt = __expf(logdt[h]);
            const float dAr = dt * ar, dAi = dt * ai;
            const float em = __expf(dAr);
            const float wr = em * __cosf(dAi), wi = em * __sinf(dAi);
            const float Er = wr - 1.0f, Ei = wi;
            const float cr = Cre[idx], ci = Cim[idx];
            const float nr = cr * Er - ci * Ei, ni = cr * Ei + ci * Er;
            const float invd = 1.0f / (ar * ar + ai * ai);
            const float CtR = (nr * ar + ni * ai) * invd;
            const float CtI = (ni * ar - nr * ai) * invd;
            sdAr[n] = dAr; sdAi[n] = dAi;
            scR[n] = 2.0f * CtR; scI[n] = 2.0f * CtI;
            sw1R[n] = wr; sw1I[n] = wi;
            w1R[idx] = wr;  w1I[idx] = wi;        // w = exp(dA)
            const float e64 = __expf(dAr * 64.0f), a64 = dAi * 64.0f;
            wwR[idx] = e64 * __cosf(a64);         // w^64 (scan weight)
            wwI[idx] = e64 * __sinf(a64);
        }
        __syncthreads();

        // K[tau] -> global ktab: tau = tid>>2, each of 4 lanes sums 16 n's,
        // then shfl_xor(1,2) reduce within the aligned 4-lane group.
        {
            const int tau = tid >> 2, ns0 = (tid & 3) * 16;
            const float ftau = (float)tau;
            float sum = 0.0f;
#pragma unroll
            for (int j = 0; j < 16; ++j) {
                const int n = ns0 + j;
                const float ee = __expf(sdAr[n] * ftau), ang = sdAi[n] * ftau;
                sum += ee * (scR[n] * __cosf(ang) - scI[n] * __sinf(ang));
            }
            sum += __shfl_xor(sum, 1);
            sum += __shfl_xor(sum, 2);
            if ((tid & 3) == 0) ktab[h * 64 + tau] = sum;
        }

        // ---- P phase A: geometric recurrence in t, into LDS staging ----
        // P[t][n] = Ct_n * w_n^(t+1). Octet o: n = o&63, t in [8k, 8k+8).
        _Float16* pst = (_Float16*)tile;          // [64t][64n] re | imneg
#pragma unroll
        for (int oo = 0; oo < 2; ++oo) {
            const int o = oo * 256 + tid;
            const int n = o & 63, k = o >> 6;
            const float wR = sw1R[n], wI = sw1I[n];
            const float w2R = fmaf(wR, wR, -wI * wI),     w2I = 2.0f * wR * wI;
            const float w4R = fmaf(w2R, w2R, -w2I * w2I), w4I = 2.0f * w2R * w2I;
            const float w8R = fmaf(w4R, w4R, -w4I * w4I), w8I = 2.0f * w4R * w4I;
            float zR = 1.0f, zI = 0.0f;           // w^(8k)
            if (k & 1) cmul(zR, zI, w8R, w8I);
            const float w16R = fmaf(w8R, w8R, -w8I * w8I),
                        w16I = 2.0f * w8R * w8I;
            if (k & 2) cmul(zR, zI, w16R, w16I);
            const float w32R = fmaf(w16R, w16R, -w16I * w16I),
                        w32I = 2.0f * w16R * w16I;
            if (k & 4) cmul(zR, zI, w32R, w32I);
            float pR = scR[n], pI = scI[n];       // Ct
            cmul(pR, pI, zR, zI);                 // Ct * w^(8k)
            cmul(pR, pI, wR, wI);                 // Ct * w^(8k+1)
#pragma unroll
            for (int j = 0; j < 8; ++j) {
                const int t = k * 8 + j;
                pst[t * 64 + n]        = (_Float16)pR;
                pst[4096 + t * 64 + n] = (_Float16)(-pI);
                cmul(pR, pI, wR, wI);
            }
        }
        __syncthreads();
        // ---- P phase B: vectorized swizzled stores (16B, contiguous) ----
#pragma unroll
        for (int oo = 0; oo < 2; ++oo) {
            const int o = oo * 256 + tid;         // row-octet index
            const int t = o >> 3, j8 = (o & 7) * 8;
            const int e = t * 64 + j8;
            const int es = e ^ ((t & 7) << 3);
            *(f16x8*)(g2 + es)        = *(const f16x8*)(pst + e);
            *(f16x8*)(g2 + 4096 + es) = *(const f16x8*)(pst + 4096 + e);
        }
    } else {
        // ---------------- transpose path (f32 in, f16 out) ----------------
        const int tb = blockIdx.x - Hh;
        const int h0 = (tb & 15) * 64;
        const int l0 = ((tb >> 4) & 63) * 64;
        const int b  = tb >> 10;
        const int c = tid & 15, r = tid >> 4;

        const float* src = x + ((size_t)(b * Lseq + l0 + r)) * Hh + h0 + 4 * c;
#pragma unroll
        for (int it = 0; it < 4; ++it) {
            const float4 v = *(const float4*)(src + (size_t)it * 16 * Hh);
            const int l = it * 16 + r;
            tile[(4 * c + 0) * 65 + l] = v.x;
            tile[(4 * c + 1) * 65 + l] = v.y;
            tile[(4 * c + 2) * 65 + l] = v.z;
            tile[(4 * c + 3) * 65 + l] = v.w;
        }
        __syncthreads();
        // store pass: 8 l-octets x 32 h-rows -> 2x 16B f16x8 stores/thread
        const int c8 = tid & 7, r32 = tid >> 3;
        _Float16* dst = xt + ((size_t)(b * Hh + h0 + r32)) * Lseq + l0 + 8 * c8;
#pragma unroll
        for (int it = 0; it < 2; ++it) {
            const float* trow = tile + (it * 32 + r32) * 65 + 8 * c8;
            f16x8 o;
#pragma unroll
            for (int j = 0; j < 8; ++j) o[j] = (_Float16)trow[j];
            *(f16x8*)(dst + (size_t)it * 32 * Lseq) = o;
        }
    }
}

// ---------------------------------------------------------------------------
// K2: chunked block-scan via MFMA. 512 threads / 2 batches per block,
// grid (2, Hh). R11 structure; ONLY change: LDS LIVENESS OVERLAP.
// U (16KB) + M1 (8KB) are dead after phase-1 MFMA reads; u/S is born then.
// u/S now lives AT OFFSET 0 (over U/M1), P moved to the tail. Max live =
// 51200B -> 3 blocks/CU (was 75776 -> 2). Costs one extra __syncthreads
// between phase-1 MFMAs and the u-writes (cross-wave: another wave may
// still be reading U/M1 fragments; syncthreads drains lgkmcnt first so all
// fragment reads complete before any clobber). Hoisted X@M1 MFMAs still
// drift past the barrier (results consumed only in the epilogue).
// ---------------------------------------------------------------------------
#define MR0 0        // U_re   f16 [64][64] stride 128B, XOR-swizzled (phase 1)
#define MI0 8192     // U_im   (phase 1)
#define MM1 16384    // M1     (phase 1)
#define USB 0        // u/S: 2 x { S_R [64][68], S_I [64][68] } stride 136B
                     //   overlaps U/M1 after the post-phase-1 barrier
#define MPR 34816    // P_re   (staged, disjoint)
#define MPI 43008    // P_im_neg

// row0 is a multiple of 16 at every use, so (row0+col)&7 == col&7
#define MFRAG(base, row0, kk) \
    (*(const f16x8*)(sm + (((base) + ((row0) + col) * 128 + ((kk) + qd * 8) * 2) ^ ((col & 7) << 4))))

static __device__ __forceinline__ f16x8 ufrag(const unsigned char* sm, int off) {
    union { f16x8 v; f16x4 h[2]; } u;
    u.h[0] = *(const f16x4*)(sm + off);      // 8B aligned
    u.h[1] = *(const f16x4*)(sm + off + 8);
    return u.v;
}

__global__ __launch_bounds__(512, 6) void k_chunk(
    const _Float16* __restrict__ xt, _Float16* __restrict__ rt,
    const _Float16* __restrict__ mats,
    const float* __restrict__ wwR, const float* __restrict__ wwI,
    const float* __restrict__ w1R, const float* __restrict__ w1I,
    const float* __restrict__ ktab, const float* __restrict__ Dp) {
    __shared__ __align__(16) unsigned char sm[51200];

    const int tid = threadIdx.x, lane = tid & 63, wv = tid >> 6;
    const int grp = wv >> 2;          // 0..1: which batch of this block's pair
    const int wb  = wv & 3;           // row-band wave 0..3
    const int h = blockIdx.y;
    const int b = blockIdx.x * 2 + grp;   // batch 0..3
    const _Float16* gp = mats + (size_t)h * 8192;   // P only
    const int col = lane & 15, qd = lane >> 4;
    const int band = wb * 16;
    const int uRo = USB + grp * 17408;
    const int uIo = uRo + 8704;

    // ---- async stage: 16KB P mats, identity global->LDS (pre-swizzled) ----
#pragma unroll
    for (int it = 0; it < 2; ++it) {
        const int chunk = it * 512 + tid;   // 16B units, 0..1023
        __builtin_amdgcn_global_load_lds(
            (gas_vp)((const uint4*)gp + chunk),
            (las_vp)(sm + MPR + chunk * 16), 16, 0, 0);
    }

    const float Dp1 = 1.0f + Dp[h];
    const _Float16* xr = xt + ((size_t)b * Hh + h) * Lseq;

    // ---- phase-1 fragment loads + epilogue x loads (latency under gen) ----
    f16x8 axk[2];
#pragma unroll
    for (int kh2 = 0; kh2 < 2; ++kh2)
        axk[kh2] = *(const f16x8*)(xr + (band + col) * 64 + kh2 * 32 + qd * 8);
    f16x8 xep[2];
#pragma unroll
    for (int h2 = 0; h2 < 2; ++h2)
        xep[h2] = *(const f16x8*)(xr + (band + h2 * 8 + (lane >> 3)) * 64 +
                                  (lane & 7) * 8);

    // scan weight ww = w^64 for this lane's n = band + (lane&15); all lanes
    const float swR = wwR[h * 64 + band + (lane & 15)];
    const float swI = wwI[h * 64 + band + (lane & 15)];

    // ---- generate U (w^p geometric rows) into swizzled LDS ----
    {
        const int n = tid >> 3, oct = tid & 7;
        const float wR = w1R[h * 64 + n], wI = w1I[h * 64 + n];
        const float w2R = fmaf(wR, wR, -wI * wI),     w2I = 2.0f * wR * wI;
        const float w4R = fmaf(w2R, w2R, -w2I * w2I), w4I = 2.0f * w2R * w2I;
        const float w8R = fmaf(w4R, w4R, -w4I * w4I), w8I = 2.0f * w4R * w4I;
        const int k = 7 - oct;                        // z = (w^8)^k
        float zR = 1.0f, zI = 0.0f;
        if (k & 1) cmul(zR, zI, w8R, w8I);
        const float w16R = fmaf(w8R, w8R, -w8I * w8I), w16I = 2.0f * w8R * w8I;
        if (k & 2) cmul(zR, zI, w16R, w16I);
        const float w32R = fmaf(w16R, w16R, -w16I * w16I),
                    w32I = 2.0f * w16R * w16I;
        if (k & 4) cmul(zR, zI, w32R, w32I);
        // octet elems: v[j] = w^(63-8*oct-j); j=7 -> z, then multiply up
        f16x8 ur, ui;
        ur[7] = (_Float16)zR; ui[7] = (_Float16)zI;
#pragma unroll
        for (int j = 6; j >= 0; --j) {
            cmul(zR, zI, wR, wI);
            ur[j] = (_Float16)zR; ui[j] = (_Float16)zI;
        }
        const int sb = n * 128 + ((oct ^ (n & 7)) << 4);
        *(f16x8*)(sm + MR0 + sb) = ur;
        *(f16x8*)(sm + MI0 + sb) = ui;
    }

    // ---- generate M1 (tril Toeplitz of K) into swizzled LDS ----
    {
        const int t = tid >> 3, oct = tid & 7;
        f16x8 m1;
#pragma unroll
        for (int i = 0; i < 8; ++i) {
            const int j = oct * 8 + i;
            float v = 0.0f;
            if (j <= t) v = ktab[h * 64 + (t - j)];
            m1[i] = (_Float16)v;
        }
        const int sb = t * 128 + ((oct ^ (t & 7)) << 4);
        *(f16x8*)(sm + MM1 + sb) = m1;
    }
    __syncthreads();  // U/M1 LDS + P staged (vmcnt drain) + x ready

    // ---- phase 1: u = X @ U^T (complex) + hoisted X@M1 ----
    f32x4v aR[4] = {}, aI[4] = {};
    f32x4v acc[4] = {};
    __builtin_amdgcn_s_setprio(1);
#pragma unroll
    for (int kh2 = 0; kh2 < 2; ++kh2) {
        const int kk = kh2 * 32;
#pragma unroll
        for (int nt = 0; nt < 4; ++nt) {
            aR[nt] = __builtin_amdgcn_mfma_f32_16x16x32_f16(
                axk[kh2], MFRAG(MR0, nt * 16, kk), aR[nt], 0, 0, 0);
            aI[nt] = __builtin_amdgcn_mfma_f32_16x16x32_f16(
                axk[kh2], MFRAG(MI0, nt * 16, kk), aI[nt], 0, 0, 0);
        }
    }
    // X@M1 hoisted: results not consumed until epilogue, so the matrix pipe
    // chews on it across the barriers + scan below
#pragma unroll
    for (int kh2 = 0; kh2 < 2; ++kh2) {
        const int kk = kh2 * 32;
#pragma unroll
        for (int tt = 0; tt < 4; ++tt)
            acc[tt] = __builtin_amdgcn_mfma_f32_16x16x32_f16(
                axk[kh2], MFRAG(MM1, tt * 16, kk), acc[tt], 0, 0, 0);
    }
    __builtin_amdgcn_s_setprio(0);
    __syncthreads();  // ALL waves' U/M1 fragment reads complete -> safe clobber

    // u write: column rotated by 16*wb (= 16*((cc>>4)&3), wave-uniform)
#pragma unroll
    for (int nt = 0; nt < 4; ++nt)
#pragma unroll
        for (int rg = 0; rg < 4; ++rg) {
            const int cc = band + qd * 4 + rg;
            const int ncol = ((nt * 16 + col) + wb * 16) & 63;
            *(_Float16*)(sm + uRo + cc * 136 + ncol * 2) = (_Float16)aR[nt][rg];
            *(_Float16*)(sm + uIo + cc * 136 + ncol * 2) = (_Float16)aI[nt][rg];
        }
    __syncthreads();  // u visible

    // ---- phase 2: 64-lane 3-step scan; lane owns (cg = lane>>4 chunk
    //      group, nn = lane&15 -> n = band+nn). Exclusive S in-place.
    //      Column rotation (16*cg) puts each cg group on its own 8-bank set.
    {
        const int nn = lane & 15, cg = lane >> 4;
        const int n = band + nn;
        const int ncol = (n + cg * 16) & 63;          // rotation for this cg
        const int c0 = cg * 16;
        // W16 = ww^16, W32 = ww^32 (4-5 squarings)
        const float W2R = fmaf(swR, swR, -swI * swI), W2I = 2.0f * swR * swI;
        const float W4R = fmaf(W2R, W2R, -W2I * W2I), W4I = 2.0f * W2R * W2I;
        const float W8R = fmaf(W4R, W4R, -W4I * W4I), W8I = 2.0f * W4R * W4I;
        const float W16R = fmaf(W8R, W8R, -W8I * W8I), W16I = 2.0f * W8R * W8I;
        const float W32R = fmaf(W16R, W16R, -W16I * W16I),
                    W32I = 2.0f * W16R * W16I;
        // step 1: group total (read-only)
        float tRv = 0.0f, tIv = 0.0f;
#pragma unroll
        for (int i = 0; i < 16; ++i) {
            const int c = c0 + i;
            const float uRv = (float)*(const _Float16*)(sm + uRo + c * 136 + ncol * 2);
            const float uIv = (float)*(const _Float16*)(sm + uIo + c * 136 + ncol * 2);
            const float nR = fmaf(swR, tRv, fmaf(-swI, tIv, uRv));
            tIv = fmaf(swR, tIv, fmaf(swI, tRv, uIv));
            tRv = nR;
        }
        // step 2: weighted KS across cg groups (within this wave)
        float GR = tRv, GI = tIv;
        float xR = __shfl_up(GR, 16), xI = __shfl_up(GI, 16);
        if (cg >= 1) {
            const float t2 = fmaf(W16R, xR, fmaf(-W16I, xI, GR));
            GI = fmaf(W16R, xI, fmaf(W16I, xR, GI));
            GR = t2;
        }
        xR = __shfl_up(GR, 32); xI = __shfl_up(GI, 32);
        if (cg >= 2) {
            const float t2 = fmaf(W32R, xR, fmaf(-W32I, xI, GR));
            GI = fmaf(W32R, xI, fmaf(W32I, xR, GI));
            GR = t2;
        }
        const float pR = __shfl_up(GR, 16), pI = __shfl_up(GI, 16);
        float sR = (cg == 0) ? 0.0f : pR;
        float sI = (cg == 0) ? 0.0f : pI;
        // step 3: exclusive write + advance (each element owned by this lane)
#pragma unroll
        for (int i = 0; i < 16; ++i) {
            const int c = c0 + i;
            _Float16* qR = (_Float16*)(sm + uRo + c * 136 + ncol * 2);
            _Float16* qI = (_Float16*)(sm + uIo + c * 136 + ncol * 2);
            const float uRv = (float)*qR;
            const float uIv = (float)*qI;
            *qR = (_Float16)sR;
            *qI = (_Float16)sI;
            const float nR = fmaf(swR, sR, fmaf(-swI, sI, uRv));
            sI = fmaf(swR, sI, fmaf(swI, sR, uIv));
            sR = nR;
        }
    }
    __syncthreads();  // S visible

    // ---- phase 3: acc += SR@PR^T + SI@PIneg^T (rotated unit index) ----
    __builtin_amdgcn_s_setprio(1);
#pragma unroll
    for (int kh2 = 0; kh2 < 2; ++kh2) {
        const int kk = kh2 * 32;
        const int ubase = ((kk + qd * 8) + wb * 16) & 63;   // rotation = 16*wb
        const f16x8 as = ufrag(sm, uRo + (band + col) * 136 + ubase * 2);
#pragma unroll
        for (int tt = 0; tt < 4; ++tt)
            acc[tt] = __builtin_amdgcn_mfma_f32_16x16x32_f16(
                as, MFRAG(MPR, tt * 16, kk), acc[tt], 0, 0, 0);
    }
#pragma unroll
    for (int kh2 = 0; kh2 < 2; ++kh2) {
        const int kk = kh2 * 32;
        const int ubase = ((kk + qd * 8) + wb * 16) & 63;
        const f16x8 az = ufrag(sm, uIo + (band + col) * 136 + ubase * 2);
#pragma unroll
        for (int tt = 0; tt < 4; ++tt)
            acc[tt] = __builtin_amdgcn_mfma_f32_16x16x32_f16(
                az, MFRAG(MPI, tt * 16, kk), acc[tt], 0, 0, 0);
    }
    __builtin_amdgcn_s_setprio(0);

    // ---- epilogue via LDS bounce (wave-local; reuses own S slice):
    // f32 staging rows 0..7 in S_R slice, rows 8..15 in S_I slice,
    // stride 272B; then two coalesced f16x8 stores per lane into the
    // l-tiled rt layout [B][L/32][H][32]. ----
#pragma unroll
    for (int tt = 0; tt < 4; ++tt)
#pragma unroll
        for (int rg = 0; rg < 4; ++rg) {
            const int row = qd * 4 + rg;
            const int base = (row < 8) ? uRo + band * 136 + row * 272
                                       : uIo + band * 136 + (row - 8) * 272;
            *(float*)(sm + base + (tt * 16 + col) * 4) = acc[tt][rg];
        }
#pragma unroll
    for (int h2 = 0; h2 < 2; ++h2) {
        const int row = h2 * 8 + (lane >> 3);
        const int tau0 = (lane & 7) * 8;
        const int base = (row < 8) ? uRo + band * 136 + row * 272
                                   : uIo + band * 136 + (row - 8) * 272;
        const float4 y0 = *(const float4*)(sm + base + tau0 * 4);
        const float4 y1 = *(const float4*)(sm + base + tau0 * 4 + 16);
        const f16x8 xv = xep[h2];
        f16x8 o;
        o[0] = (_Float16)fmaf((float)xv[0], Dp1, y0.x);
        o[1] = (_Float16)fmaf((float)xv[1], Dp1, y0.y);
        o[2] = (_Float16)fmaf((float)xv[2], Dp1, y0.z);
        o[3] = (_Float16)fmaf((float)xv[3], Dp1, y0.w);
        o[4] = (_Float16)fmaf((float)xv[4], Dp1, y1.x);
        o[5] = (_Float16)fmaf((float)xv[5], Dp1, y1.y);
        o[6] = (_Float16)fmaf((float)xv[6], Dp1, y1.z);
        o[7] = (_Float16)fmaf((float)xv[7], Dp1, y1.w);
        // l = (band+row)*64 + tau0 -> lt = c*2 + (tau0>>5), li = tau0&31
        const int c = band + row;
        const int lt2 = c * 2 + (tau0 >> 5);
        const int li = tau0 & 31;
        *(f16x8*)(rt + (((size_t)b * 128 + lt2) * 1024 + h) * 32 + li) = o;
    }
}

// ---------------------------------------------------------------------------
// K3: LayerNorm + transpose back from l-tiled rt [B][L/32][H][32] f16.
// Pass 1: fully-coalesced reads (1KB contiguous per wave), stage LDS tile
// [l][h] + 8 per-l register sums, shfl_xor(4..32) reduce. Pass 2: f16x4 LDS
// reads along h, normalize, 256B-contiguous float4 writes. 2 blocks/CU.
// ---------------------------------------------------------------------------
#define HPAD 1032
__global__ __launch_bounds__(512, 2) void k_ln(const _Float16* __restrict__ rt,
                                               float* __restrict__ out,
                                               const float* __restrict__ lnw,
                                               const float* __restrict__ lnb) {
    __shared__ _Float16 tile[32 * HPAD];          // [l][h], 66048B
    __shared__ float ps[8][32], pq[8][32];
    __shared__ float mm[32], rs[32];
    const int b  = blockIdx.y;
    const int lt = blockIdx.x;                    // 32-l tile index
    const int tid = threadIdx.x;
    const int lane = tid & 63, wvv = tid >> 6;
    const int oct = tid & 3;                      // li-octet: li = oct*8..+7
    const int hloc = tid >> 2;                    // 0..127

    const _Float16* base = rt + ((size_t)b * 128 + lt) * 1024 * 32;

    float s[8] = {}, q[8] = {};
#pragma unroll
    for (int p = 0; p < 8; ++p) {
        const int h = p * 128 + hloc;
        const f16x8 v = *(const f16x8*)(base + h * 32 + oct * 8);
#pragma unroll
        for (int j = 0; j < 8; ++j) {
            const float f = (float)v[j];
            tile[(oct * 8 + j) * HPAD + h] = v[j];
            s[j] += f;
            q[j] = fmaf(f, f, q[j]);
        }
    }
    // reduce across lanes sharing oct (stride 4): d = 4,8,16,32
#pragma unroll
    for (int d = 4; d <= 32; d <<= 1) {
#pragma unroll
        for (int j = 0; j < 8; ++j) {
            s[j] += __shfl_xor(s[j], d);
            q[j] += __shfl_xor(q[j], d);
        }
    }
    if ((lane >> 2) == 0) {   // lanes 0..3, one per oct
#pragma unroll
        for (int j = 0; j < 8; ++j) {
            ps[wvv][oct * 8 + j] = s[j];
            pq[wvv][oct * 8 + j] = q[j];
        }
    }
    __syncthreads();
    if (tid < 32) {
        float ss = 0.f, qq = 0.f;
#pragma unroll
        for (int w = 0; w < 8; ++w) { ss += ps[w][tid]; qq += pq[w][tid]; }
        const float mu  = ss * (1.0f / Hh);
        const float var = fmaf(-mu, mu, qq * (1.0f / Hh));
        mm[tid] = mu;
        rs[tid] = rsqrtf(var + LN_EPS);
    }
    __syncthreads();

    // pass 2: thread t -> l = t>>4 (0..31), hq0 = t&15
    const int l = tid >> 4, hq0 = tid & 15;
    const float mu = mm[l], rsg = rs[l];
    float* obase = out + ((size_t)(b * Lseq + lt * 32 + l)) * Hh;
#pragma unroll
    for (int p = 0; p < 16; ++p) {
        const int hh = (p * 16 + hq0) * 4;
        const f16x4 v = *(const f16x4*)(&tile[l * HPAD + hh]);
        const float4 w4 = *(const float4*)(lnw + hh);
        const float4 b4 = *(const float4*)(lnb + hh);
        float4 o;
        o.x = fmaf(((float)v[0] - mu) * rsg, w4.x, b4.x);
        o.y = fmaf(((float)v[1] - mu) * rsg, w4.y, b4.y);
        o.z = fmaf(((float)v[2] - mu) * rsg, w4.z, b4.z);
        o.w = fmaf(((float)v[3] - mu) * rsg, w4.w, b4.w);
        *(float4*)(obase + hh) = o;
    }
}

// ---------------------------------------------------------------------------
extern "C" void kernel_launch(void* const* d_in, const int* in_sizes, int n_in,
                              void* d_out, int out_size, void* d_ws, size_t ws_size,
                              hipStream_t stream) {
    const float* x     = (const float*)d_in[0];
    const float* logA  = (const float*)d_in[1];
    const float* Aim   = (const float*)d_in[2];
    const float* Cre   = (const float*)d_in[3];
    const float* Cim   = (const float*)d_in[4];
    const float* logdt = (const float*)d_in[5];
    const float* Dp    = (const float*)d_in[6];
    const float* lnw   = (const float*)d_in[7];
    const float* lnb   = (const float*)d_in[8];
    float* out = (float*)d_out;

    _Float16* xt = (_Float16*)d_ws;                        // 32 MiB f16 [B,H,L]
    _Float16* rt = xt + (size_t)Bb * Hh * Lseq;            // 32 MiB f16 tiled

    _Float16* mats = (_Float16*)d_out;                     // 16 MiB (P only)
    char* tb = (char*)d_out + 16777216;
    float* wwR  = (float*)(tb);                            // 256 KiB each
    float* wwI  = (float*)(tb + 262144);
    float* w1R  = (float*)(tb + 2 * 262144);
    float* w1I  = (float*)(tb + 3 * 262144);
    float* ktab = (float*)(tb + 4 * 262144);

    // precompute blocks (0..1023) overlap transpose blocks (1024..5119)
    k_pre_trans<<<dim3(Hh + (Hh / 64) * (Lseq / 64) * Bb), 256, 0, stream>>>(
        x, xt, logA, Aim, Cre, Cim, logdt, mats, wwR, wwI, w1R, w1I, ktab);
    k_chunk<<<dim3(2, Hh), 512, 0, stream>>>(xt, rt, mats, wwR, wwI,
                                             w1R, w1I, ktab, Dp);
    k_ln<<<dim3(Lseq / 32, Bb), 512, 0, stream>>>(rt, out, lnw, lnb);
}

// Round 13
// 178.962 us; speedup vs baseline: 1.2976x; 1.0124x over previous
//
#include <hip/hip_runtime.h>
#include <cstdint>

#define Bb 4
#define Lseq 4096
#define Hh 1024
#define Nst 64
constexpr float LN_EPS = 1e-5f;

typedef _Float16 f16x8 __attribute__((ext_vector_type(8)));
typedef _Float16 f16x4 __attribute__((ext_vector_type(4)));
typedef float f32x4v __attribute__((ext_vector_type(4)));

typedef const __attribute__((address_space(1))) void* gas_vp;
typedef __attribute__((address_space(3))) void* las_vp;

// XOR-swizzle within a 64x64 f16 matrix: elem e=(row*64+col) stored at
// e ^ ((row&7)<<3). P written pre-swizzled by k_pre (identity global->LDS
// staging); U/M1 generated in-kernel directly at swizzled offsets.
__device__ __forceinline__ int swz(int e) { return e ^ (((e >> 6) & 7) << 3); }

__device__ __forceinline__ void cmul(float& zR, float& zI, float bR, float bI) {
    const float tR = fmaf(zR, bR, -zI * bI);
    zI = fmaf(zR, bI, zI * bR);
    zR = tR;
}

// ---------------------------------------------------------------------------
// K0+K1 fused: precompute (blocks 0..1023) overlaps transpose (blocks 1024+).
// Precompute emits: P_re/P_imneg mats (16KB/h, pre-swizzled) + small tables
// (w1, w64, K[0..63] per h). P built via geometric recurrence in t (no
// per-element transcendentals), stored as 16B f16x8 writes. U and M1 are
// generated inside k_chunk.
// ---------------------------------------------------------------------------
__global__ __launch_bounds__(256) void k_pre_trans(
    const float* __restrict__ x, _Float16* __restrict__ xt,
    const float* __restrict__ logA, const float* __restrict__ Aim,
    const float* __restrict__ Cre, const float* __restrict__ Cim,
    const float* __restrict__ logdt, _Float16* __restrict__ mats,
    float* __restrict__ wwR, float* __restrict__ wwI,
    float* __restrict__ w1R, float* __restrict__ w1I,
    float* __restrict__ ktab) {
    __shared__ float tile[64 * 65];               // transpose OR P staging
    __shared__ float sdAr[64], sdAi[64], scR[64], scI[64];
    __shared__ float sw1R[64], sw1I[64];
    const int tid = threadIdx.x;

    if (blockIdx.x < Hh) {
        // ---------------- precompute path ----------------
        const int h = blockIdx.x;
        _Float16* g2 = mats + (size_t)h * 8192;   // P_re | P_imneg

        if (tid < 64) {
            const int n = tid, idx = h * 64 + n;
            const float ar = -__expf(logA[idx]), ai = Aim[idx];
            const float dt = __expf(logdt[h]);
            const float dAr = dt * ar, dAi = dt * ai;
            const float em = __expf(dAr);
            const float wr = em * __cosf(dAi), wi = em * __sinf(dAi);
            const float Er = wr - 1.0f, Ei = wi;
            const float cr = Cre[idx], ci = Cim[idx];
            const float nr = cr * Er - ci * Ei, ni = cr * Ei + ci * Er;
            const float invd = 1.0f / (ar * ar + ai * ai);
            const float CtR = (nr * ar + ni * ai) * invd;
            const float CtI = (ni * ar - nr * ai) * invd;
            sdAr[n] = dAr; sdAi[n] = dAi;
            scR[n] = 2.0f * CtR; scI[n] = 2.0f * CtI;
            sw1R[n] = wr; sw1I[n] = wi;
            w1R[idx] = wr;  w1I[idx] = wi;        // w = exp(dA)
            const float e64 = __expf(dAr * 64.0f), a64 = dAi * 64.0f;
            wwR[idx] = e64 * __cosf(a64);         // w^64 (scan weight)
            wwI[idx] = e64 * __sinf(a64);
        }
        __syncthreads();

        // K[tau] -> global ktab: tau = tid>>2, each of 4 lanes sums 16 n's,
        // then shfl_xor(1,2) reduce within the aligned 4-lane group.
        {
            const int tau = tid >> 2, ns0 = (tid & 3) * 16;
            const float ftau = (float)tau;
            float sum = 0.0f;
#pragma unroll
            for (int j = 0; j < 16; ++j) {
                const int n = ns0 + j;
                const float ee = __expf(sdAr[n] * ftau), ang = sdAi[n] * ftau;
                sum += ee * (scR[n] * __cosf(ang) - scI[n] * __sinf(ang));
            }
            sum += __shfl_xor(sum, 1);
            sum += __shfl_xor(sum, 2);
            if ((tid & 3) == 0) ktab[h * 64 + tau] = sum;
        }

        // ---- P phase A: geometric recurrence in t, into LDS staging ----
        // P[t][n] = Ct_n * w_n^(t+1). Octet o: n = o&63, t in [8k, 8k+8).
        _Float16* pst = (_Float16*)tile;          // [64t][64n] re | imneg
#pragma unroll
        for (int oo = 0; oo < 2; ++oo) {
            const int o = oo * 256 + tid;
            const int n = o & 63, k = o >> 6;
            const float wR = sw1R[n], wI = sw1I[n];
            const float w2R = fmaf(wR, wR, -wI * wI),     w2I = 2.0f * wR * wI;
            const float w4R = fmaf(w2R, w2R, -w2I * w2I), w4I = 2.0f * w2R * w2I;
            const float w8R = fmaf(w4R, w4R, -w4I * w4I), w8I = 2.0f * w4R * w4I;
            float zR = 1.0f, zI = 0.0f;           // w^(8k)
            if (k & 1) cmul(zR, zI, w8R, w8I);
            const float w16R = fmaf(w8R, w8R, -w8I * w8I),
                        w16I = 2.0f * w8R * w8I;
            if (k & 2) cmul(zR, zI, w16R, w16I);
            const float w32R = fmaf(w16R, w16R, -w16I * w16I),
                        w32I = 2.0f * w16R * w16I;
            if (k & 4) cmul(zR, zI, w32R, w32I);
            float pR = scR[n], pI = scI[n];       // Ct
            cmul(pR, pI, zR, zI);                 // Ct * w^(8k)
            cmul(pR, pI, wR, wI);                 // Ct * w^(8k+1)
#pragma unroll
            for (int j = 0; j < 8; ++j) {
                const int t = k * 8 + j;
                pst[t * 64 + n]        = (_Float16)pR;
                pst[4096 + t * 64 + n] = (_Float16)(-pI);
                cmul(pR, pI, wR, wI);
            }
        }
        __syncthreads();
        // ---- P phase B: vectorized swizzled stores (16B, contiguous) ----
#pragma unroll
        for (int oo = 0; oo < 2; ++oo) {
            const int o = oo * 256 + tid;         // row-octet index
            const int t = o >> 3, j8 = (o & 7) * 8;
            const int e = t * 64 + j8;
            const int es = e ^ ((t & 7) << 3);
            *(f16x8*)(g2 + es)        = *(const f16x8*)(pst + e);
            *(f16x8*)(g2 + 4096 + es) = *(const f16x8*)(pst + 4096 + e);
        }
    } else {
        // ---------------- transpose path (f32 in, f16 out) ----------------
        const int tb = blockIdx.x - Hh;
        const int h0 = (tb & 15) * 64;
        const int l0 = ((tb >> 4) & 63) * 64;
        const int b  = tb >> 10;
        const int c = tid & 15, r = tid >> 4;

        const float* src = x + ((size_t)(b * Lseq + l0 + r)) * Hh + h0 + 4 * c;
#pragma unroll
        for (int it = 0; it < 4; ++it) {
            const float4 v = *(const float4*)(src + (size_t)it * 16 * Hh);
            const int l = it * 16 + r;
            tile[(4 * c + 0) * 65 + l] = v.x;
            tile[(4 * c + 1) * 65 + l] = v.y;
            tile[(4 * c + 2) * 65 + l] = v.z;
            tile[(4 * c + 3) * 65 + l] = v.w;
        }
        __syncthreads();
        // store pass: 8 l-octets x 32 h-rows -> 2x 16B f16x8 stores/thread
        const int c8 = tid & 7, r32 = tid >> 3;
        _Float16* dst = xt + ((size_t)(b * Hh + h0 + r32)) * Lseq + l0 + 8 * c8;
#pragma unroll
        for (int it = 0; it < 2; ++it) {
            const float* trow = tile + (it * 32 + r32) * 65 + 8 * c8;
            f16x8 o;
#pragma unroll
            for (int j = 0; j < 8; ++j) o[j] = (_Float16)trow[j];
            *(f16x8*)(dst + (size_t)it * 32 * Lseq) = o;
        }
    }
}

// ---------------------------------------------------------------------------
// K2: chunked block-scan via MFMA. 512 threads / 2 batches per block,
// grid (2, Hh). R12 structure (LDS liveness overlap, 51200B -> 3 blocks/CU)
// with the SPILL FIXED: xep (epilogue x term, 8 VGPRs) is no longer
// preloaded in the prologue — its loads are issued after the S-barrier,
// hiding under phase-3's 32 MFMAs and occupying registers only during the
// low-pressure phase 3. Phase-1 peak live set now ~70 regs <= the 85-reg
// budget of __launch_bounds__(512,6) -> no scratch (R12: WRITE_SIZE +8MB).
// ---------------------------------------------------------------------------
#define MR0 0        // U_re   f16 [64][64] stride 128B, XOR-swizzled (phase 1)
#define MI0 8192     // U_im   (phase 1)
#define MM1 16384    // M1     (phase 1)
#define USB 0        // u/S: 2 x { S_R [64][68], S_I [64][68] } stride 136B
                     //   overlaps U/M1 after the post-phase-1 barrier
#define MPR 34816    // P_re   (staged, disjoint)
#define MPI 43008    // P_im_neg

// row0 is a multiple of 16 at every use, so (row0+col)&7 == col&7
#define MFRAG(base, row0, kk) \
    (*(const f16x8*)(sm + (((base) + ((row0) + col) * 128 + ((kk) + qd * 8) * 2) ^ ((col & 7) << 4))))

static __device__ __forceinline__ f16x8 ufrag(const unsigned char* sm, int off) {
    union { f16x8 v; f16x4 h[2]; } u;
    u.h[0] = *(const f16x4*)(sm + off);      // 8B aligned
    u.h[1] = *(const f16x4*)(sm + off + 8);
    return u.v;
}

__global__ __launch_bounds__(512, 6) void k_chunk(
    const _Float16* __restrict__ xt, _Float16* __restrict__ rt,
    const _Float16* __restrict__ mats,
    const float* __restrict__ wwR, const float* __restrict__ wwI,
    const float* __restrict__ w1R, const float* __restrict__ w1I,
    const float* __restrict__ ktab, const float* __restrict__ Dp) {
    __shared__ __align__(16) unsigned char sm[51200];

    const int tid = threadIdx.x, lane = tid & 63, wv = tid >> 6;
    const int grp = wv >> 2;          // 0..1: which batch of this block's pair
    const int wb  = wv & 3;           // row-band wave 0..3
    const int h = blockIdx.y;
    const int b = blockIdx.x * 2 + grp;   // batch 0..3
    const _Float16* gp = mats + (size_t)h * 8192;   // P only
    const int col = lane & 15, qd = lane >> 4;
    const int band = wb * 16;
    const int uRo = USB + grp * 17408;
    const int uIo = uRo + 8704;

    // ---- async stage: 16KB P mats, identity global->LDS (pre-swizzled) ----
#pragma unroll
    for (int it = 0; it < 2; ++it) {
        const int chunk = it * 512 + tid;   // 16B units, 0..1023
        __builtin_amdgcn_global_load_lds(
            (gas_vp)((const uint4*)gp + chunk),
            (las_vp)(sm + MPR + chunk * 16), 16, 0, 0);
    }

    const float Dp1 = 1.0f + Dp[h];
    const _Float16* xr = xt + ((size_t)b * Hh + h) * Lseq;

    // ---- phase-1 fragment loads (latency hides under U/M1 gen) ----
    f16x8 axk[2];
#pragma unroll
    for (int kh2 = 0; kh2 < 2; ++kh2)
        axk[kh2] = *(const f16x8*)(xr + (band + col) * 64 + kh2 * 32 + qd * 8);

    // scan weight ww = w^64 for this lane's n = band + (lane&15); all lanes
    const float swR = wwR[h * 64 + band + (lane & 15)];
    const float swI = wwI[h * 64 + band + (lane & 15)];

    // ---- generate U (w^p geometric rows) into swizzled LDS ----
    {
        const int n = tid >> 3, oct = tid & 7;
        const float wR = w1R[h * 64 + n], wI = w1I[h * 64 + n];
        const float w2R = fmaf(wR, wR, -wI * wI),     w2I = 2.0f * wR * wI;
        const float w4R = fmaf(w2R, w2R, -w2I * w2I), w4I = 2.0f * w2R * w2I;
        const float w8R = fmaf(w4R, w4R, -w4I * w4I), w8I = 2.0f * w4R * w4I;
        const int k = 7 - oct;                        // z = (w^8)^k
        float zR = 1.0f, zI = 0.0f;
        if (k & 1) cmul(zR, zI, w8R, w8I);
        const float w16R = fmaf(w8R, w8R, -w8I * w8I), w16I = 2.0f * w8R * w8I;
        if (k & 2) cmul(zR, zI, w16R, w16I);
        const float w32R = fmaf(w16R, w16R, -w16I * w16I),
                    w32I = 2.0f * w16R * w16I;
        if (k & 4) cmul(zR, zI, w32R, w32I);
        // octet elems: v[j] = w^(63-8*oct-j); j=7 -> z, then multiply up
        f16x8 ur, ui;
        ur[7] = (_Float16)zR; ui[7] = (_Float16)zI;
#pragma unroll
        for (int j = 6; j >= 0; --j) {
            cmul(zR, zI, wR, wI);
            ur[j] = (_Float16)zR; ui[j] = (_Float16)zI;
        }
        const int sb = n * 128 + ((oct ^ (n & 7)) << 4);
        *(f16x8*)(sm + MR0 + sb) = ur;
        *(f16x8*)(sm + MI0 + sb) = ui;
    }

    // ---- generate M1 (tril Toeplitz of K) into swizzled LDS ----
    {
        const int t = tid >> 3, oct = tid & 7;
        f16x8 m1;
#pragma unroll
        for (int i = 0; i < 8; ++i) {
            const int j = oct * 8 + i;
            float v = 0.0f;
            if (j <= t) v = ktab[h * 64 + (t - j)];
            m1[i] = (_Float16)v;
        }
        const int sb = t * 128 + ((oct ^ (t & 7)) << 4);
        *(f16x8*)(sm + MM1 + sb) = m1;
    }
    __syncthreads();  // U/M1 LDS + P staged (vmcnt drain) + x ready

    // ---- phase 1: u = X @ U^T (complex) + hoisted X@M1 ----
    f32x4v aR[4] = {}, aI[4] = {};
    f32x4v acc[4] = {};
    __builtin_amdgcn_s_setprio(1);
#pragma unroll
    for (int kh2 = 0; kh2 < 2; ++kh2) {
        const int kk = kh2 * 32;
#pragma unroll
        for (int nt = 0; nt < 4; ++nt) {
            aR[nt] = __builtin_amdgcn_mfma_f32_16x16x32_f16(
                axk[kh2], MFRAG(MR0, nt * 16, kk), aR[nt], 0, 0, 0);
            aI[nt] = __builtin_amdgcn_mfma_f32_16x16x32_f16(
                axk[kh2], MFRAG(MI0, nt * 16, kk), aI[nt], 0, 0, 0);
        }
    }
    // X@M1 hoisted: results not consumed until epilogue, so the matrix pipe
    // chews on it across the barriers + scan below
#pragma unroll
    for (int kh2 = 0; kh2 < 2; ++kh2) {
        const int kk = kh2 * 32;
#pragma unroll
        for (int tt = 0; tt < 4; ++tt)
            acc[tt] = __builtin_amdgcn_mfma_f32_16x16x32_f16(
                axk[kh2], MFRAG(MM1, tt * 16, kk), acc[tt], 0, 0, 0);
    }
    __builtin_amdgcn_s_setprio(0);
    __syncthreads();  // ALL waves' U/M1 fragment reads complete -> safe clobber

    // u write: column rotated by 16*wb (= 16*((cc>>4)&3), wave-uniform)
#pragma unroll
    for (int nt = 0; nt < 4; ++nt)
#pragma unroll
        for (int rg = 0; rg < 4; ++rg) {
            const int cc = band + qd * 4 + rg;
            const int ncol = ((nt * 16 + col) + wb * 16) & 63;
            *(_Float16*)(sm + uRo + cc * 136 + ncol * 2) = (_Float16)aR[nt][rg];
            *(_Float16*)(sm + uIo + cc * 136 + ncol * 2) = (_Float16)aI[nt][rg];
        }
    __syncthreads();  // u visible

    // ---- phase 2: 64-lane 3-step scan; lane owns (cg = lane>>4 chunk
    //      group, nn = lane&15 -> n = band+nn). Exclusive S in-place.
    //      Column rotation (16*cg) puts each cg group on its own 8-bank set.
    {
        const int nn = lane & 15, cg = lane >> 4;
        const int n = band + nn;
        const int ncol = (n + cg * 16) & 63;          // rotation for this cg
        const int c0 = cg * 16;
        // W16 = ww^16, W32 = ww^32 (4-5 squarings)
        const float W2R = fmaf(swR, swR, -swI * swI), W2I = 2.0f * swR * swI;
        const float W4R = fmaf(W2R, W2R, -W2I * W2I), W4I = 2.0f * W2R * W2I;
        const float W8R = fmaf(W4R, W4R, -W4I * W4I), W8I = 2.0f * W4R * W4I;
        const float W16R = fmaf(W8R, W8R, -W8I * W8I), W16I = 2.0f * W8R * W8I;
        const float W32R = fmaf(W16R, W16R, -W16I * W16I),
                    W32I = 2.0f * W16R * W16I;
        // step 1: group total (read-only)
        float tRv = 0.0f, tIv = 0.0f;
#pragma unroll
        for (int i = 0; i < 16; ++i) {
            const int c = c0 + i;
            const float uRv = (float)*(const _Float16*)(sm + uRo + c * 136 + ncol * 2);
            const float uIv = (float)*(const _Float16*)(sm + uIo + c * 136 + ncol * 2);
            const float nR = fmaf(swR, tRv, fmaf(-swI, tIv, uRv));
            tIv = fmaf(swR, tIv, fmaf(swI, tRv, uIv));
            tRv = nR;
        }
        // step 2: weighted KS across cg groups (within this wave)
        float GR = tRv, GI = tIv;
        float xR = __shfl_up(GR, 16), xI = __shfl_up(GI, 16);
        if (cg >= 1) {
            const float t2 = fmaf(W16R, xR, fmaf(-W16I, xI, GR));
            GI = fmaf(W16R, xI, fmaf(W16I, xR, GI));
            GR = t2;
        }
        xR = __shfl_up(GR, 32); xI = __shfl_up(GI, 32);
        if (cg >= 2) {
            const float t2 = fmaf(W32R, xR, fmaf(-W32I, xI, GR));
            GI = fmaf(W32R, xI, fmaf(W32I, xR, GI));
            GR = t2;
        }
        const float pR = __shfl_up(GR, 16), pI = __shfl_up(GI, 16);
        float sR = (cg == 0) ? 0.0f : pR;
        float sI = (cg == 0) ? 0.0f : pI;
        // step 3: exclusive write + advance (each element owned by this lane)
#pragma unroll
        for (int i = 0; i < 16; ++i) {
            const int c = c0 + i;
            _Float16* qR = (_Float16*)(sm + uRo + c * 136 + ncol * 2);
            _Float16* qI = (_Float16*)(sm + uIo + c * 136 + ncol * 2);
            const float uRv = (float)*qR;
            const float uIv = (float)*qI;
            *qR = (_Float16)sR;
            *qI = (_Float16)sI;
            const float nR = fmaf(swR, sR, fmaf(-swI, sI, uRv));
            sI = fmaf(swR, sI, fmaf(swI, sR, uIv));
            sR = nR;
        }
    }
    __syncthreads();  // S visible

    // ---- epilogue x loads issued HERE: latency hides under phase-3 MFMAs,
    //      registers live only during low-pressure phase 3 ----
    f16x8 xep[2];
#pragma unroll
    for (int h2 = 0; h2 < 2; ++h2)
        xep[h2] = *(const f16x8*)(xr + (band + h2 * 8 + (lane >> 3)) * 64 +
                                  (lane & 7) * 8);

    // ---- phase 3: acc += SR@PR^T + SI@PIneg^T (rotated unit index) ----
    __builtin_amdgcn_s_setprio(1);
#pragma unroll
    for (int kh2 = 0; kh2 < 2; ++kh2) {
        const int kk = kh2 * 32;
        const int ubase = ((kk + qd * 8) + wb * 16) & 63;   // rotation = 16*wb
        const f16x8 as = ufrag(sm, uRo + (band + col) * 136 + ubase * 2);
#pragma unroll
        for (int tt = 0; tt < 4; ++tt)
            acc[tt] = __builtin_amdgcn_mfma_f32_16x16x32_f16(
                as, MFRAG(MPR, tt * 16, kk), acc[tt], 0, 0, 0);
    }
#pragma unroll
    for (int kh2 = 0; kh2 < 2; ++kh2) {
        const int kk = kh2 * 32;
        const int ubase = ((kk + qd * 8) + wb * 16) & 63;
        const f16x8 az = ufrag(sm, uIo + (band + col) * 136 + ubase * 2);
#pragma unroll
        for (int tt = 0; tt < 4; ++tt)
            acc[tt] = __builtin_amdgcn_mfma_f32_16x16x32_f16(
                az, MFRAG(MPI, tt * 16, kk), acc[tt], 0, 0, 0);
    }
    __builtin_amdgcn_s_setprio(0);

    // ---- epilogue via LDS bounce (wave-local; reuses own S slice):
    // f32 staging rows 0..7 in S_R slice, rows 8..15 in S_I slice,
    // stride 272B; then two coalesced f16x8 stores per lane into the
    // l-tiled rt layout [B][L/32][H][32]. ----
#pragma unroll
    for (int tt = 0; tt < 4; ++tt)
#pragma unroll
        for (int rg = 0; rg < 4; ++rg) {
            const int row = qd * 4 + rg;
            const int base = (row < 8) ? uRo + band * 136 + row * 272
                                       : uIo + band * 136 + (row - 8) * 272;
            *(float*)(sm + base + (tt * 16 + col) * 4) = acc[tt][rg];
        }
#pragma unroll
    for (int h2 = 0; h2 < 2; ++h2) {
        const int row = h2 * 8 + (lane >> 3);
        const int tau0 = (lane & 7) * 8;
        const int base = (row < 8) ? uRo + band * 136 + row * 272
                                   : uIo + band * 136 + (row - 8) * 272;
        const float4 y0 = *(const float4*)(sm + base + tau0 * 4);
        const float4 y1 = *(const float4*)(sm + base + tau0 * 4 + 16);
        const f16x8 xv = xep[h2];
        f16x8 o;
        o[0] = (_Float16)fmaf((float)xv[0], Dp1, y0.x);
        o[1] = (_Float16)fmaf((float)xv[1], Dp1, y0.y);
        o[2] = (_Float16)fmaf((float)xv[2], Dp1, y0.z);
        o[3] = (_Float16)fmaf((float)xv[3], Dp1, y0.w);
        o[4] = (_Float16)fmaf((float)xv[4], Dp1, y1.x);
        o[5] = (_Float16)fmaf((float)xv[5], Dp1, y1.y);
        o[6] = (_Float16)fmaf((float)xv[6], Dp1, y1.z);
        o[7] = (_Float16)fmaf((float)xv[7], Dp1, y1.w);
        // l = (band+row)*64 + tau0 -> lt = c*2 + (tau0>>5), li = tau0&31
        const int c = band + row;
        const int lt2 = c * 2 + (tau0 >> 5);
        const int li = tau0 & 31;
        *(f16x8*)(rt + (((size_t)b * 128 + lt2) * 1024 + h) * 32 + li) = o;
    }
}

// ---------------------------------------------------------------------------
// K3: LayerNorm + transpose back from l-tiled rt [B][L/32][H][32] f16.
// Pass 1: fully-coalesced reads (1KB contiguous per wave), stage LDS tile
// [l][h] + 8 per-l register sums, shfl_xor(4..32) reduce. Pass 2: f16x4 LDS
// reads along h, normalize, 256B-contiguous float4 writes. 2 blocks/CU.
// ---------------------------------------------------------------------------
#define HPAD 1032
__global__ __launch_bounds__(512, 2) void k_ln(const _Float16* __restrict__ rt,
                                               float* __restrict__ out,
                                               const float* __restrict__ lnw,
                                               const float* __restrict__ lnb) {
    __shared__ _Float16 tile[32 * HPAD];          // [l][h], 66048B
    __shared__ float ps[8][32], pq[8][32];
    __shared__ float mm[32], rs[32];
    const int b  = blockIdx.y;
    const int lt = blockIdx.x;                    // 32-l tile index
    const int tid = threadIdx.x;
    const int lane = tid & 63, wvv = tid >> 6;
    const int oct = tid & 3;                      // li-octet: li = oct*8..+7
    const int hloc = tid >> 2;                    // 0..127

    const _Float16* base = rt + ((size_t)b * 128 + lt) * 1024 * 32;

    float s[8] = {}, q[8] = {};
#pragma unroll
    for (int p = 0; p < 8; ++p) {
        const int h = p * 128 + hloc;
        const f16x8 v = *(const f16x8*)(base + h * 32 + oct * 8);
#pragma unroll
        for (int j = 0; j < 8; ++j) {
            const float f = (float)v[j];
            tile[(oct * 8 + j) * HPAD + h] = v[j];
            s[j] += f;
            q[j] = fmaf(f, f, q[j]);
        }
    }
    // reduce across lanes sharing oct (stride 4): d = 4,8,16,32
#pragma unroll
    for (int d = 4; d <= 32; d <<= 1) {
#pragma unroll
        for (int j = 0; j < 8; ++j) {
            s[j] += __shfl_xor(s[j], d);
            q[j] += __shfl_xor(q[j], d);
        }
    }
    if ((lane >> 2) == 0) {   // lanes 0..3, one per oct
#pragma unroll
        for (int j = 0; j < 8; ++j) {
            ps[wvv][oct * 8 + j] = s[j];
            pq[wvv][oct * 8 + j] = q[j];
        }
    }
    __syncthreads();
    if (tid < 32) {
        float ss = 0.f, qq = 0.f;
#pragma unroll
        for (int w = 0; w < 8; ++w) { ss += ps[w][tid]; qq += pq[w][tid]; }
        const float mu  = ss * (1.0f / Hh);
        const float var = fmaf(-mu, mu, qq * (1.0f / Hh));
        mm[tid] = mu;
        rs[tid] = rsqrtf(var + LN_EPS);
    }
    __syncthreads();

    // pass 2: thread t -> l = t>>4 (0..31), hq0 = t&15
    const int l = tid >> 4, hq0 = tid & 15;
    const float mu = mm[l], rsg = rs[l];
    float* obase = out + ((size_t)(b * Lseq + lt * 32 + l)) * Hh;
#pragma unroll
    for (int p = 0; p < 16; ++p) {
        const int hh = (p * 16 + hq0) * 4;
        const f16x4 v = *(const f16x4*)(&tile[l * HPAD + hh]);
        const float4 w4 = *(const float4*)(lnw + hh);
        const float4 b4 = *(const float4*)(lnb + hh);
        float4 o;
        o.x = fmaf(((float)v[0] - mu) * rsg, w4.x, b4.x);
        o.y = fmaf(((float)v[1] - mu) * rsg, w4.y, b4.y);
        o.z = fmaf(((float)v[2] - mu) * rsg, w4.z, b4.z);
        o.w = fmaf(((float)v[3] - mu) * rsg, w4.w, b4.w);
        *(float4*)(obase + hh) = o;
    }
}

// ---------------------------------------------------------------------------
extern "C" void kernel_launch(void* const* d_in, const int* in_sizes, int n_in,
                              void* d_out, int out_size, void* d_ws, size_t ws_size,
                              hipStream_t stream) {
    const float* x     = (const float*)d_in[0];
    const float* logA  = (const float*)d_in[1];
    const float* Aim   = (const float*)d_in[2];
    const float* Cre   = (const float*)d_in[3];
    const float* Cim   = (const float*)d_in[4];
    const float* logdt = (const float*)d_in[5];
    const float* Dp    = (const float*)d_in[6];
    const float* lnw   = (const float*)d_in[7];
    const float* lnb   = (const float*)d_in[8];
    float* out = (float*)d_out;

    _Float16* xt = (_Float16*)d_ws;                        // 32 MiB f16 [B,H,L]
    _Float16* rt = xt + (size_t)Bb * Hh * Lseq;            // 32 MiB f16 tiled

    _Float16* mats = (_Float16*)d_out;                     // 16 MiB (P only)
    char* tb = (char*)d_out + 16777216;
    float* wwR  = (float*)(tb);                            // 256 KiB each
    float* wwI  = (float*)(tb + 262144);
    float* w1R  = (float*)(tb + 2 * 262144);
    float* w1I  = (float*)(tb + 3 * 262144);
    float* ktab = (float*)(tb + 4 * 262144);

    // precompute blocks (0..1023) overlap transpose blocks (1024..5119)
    k_pre_trans<<<dim3(Hh + (Hh / 64) * (Lseq / 64) * Bb), 256, 0, stream>>>(
        x, xt, logA, Aim, Cre, Cim, logdt, mats, wwR, wwI, w1R, w1I, ktab);
    k_chunk<<<dim3(2, Hh), 512, 0, stream>>>(xt, rt, mats, wwR, wwI,
                                             w1R, w1I, ktab, Dp);
    k_ln<<<dim3(Lseq / 32, Bb), 512, 0, stream>>>(rt, out, lnw, lnb);
}

// Round 14
// 178.296 us; speedup vs baseline: 1.3024x; 1.0037x over previous
//
#include <hip/hip_runtime.h>
#include <cstdint>

#define Bb 4
#define Lseq 4096
#define Hh 1024
#define Nst 64
constexpr float LN_EPS = 1e-5f;

typedef _Float16 f16x8 __attribute__((ext_vector_type(8)));
typedef _Float16 f16x4 __attribute__((ext_vector_type(4)));
typedef float f32x4v __attribute__((ext_vector_type(4)));

typedef const __attribute__((address_space(1))) void* gas_vp;
typedef __attribute__((address_space(3))) void* las_vp;

// XOR-swizzle within a 64x64 f16 matrix: elem e=(row*64+col) stored at
// e ^ ((row&7)<<3). P written pre-swizzled by k_pre (identity global->LDS
// staging); U/M1 generated in-kernel directly at swizzled offsets.
__device__ __forceinline__ int swz(int e) { return e ^ (((e >> 6) & 7) << 3); }

__device__ __forceinline__ void cmul(float& zR, float& zI, float bR, float bI) {
    const float tR = fmaf(zR, bR, -zI * bI);
    zI = fmaf(zR, bI, zI * bR);
    zR = tR;
}

// ---------------------------------------------------------------------------
// K0+K1 fused: precompute (blocks 0..1023) overlaps transpose (blocks 1024+).
// Precompute emits: P_re/P_imneg mats (16KB/h, pre-swizzled) + small tables
// (w1, w64, K[0..63] per h). P built via geometric recurrence in t (no
// per-element transcendentals), stored as 16B f16x8 writes. U and M1 are
// generated inside k_chunk.
// ---------------------------------------------------------------------------
__global__ __launch_bounds__(256) void k_pre_trans(
    const float* __restrict__ x, _Float16* __restrict__ xt,
    const float* __restrict__ logA, const float* __restrict__ Aim,
    const float* __restrict__ Cre, const float* __restrict__ Cim,
    const float* __restrict__ logdt, _Float16* __restrict__ mats,
    float* __restrict__ wwR, float* __restrict__ wwI,
    float* __restrict__ w1R, float* __restrict__ w1I,
    float* __restrict__ ktab) {
    __shared__ float tile[64 * 65];               // transpose OR P staging
    __shared__ float sdAr[64], sdAi[64], scR[64], scI[64];
    __shared__ float sw1R[64], sw1I[64];
    const int tid = threadIdx.x;

    if (blockIdx.x < Hh) {
        // ---------------- precompute path ----------------
        const int h = blockIdx.x;
        _Float16* g2 = mats + (size_t)h * 8192;   // P_re | P_imneg

        if (tid < 64) {
            const int n = tid, idx = h * 64 + n;
            const float ar = -__expf(logA[idx]), ai = Aim[idx];
            const float dt = __expf(logdt[h]);
            const float dAr = dt * ar, dAi = dt * ai;
            const float em = __expf(dAr);
            const float wr = em * __cosf(dAi), wi = em * __sinf(dAi);
            const float Er = wr - 1.0f, Ei = wi;
            const float cr = Cre[idx], ci = Cim[idx];
            const float nr = cr * Er - ci * Ei, ni = cr * Ei + ci * Er;
            const float invd = 1.0f / (ar * ar + ai * ai);
            const float CtR = (nr * ar + ni * ai) * invd;
            const float CtI = (ni * ar - nr * ai) * invd;
            sdAr[n] = dAr; sdAi[n] = dAi;
            scR[n] = 2.0f * CtR; scI[n] = 2.0f * CtI;
            sw1R[n] = wr; sw1I[n] = wi;
            w1R[idx] = wr;  w1I[idx] = wi;        // w = exp(dA)
            const float e64 = __expf(dAr * 64.0f), a64 = dAi * 64.0f;
            wwR[idx] = e64 * __cosf(a64);         // w^64 (scan weight)
            wwI[idx] = e64 * __sinf(a64);
        }
        __syncthreads();

        // K[tau] -> global ktab: tau = tid>>2, each of 4 lanes sums 16 n's,
        // then shfl_xor(1,2) reduce within the aligned 4-lane group.
        {
            const int tau = tid >> 2, ns0 = (tid & 3) * 16;
            const float ftau = (float)tau;
            float sum = 0.0f;
#pragma unroll
            for (int j = 0; j < 16; ++j) {
                const int n = ns0 + j;
                const float ee = __expf(sdAr[n] * ftau), ang = sdAi[n] * ftau;
                sum += ee * (scR[n] * __cosf(ang) - scI[n] * __sinf(ang));
            }
            sum += __shfl_xor(sum, 1);
            sum += __shfl_xor(sum, 2);
            if ((tid & 3) == 0) ktab[h * 64 + tau] = sum;
        }

        // ---- P phase A: geometric recurrence in t, into LDS staging ----
        // P[t][n] = Ct_n * w_n^(t+1). Octet o: n = o&63, t in [8k, 8k+8).
        _Float16* pst = (_Float16*)tile;          // [64t][64n] re | imneg
#pragma unroll
        for (int oo = 0; oo < 2; ++oo) {
            const int o = oo * 256 + tid;
            const int n = o & 63, k = o >> 6;
            const float wR = sw1R[n], wI = sw1I[n];
            const float w2R = fmaf(wR, wR, -wI * wI),     w2I = 2.0f * wR * wI;
            const float w4R = fmaf(w2R, w2R, -w2I * w2I), w4I = 2.0f * w2R * w2I;
            const float w8R = fmaf(w4R, w4R, -w4I * w4I), w8I = 2.0f * w4R * w4I;
            float zR = 1.0f, zI = 0.0f;           // w^(8k)
            if (k & 1) cmul(zR, zI, w8R, w8I);
            const float w16R = fmaf(w8R, w8R, -w8I * w8I),
                        w16I = 2.0f * w8R * w8I;
            if (k & 2) cmul(zR, zI, w16R, w16I);
            const float w32R = fmaf(w16R, w16R, -w16I * w16I),
                        w32I = 2.0f * w16R * w16I;
            if (k & 4) cmul(zR, zI, w32R, w32I);
            float pR = scR[n], pI = scI[n];       // Ct
            cmul(pR, pI, zR, zI);                 // Ct * w^(8k)
            cmul(pR, pI, wR, wI);                 // Ct * w^(8k+1)
#pragma unroll
            for (int j = 0; j < 8; ++j) {
                const int t = k * 8 + j;
                pst[t * 64 + n]        = (_Float16)pR;
                pst[4096 + t * 64 + n] = (_Float16)(-pI);
                cmul(pR, pI, wR, wI);
            }
        }
        __syncthreads();
        // ---- P phase B: vectorized swizzled stores (16B, contiguous) ----
#pragma unroll
        for (int oo = 0; oo < 2; ++oo) {
            const int o = oo * 256 + tid;         // row-octet index
            const int t = o >> 3, j8 = (o & 7) * 8;
            const int e = t * 64 + j8;
            const int es = e ^ ((t & 7) << 3);
            *(f16x8*)(g2 + es)        = *(const f16x8*)(pst + e);
            *(f16x8*)(g2 + 4096 + es) = *(const f16x8*)(pst + 4096 + e);
        }
    } else {
        // ---------------- transpose path (f32 in, f16 out) ----------------
        const int tb = blockIdx.x - Hh;
        const int h0 = (tb & 15) * 64;
        const int l0 = ((tb >> 4) & 63) * 64;
        const int b  = tb >> 10;
        const int c = tid & 15, r = tid >> 4;

        const float* src = x + ((size_t)(b * Lseq + l0 + r)) * Hh + h0 + 4 * c;
#pragma unroll
        for (int it = 0; it < 4; ++it) {
            const float4 v = *(const float4*)(src + (size_t)it * 16 * Hh);
            const int l = it * 16 + r;
            tile[(4 * c + 0) * 65 + l] = v.x;
            tile[(4 * c + 1) * 65 + l] = v.y;
            tile[(4 * c + 2) * 65 + l] = v.z;
            tile[(4 * c + 3) * 65 + l] = v.w;
        }
        __syncthreads();
        // store pass: 8 l-octets x 32 h-rows -> 2x 16B f16x8 stores/thread
        const int c8 = tid & 7, r32 = tid >> 3;
        _Float16* dst = xt + ((size_t)(b * Hh + h0 + r32)) * Lseq + l0 + 8 * c8;
#pragma unroll
        for (int it = 0; it < 2; ++it) {
            const float* trow = tile + (it * 32 + r32) * 65 + 8 * c8;
            f16x8 o;
#pragma unroll
            for (int j = 0; j < 8; ++j) o[j] = (_Float16)trow[j];
            *(f16x8*)(dst + (size_t)it * 32 * Lseq) = o;
        }
    }
}

// ---------------------------------------------------------------------------
// K2: chunked block-scan via MFMA. 512 threads / 2 batches per block,
// grid (2, Hh), 3 blocks/CU (51200B LDS overlay). R13 structure; ONLY
// change: the epilogue x-term comes FROM axk (already in registers) via a
// re-mapped epilogue assignment — lane (col,qd),kh2 writes exactly the
// (row = band+col, tau = kh2*32+qd*8+j) positions it loaded for phase 1.
// Deletes the xep global loads entirely (R13: their deferred re-read missed
// L2 and cost +12.7MB FETCH) and 8 live VGPRs.
// ---------------------------------------------------------------------------
#define MR0 0        // U_re   f16 [64][64] stride 128B, XOR-swizzled (phase 1)
#define MI0 8192     // U_im   (phase 1)
#define MM1 16384    // M1     (phase 1)
#define USB 0        // u/S: 2 x { S_R [64][68], S_I [64][68] } stride 136B
                     //   overlaps U/M1 after the post-phase-1 barrier
#define MPR 34816    // P_re   (staged, disjoint)
#define MPI 43008    // P_im_neg

// row0 is a multiple of 16 at every use, so (row0+col)&7 == col&7
#define MFRAG(base, row0, kk) \
    (*(const f16x8*)(sm + (((base) + ((row0) + col) * 128 + ((kk) + qd * 8) * 2) ^ ((col & 7) << 4))))

static __device__ __forceinline__ f16x8 ufrag(const unsigned char* sm, int off) {
    union { f16x8 v; f16x4 h[2]; } u;
    u.h[0] = *(const f16x4*)(sm + off);      // 8B aligned
    u.h[1] = *(const f16x4*)(sm + off + 8);
    return u.v;
}

__global__ __launch_bounds__(512, 6) void k_chunk(
    const _Float16* __restrict__ xt, _Float16* __restrict__ rt,
    const _Float16* __restrict__ mats,
    const float* __restrict__ wwR, const float* __restrict__ wwI,
    const float* __restrict__ w1R, const float* __restrict__ w1I,
    const float* __restrict__ ktab, const float* __restrict__ Dp) {
    __shared__ __align__(16) unsigned char sm[51200];

    const int tid = threadIdx.x, lane = tid & 63, wv = tid >> 6;
    const int grp = wv >> 2;          // 0..1: which batch of this block's pair
    const int wb  = wv & 3;           // row-band wave 0..3
    const int h = blockIdx.y;
    const int b = blockIdx.x * 2 + grp;   // batch 0..3
    const _Float16* gp = mats + (size_t)h * 8192;   // P only
    const int col = lane & 15, qd = lane >> 4;
    const int band = wb * 16;
    const int uRo = USB + grp * 17408;
    const int uIo = uRo + 8704;

    // ---- async stage: 16KB P mats, identity global->LDS (pre-swizzled) ----
#pragma unroll
    for (int it = 0; it < 2; ++it) {
        const int chunk = it * 512 + tid;   // 16B units, 0..1023
        __builtin_amdgcn_global_load_lds(
            (gas_vp)((const uint4*)gp + chunk),
            (las_vp)(sm + MPR + chunk * 16), 16, 0, 0);
    }

    const float Dp1 = 1.0f + Dp[h];
    const _Float16* xr = xt + ((size_t)b * Hh + h) * Lseq;

    // ---- phase-1 fragment loads (latency hides under U/M1 gen) ----
    f16x8 axk[2];
#pragma unroll
    for (int kh2 = 0; kh2 < 2; ++kh2)
        axk[kh2] = *(const f16x8*)(xr + (band + col) * 64 + kh2 * 32 + qd * 8);

    // scan weight ww = w^64 for this lane's n = band + (lane&15); all lanes
    const float swR = wwR[h * 64 + band + (lane & 15)];
    const float swI = wwI[h * 64 + band + (lane & 15)];

    // ---- generate U (w^p geometric rows) into swizzled LDS ----
    {
        const int n = tid >> 3, oct = tid & 7;
        const float wR = w1R[h * 64 + n], wI = w1I[h * 64 + n];
        const float w2R = fmaf(wR, wR, -wI * wI),     w2I = 2.0f * wR * wI;
        const float w4R = fmaf(w2R, w2R, -w2I * w2I), w4I = 2.0f * w2R * w2I;
        const float w8R = fmaf(w4R, w4R, -w4I * w4I), w8I = 2.0f * w4R * w4I;
        const int k = 7 - oct;                        // z = (w^8)^k
        float zR = 1.0f, zI = 0.0f;
        if (k & 1) cmul(zR, zI, w8R, w8I);
        const float w16R = fmaf(w8R, w8R, -w8I * w8I), w16I = 2.0f * w8R * w8I;
        if (k & 2) cmul(zR, zI, w16R, w16I);
        const float w32R = fmaf(w16R, w16R, -w16I * w16I),
                    w32I = 2.0f * w16R * w16I;
        if (k & 4) cmul(zR, zI, w32R, w32I);
        // octet elems: v[j] = w^(63-8*oct-j); j=7 -> z, then multiply up
        f16x8 ur, ui;
        ur[7] = (_Float16)zR; ui[7] = (_Float16)zI;
#pragma unroll
        for (int j = 6; j >= 0; --j) {
            cmul(zR, zI, wR, wI);
            ur[j] = (_Float16)zR; ui[j] = (_Float16)zI;
        }
        const int sb = n * 128 + ((oct ^ (n & 7)) << 4);
        *(f16x8*)(sm + MR0 + sb) = ur;
        *(f16x8*)(sm + MI0 + sb) = ui;
    }

    // ---- generate M1 (tril Toeplitz of K) into swizzled LDS ----
    {
        const int t = tid >> 3, oct = tid & 7;
        f16x8 m1;
#pragma unroll
        for (int i = 0; i < 8; ++i) {
            const int j = oct * 8 + i;
            float v = 0.0f;
            if (j <= t) v = ktab[h * 64 + (t - j)];
            m1[i] = (_Float16)v;
        }
        const int sb = t * 128 + ((oct ^ (t & 7)) << 4);
        *(f16x8*)(sm + MM1 + sb) = m1;
    }
    __syncthreads();  // U/M1 LDS + P staged (vmcnt drain) + x ready

    // ---- phase 1: u = X @ U^T (complex) + hoisted X@M1 ----
    f32x4v aR[4] = {}, aI[4] = {};
    f32x4v acc[4] = {};
    __builtin_amdgcn_s_setprio(1);
#pragma unroll
    for (int kh2 = 0; kh2 < 2; ++kh2) {
        const int kk = kh2 * 32;
#pragma unroll
        for (int nt = 0; nt < 4; ++nt) {
            aR[nt] = __builtin_amdgcn_mfma_f32_16x16x32_f16(
                axk[kh2], MFRAG(MR0, nt * 16, kk), aR[nt], 0, 0, 0);
            aI[nt] = __builtin_amdgcn_mfma_f32_16x16x32_f16(
                axk[kh2], MFRAG(MI0, nt * 16, kk), aI[nt], 0, 0, 0);
        }
    }
    // X@M1 hoisted: results not consumed until epilogue, so the matrix pipe
    // chews on it across the barriers + scan below
#pragma unroll
    for (int kh2 = 0; kh2 < 2; ++kh2) {
        const int kk = kh2 * 32;
#pragma unroll
        for (int tt = 0; tt < 4; ++tt)
            acc[tt] = __builtin_amdgcn_mfma_f32_16x16x32_f16(
                axk[kh2], MFRAG(MM1, tt * 16, kk), acc[tt], 0, 0, 0);
    }
    __builtin_amdgcn_s_setprio(0);
    __syncthreads();  // ALL waves' U/M1 fragment reads complete -> safe clobber

    // u write: column rotated by 16*wb (= 16*((cc>>4)&3), wave-uniform)
#pragma unroll
    for (int nt = 0; nt < 4; ++nt)
#pragma unroll
        for (int rg = 0; rg < 4; ++rg) {
            const int cc = band + qd * 4 + rg;
            const int ncol = ((nt * 16 + col) + wb * 16) & 63;
            *(_Float16*)(sm + uRo + cc * 136 + ncol * 2) = (_Float16)aR[nt][rg];
            *(_Float16*)(sm + uIo + cc * 136 + ncol * 2) = (_Float16)aI[nt][rg];
        }
    __syncthreads();  // u visible

    // ---- phase 2: 64-lane 3-step scan; lane owns (cg = lane>>4 chunk
    //      group, nn = lane&15 -> n = band+nn). Exclusive S in-place.
    //      Column rotation (16*cg) puts each cg group on its own 8-bank set.
    {
        const int nn = lane & 15, cg = lane >> 4;
        const int n = band + nn;
        const int ncol = (n + cg * 16) & 63;          // rotation for this cg
        const int c0 = cg * 16;
        // W16 = ww^16, W32 = ww^32 (4-5 squarings)
        const float W2R = fmaf(swR, swR, -swI * swI), W2I = 2.0f * swR * swI;
        const float W4R = fmaf(W2R, W2R, -W2I * W2I), W4I = 2.0f * W2R * W2I;
        const float W8R = fmaf(W4R, W4R, -W4I * W4I), W8I = 2.0f * W4R * W4I;
        const float W16R = fmaf(W8R, W8R, -W8I * W8I), W16I = 2.0f * W8R * W8I;
        const float W32R = fmaf(W16R, W16R, -W16I * W16I),
                    W32I = 2.0f * W16R * W16I;
        // step 1: group total (read-only)
        float tRv = 0.0f, tIv = 0.0f;
#pragma unroll
        for (int i = 0; i < 16; ++i) {
            const int c = c0 + i;
            const float uRv = (float)*(const _Float16*)(sm + uRo + c * 136 + ncol * 2);
            const float uIv = (float)*(const _Float16*)(sm + uIo + c * 136 + ncol * 2);
            const float nR = fmaf(swR, tRv, fmaf(-swI, tIv, uRv));
            tIv = fmaf(swR, tIv, fmaf(swI, tRv, uIv));
            tRv = nR;
        }
        // step 2: weighted KS across cg groups (within this wave)
        float GR = tRv, GI = tIv;
        float xR = __shfl_up(GR, 16), xI = __shfl_up(GI, 16);
        if (cg >= 1) {
            const float t2 = fmaf(W16R, xR, fmaf(-W16I, xI, GR));
            GI = fmaf(W16R, xI, fmaf(W16I, xR, GI));
            GR = t2;
        }
        xR = __shfl_up(GR, 32); xI = __shfl_up(GI, 32);
        if (cg >= 2) {
            const float t2 = fmaf(W32R, xR, fmaf(-W32I, xI, GR));
            GI = fmaf(W32R, xI, fmaf(W32I, xR, GI));
            GR = t2;
        }
        const float pR = __shfl_up(GR, 16), pI = __shfl_up(GI, 16);
        float sR = (cg == 0) ? 0.0f : pR;
        float sI = (cg == 0) ? 0.0f : pI;
        // step 3: exclusive write + advance (each element owned by this lane)
#pragma unroll
        for (int i = 0; i < 16; ++i) {
            const int c = c0 + i;
            _Float16* qR = (_Float16*)(sm + uRo + c * 136 + ncol * 2);
            _Float16* qI = (_Float16*)(sm + uIo + c * 136 + ncol * 2);
            const float uRv = (float)*qR;
            const float uIv = (float)*qI;
            *qR = (_Float16)sR;
            *qI = (_Float16)sI;
            const float nR = fmaf(swR, sR, fmaf(-swI, sI, uRv));
            sI = fmaf(swR, sI, fmaf(swI, sR, uIv));
            sR = nR;
        }
    }
    __syncthreads();  // S visible

    // ---- phase 3: acc += SR@PR^T + SI@PIneg^T (rotated unit index) ----
    __builtin_amdgcn_s_setprio(1);
#pragma unroll
    for (int kh2 = 0; kh2 < 2; ++kh2) {
        const int kk = kh2 * 32;
        const int ubase = ((kk + qd * 8) + wb * 16) & 63;   // rotation = 16*wb
        const f16x8 as = ufrag(sm, uRo + (band + col) * 136 + ubase * 2);
#pragma unroll
        for (int tt = 0; tt < 4; ++tt)
            acc[tt] = __builtin_amdgcn_mfma_f32_16x16x32_f16(
                as, MFRAG(MPR, tt * 16, kk), acc[tt], 0, 0, 0);
    }
#pragma unroll
    for (int kh2 = 0; kh2 < 2; ++kh2) {
        const int kk = kh2 * 32;
        const int ubase = ((kk + qd * 8) + wb * 16) & 63;
        const f16x8 az = ufrag(sm, uIo + (band + col) * 136 + ubase * 2);
#pragma unroll
        for (int tt = 0; tt < 4; ++tt)
            acc[tt] = __builtin_amdgcn_mfma_f32_16x16x32_f16(
                az, MFRAG(MPI, tt * 16, kk), acc[tt], 0, 0, 0);
    }
    __builtin_amdgcn_s_setprio(0);

    // ---- epilogue via LDS bounce (wave-local; reuses own S slice):
    // f32 staging rows 0..7 in S_R slice, rows 8..15 in S_I slice,
    // stride 272B. Read-back RE-MAPPED to the axk lane assignment:
    // lane (col,qd), kh2 reads row=col, taus kh2*32+qd*8..+7 — the exact
    // elements this lane holds in axk[kh2] — fusing r = x*(1+D) + y with
    // ZERO extra global reads. ----
#pragma unroll
    for (int tt = 0; tt < 4; ++tt)
#pragma unroll
        for (int rg = 0; rg < 4; ++rg) {
            const int row = qd * 4 + rg;
            const int base = (row < 8) ? uRo + band * 136 + row * 272
                                       : uIo + band * 136 + (row - 8) * 272;
            *(float*)(sm + base + (tt * 16 + col) * 4) = acc[tt][rg];
        }
#pragma unroll
    for (int kh2 = 0; kh2 < 2; ++kh2) {
        const int tau0 = kh2 * 32 + qd * 8;
        const int base = (col < 8) ? uRo + band * 136 + col * 272
                                   : uIo + band * 136 + (col - 8) * 272;
        const float4 y0 = *(const float4*)(sm + base + tau0 * 4);
        const float4 y1 = *(const float4*)(sm + base + tau0 * 4 + 16);
        const f16x8 xv = axk[kh2];
        f16x8 o;
        o[0] = (_Float16)fmaf((float)xv[0], Dp1, y0.x);
        o[1] = (_Float16)fmaf((float)xv[1], Dp1, y0.y);
        o[2] = (_Float16)fmaf((float)xv[2], Dp1, y0.z);
        o[3] = (_Float16)fmaf((float)xv[3], Dp1, y0.w);
        o[4] = (_Float16)fmaf((float)xv[4], Dp1, y1.x);
        o[5] = (_Float16)fmaf((float)xv[5], Dp1, y1.y);
        o[6] = (_Float16)fmaf((float)xv[6], Dp1, y1.z);
        o[7] = (_Float16)fmaf((float)xv[7], Dp1, y1.w);
        // l = (band+col)*64 + tau0 -> lt2 = (band+col)*2 + kh2, li = qd*8
        const int lt2 = (band + col) * 2 + kh2;
        const int li = qd * 8;
        *(f16x8*)(rt + (((size_t)b * 128 + lt2) * 1024 + h) * 32 + li) = o;
    }
}

// ---------------------------------------------------------------------------
// K3: LayerNorm + transpose back from l-tiled rt [B][L/32][H][32] f16.
// Pass 1: fully-coalesced reads (1KB contiguous per wave), stage LDS tile
// [l][h] + 8 per-l register sums, shfl_xor(4..32) reduce. Pass 2: f16x4 LDS
// reads along h, normalize, 256B-contiguous float4 writes. 2 blocks/CU.
// ---------------------------------------------------------------------------
#define HPAD 1032
__global__ __launch_bounds__(512, 2) void k_ln(const _Float16* __restrict__ rt,
                                               float* __restrict__ out,
                                               const float* __restrict__ lnw,
                                               const float* __restrict__ lnb) {
    __shared__ _Float16 tile[32 * HPAD];          // [l][h], 66048B
    __shared__ float ps[8][32], pq[8][32];
    __shared__ float mm[32], rs[32];
    const int b  = blockIdx.y;
    const int lt = blockIdx.x;                    // 32-l tile index
    const int tid = threadIdx.x;
    const int lane = tid & 63, wvv = tid >> 6;
    const int oct = tid & 3;                      // li-octet: li = oct*8..+7
    const int hloc = tid >> 2;                    // 0..127

    const _Float16* base = rt + ((size_t)b * 128 + lt) * 1024 * 32;

    float s[8] = {}, q[8] = {};
#pragma unroll
    for (int p = 0; p < 8; ++p) {
        const int h = p * 128 + hloc;
        const f16x8 v = *(const f16x8*)(base + h * 32 + oct * 8);
#pragma unroll
        for (int j = 0; j < 8; ++j) {
            const float f = (float)v[j];
            tile[(oct * 8 + j) * HPAD + h] = v[j];
            s[j] += f;
            q[j] = fmaf(f, f, q[j]);
        }
    }
    // reduce across lanes sharing oct (stride 4): d = 4,8,16,32
#pragma unroll
    for (int d = 4; d <= 32; d <<= 1) {
#pragma unroll
        for (int j = 0; j < 8; ++j) {
            s[j] += __shfl_xor(s[j], d);
            q[j] += __shfl_xor(q[j], d);
        }
    }
    if ((lane >> 2) == 0) {   // lanes 0..3, one per oct
#pragma unroll
        for (int j = 0; j < 8; ++j) {
            ps[wvv][oct * 8 + j] = s[j];
            pq[wvv][oct * 8 + j] = q[j];
        }
    }
    __syncthreads();
    if (tid < 32) {
        float ss = 0.f, qq = 0.f;
#pragma unroll
        for (int w = 0; w < 8; ++w) { ss += ps[w][tid]; qq += pq[w][tid]; }
        const float mu  = ss * (1.0f / Hh);
        const float var = fmaf(-mu, mu, qq * (1.0f / Hh));
        mm[tid] = mu;
        rs[tid] = rsqrtf(var + LN_EPS);
    }
    __syncthreads();

    // pass 2: thread t -> l = t>>4 (0..31), hq0 = t&15
    const int l = tid >> 4, hq0 = tid & 15;
    const float mu = mm[l], rsg = rs[l];
    float* obase = out + ((size_t)(b * Lseq + lt * 32 + l)) * Hh;
#pragma unroll
    for (int p = 0; p < 16; ++p) {
        const int hh = (p * 16 + hq0) * 4;
        const f16x4 v = *(const f16x4*)(&tile[l * HPAD + hh]);
        const float4 w4 = *(const float4*)(lnw + hh);
        const float4 b4 = *(const float4*)(lnb + hh);
        float4 o;
        o.x = fmaf(((float)v[0] - mu) * rsg, w4.x, b4.x);
        o.y = fmaf(((float)v[1] - mu) * rsg, w4.y, b4.y);
        o.z = fmaf(((float)v[2] - mu) * rsg, w4.z, b4.z);
        o.w = fmaf(((float)v[3] - mu) * rsg, w4.w, b4.w);
        *(float4*)(obase + hh) = o;
    }
}

// ---------------------------------------------------------------------------
extern "C" void kernel_launch(void* const* d_in, const int* in_sizes, int n_in,
                              void* d_out, int out_size, void* d_ws, size_t ws_size,
                              hipStream_t stream) {
    const float* x     = (const float*)d_in[0];
    const float* logA  = (const float*)d_in[1];
    const float* Aim   = (const float*)d_in[2];
    const float* Cre   = (const float*)d_in[3];
    const float* Cim   = (const float*)d_in[4];
    const float* logdt = (const float*)d_in[5];
    const float* Dp    = (const float*)d_in[6];
    const float* lnw   = (const float*)d_in[7];
    const float* lnb   = (const float*)d_in[8];
    float* out = (float*)d_out;

    _Float16* xt = (_Float16*)d_ws;                        // 32 MiB f16 [B,H,L]
    _Float16* rt = xt + (size_t)Bb * Hh * Lseq;            // 32 MiB f16 tiled

    _Float16* mats = (_Float16*)d_out;                     // 16 MiB (P only)
    char* tb = (char*)d_out + 16777216;
    float* wwR  = (float*)(tb);                            // 256 KiB each
    float* wwI  = (float*)(tb + 262144);
    float* w1R  = (float*)(tb + 2 * 262144);
    float* w1I  = (float*)(tb + 3 * 262144);
    float* ktab = (float*)(tb + 4 * 262144);

    // precompute blocks (0..1023) overlap transpose blocks (1024..5119)
    k_pre_trans<<<dim3(Hh + (Hh / 64) * (Lseq / 64) * Bb), 256, 0, stream>>>(
        x, xt, logA, Aim, Cre, Cim, logdt, mats, wwR, wwI, w1R, w1I, ktab);
    k_chunk<<<dim3(2, Hh), 512, 0, stream>>>(xt, rt, mats, wwR, wwI,
                                             w1R, w1I, ktab, Dp);
    k_ln<<<dim3(Lseq / 32, Bb), 512, 0, stream>>>(rt, out, lnw, lnb);
}

// Round 15
// 173.524 us; speedup vs baseline: 1.3382x; 1.0275x over previous
//
#include <hip/hip_runtime.h>
#include <cstdint>

#define Bb 4
#define Lseq 4096
#define Hh 1024
#define Nst 64
constexpr float LN_EPS = 1e-5f;

typedef _Float16 f16x8 __attribute__((ext_vector_type(8)));
typedef _Float16 f16x4 __attribute__((ext_vector_type(4)));
typedef float f32x4v __attribute__((ext_vector_type(4)));

// XOR-swizzle within a 64x64 f16 matrix: elem e=(row*64+col) stored at
// e ^ ((row&7)<<3). ALL matrices (U, M1, P) are now generated in-kernel in
// k_chunk directly at swizzled LDS offsets — no global mats buffer at all.
__device__ __forceinline__ void cmul(float& zR, float& zI, float bR, float bI) {
    const float tR = fmaf(zR, bR, -zI * bI);
    zI = fmaf(zR, bI, zI * bR);
    zR = tR;
}

// ---------------------------------------------------------------------------
// K0+K1 fused: precompute (blocks 0..1023) overlaps transpose (blocks 1024+).
// Precompute now emits ONLY small tables: w1 = exp(dA), w64 (scan weight),
// Ct (cR/cI), K[0..63] per h. U, M1 AND P are generated inside k_chunk from
// these tables via geometric recurrences (no 16MB mats traffic).
// ---------------------------------------------------------------------------
__global__ __launch_bounds__(256) void k_pre_trans(
    const float* __restrict__ x, _Float16* __restrict__ xt,
    const float* __restrict__ logA, const float* __restrict__ Aim,
    const float* __restrict__ Cre, const float* __restrict__ Cim,
    const float* __restrict__ logdt,
    float* __restrict__ wwR, float* __restrict__ wwI,
    float* __restrict__ w1R, float* __restrict__ w1I,
    float* __restrict__ cRt, float* __restrict__ cIt,
    float* __restrict__ ktab) {
    __shared__ float tile[64 * 65];               // transpose path (16.6KB)
    __shared__ float sdAr[64], sdAi[64], scR[64], scI[64];
    const int tid = threadIdx.x;

    if (blockIdx.x < Hh) {
        // ---------------- precompute path (tables only) ----------------
        const int h = blockIdx.x;

        if (tid < 64) {
            const int n = tid, idx = h * 64 + n;
            const float ar = -__expf(logA[idx]), ai = Aim[idx];
            const float dt = __expf(logdt[h]);
            const float dAr = dt * ar, dAi = dt * ai;
            const float em = __expf(dAr);
            const float wr = em * __cosf(dAi), wi = em * __sinf(dAi);
            const float Er = wr - 1.0f, Ei = wi;
            const float cr = Cre[idx], ci = Cim[idx];
            const float nr = cr * Er - ci * Ei, ni = cr * Ei + ci * Er;
            const float invd = 1.0f / (ar * ar + ai * ai);
            const float CtR = (nr * ar + ni * ai) * invd;
            const float CtI = (ni * ar - nr * ai) * invd;
            sdAr[n] = dAr; sdAi[n] = dAi;
            scR[n] = 2.0f * CtR; scI[n] = 2.0f * CtI;
            w1R[idx] = wr;  w1I[idx] = wi;        // w = exp(dA)
            cRt[idx] = 2.0f * CtR; cIt[idx] = 2.0f * CtI;
            const float e64 = __expf(dAr * 64.0f), a64 = dAi * 64.0f;
            wwR[idx] = e64 * __cosf(a64);         // w^64 (scan weight)
            wwI[idx] = e64 * __sinf(a64);
        }
        __syncthreads();

        // K[tau] -> global ktab: tau = tid>>2, each of 4 lanes sums 16 n's,
        // then shfl_xor(1,2) reduce within the aligned 4-lane group.
        {
            const int tau = tid >> 2, ns0 = (tid & 3) * 16;
            const float ftau = (float)tau;
            float sum = 0.0f;
#pragma unroll
            for (int j = 0; j < 16; ++j) {
                const int n = ns0 + j;
                const float ee = __expf(sdAr[n] * ftau), ang = sdAi[n] * ftau;
                sum += ee * (scR[n] * __cosf(ang) - scI[n] * __sinf(ang));
            }
            sum += __shfl_xor(sum, 1);
            sum += __shfl_xor(sum, 2);
            if ((tid & 3) == 0) ktab[h * 64 + tau] = sum;
        }
    } else {
        // ---------------- transpose path (f32 in, f16 out) ----------------
        const int tb = blockIdx.x - Hh;
        const int h0 = (tb & 15) * 64;
        const int l0 = ((tb >> 4) & 63) * 64;
        const int b  = tb >> 10;
        const int c = tid & 15, r = tid >> 4;

        const float* src = x + ((size_t)(b * Lseq + l0 + r)) * Hh + h0 + 4 * c;
#pragma unroll
        for (int it = 0; it < 4; ++it) {
            const float4 v = *(const float4*)(src + (size_t)it * 16 * Hh);
            const int l = it * 16 + r;
            tile[(4 * c + 0) * 65 + l] = v.x;
            tile[(4 * c + 1) * 65 + l] = v.y;
            tile[(4 * c + 2) * 65 + l] = v.z;
            tile[(4 * c + 3) * 65 + l] = v.w;
        }
        __syncthreads();
        // store pass: 8 l-octets x 32 h-rows -> 2x 16B f16x8 stores/thread
        const int c8 = tid & 7, r32 = tid >> 3;
        _Float16* dst = xt + ((size_t)(b * Hh + h0 + r32)) * Lseq + l0 + 8 * c8;
#pragma unroll
        for (int it = 0; it < 2; ++it) {
            const float* trow = tile + (it * 32 + r32) * 65 + 8 * c8;
            f16x8 o;
#pragma unroll
            for (int j = 0; j < 8; ++j) o[j] = (_Float16)trow[j];
            *(f16x8*)(dst + (size_t)it * 32 * Lseq) = o;
        }
    }
}

// ---------------------------------------------------------------------------
// K2: chunked block-scan via MFMA. 512 threads / 2 batches per block,
// grid (2, Hh), 3 blocks/CU (51200B LDS overlay). R14 structure; ONLY
// change: P_re/P_imneg are GENERATED IN-KERNEL (geometric recurrence in t,
// same trick as U/M1) instead of staged from global. Deletes the 16MB mats
// buffer (pre's P gen + 16MB HBM writes + chunk's async stage + the vmcnt
// drain at the first barrier). P writes are 2B LDS stores at MFRAG-
// compatible swizzled offsets; per-step bank aliasing is 2-way (free).
// ---------------------------------------------------------------------------
#define MR0 0        // U_re   f16 [64][64] stride 128B, XOR-swizzled (phase 1)
#define MI0 8192     // U_im   (phase 1)
#define MM1 16384    // M1     (phase 1)
#define USB 0        // u/S: 2 x { S_R [64][68], S_I [64][68] } stride 136B
                     //   overlaps U/M1 after the post-phase-1 barrier
#define MPR 34816    // P_re   (generated, disjoint)
#define MPI 43008    // P_im_neg

// row0 is a multiple of 16 at every use, so (row0+col)&7 == col&7
#define MFRAG(base, row0, kk) \
    (*(const f16x8*)(sm + (((base) + ((row0) + col) * 128 + ((kk) + qd * 8) * 2) ^ ((col & 7) << 4))))

static __device__ __forceinline__ f16x8 ufrag(const unsigned char* sm, int off) {
    union { f16x8 v; f16x4 h[2]; } u;
    u.h[0] = *(const f16x4*)(sm + off);      // 8B aligned
    u.h[1] = *(const f16x4*)(sm + off + 8);
    return u.v;
}

__global__ __launch_bounds__(512, 6) void k_chunk(
    const _Float16* __restrict__ xt, _Float16* __restrict__ rt,
    const float* __restrict__ wwR, const float* __restrict__ wwI,
    const float* __restrict__ w1R, const float* __restrict__ w1I,
    const float* __restrict__ cRt, const float* __restrict__ cIt,
    const float* __restrict__ ktab, const float* __restrict__ Dp) {
    __shared__ __align__(16) unsigned char sm[51200];

    const int tid = threadIdx.x, lane = tid & 63, wv = tid >> 6;
    const int grp = wv >> 2;          // 0..1: which batch of this block's pair
    const int wb  = wv & 3;           // row-band wave 0..3
    const int h = blockIdx.y;
    const int b = blockIdx.x * 2 + grp;   // batch 0..3
    const int col = lane & 15, qd = lane >> 4;
    const int band = wb * 16;
    const int uRo = USB + grp * 17408;
    const int uIo = uRo + 8704;

    const float Dp1 = 1.0f + Dp[h];
    const _Float16* xr = xt + ((size_t)b * Hh + h) * Lseq;

    // ---- phase-1 fragment loads (latency hides under U/M1/P gen) ----
    f16x8 axk[2];
#pragma unroll
    for (int kh2 = 0; kh2 < 2; ++kh2)
        axk[kh2] = *(const f16x8*)(xr + (band + col) * 64 + kh2 * 32 + qd * 8);

    // scan weight ww = w^64 for this lane's n = band + (lane&15); all lanes
    const float swR = wwR[h * 64 + band + (lane & 15)];
    const float swI = wwI[h * 64 + band + (lane & 15)];

    // ---- generate U (w^p geometric rows) into swizzled LDS ----
    {
        const int n = tid >> 3, oct = tid & 7;
        const float wR = w1R[h * 64 + n], wI = w1I[h * 64 + n];
        const float w2R = fmaf(wR, wR, -wI * wI),     w2I = 2.0f * wR * wI;
        const float w4R = fmaf(w2R, w2R, -w2I * w2I), w4I = 2.0f * w2R * w2I;
        const float w8R = fmaf(w4R, w4R, -w4I * w4I), w8I = 2.0f * w4R * w4I;
        const int k = 7 - oct;                        // z = (w^8)^k
        float zR = 1.0f, zI = 0.0f;
        if (k & 1) cmul(zR, zI, w8R, w8I);
        const float w16R = fmaf(w8R, w8R, -w8I * w8I), w16I = 2.0f * w8R * w8I;
        if (k & 2) cmul(zR, zI, w16R, w16I);
        const float w32R = fmaf(w16R, w16R, -w16I * w16I),
                    w32I = 2.0f * w16R * w16I;
        if (k & 4) cmul(zR, zI, w32R, w32I);
        // octet elems: v[j] = w^(63-8*oct-j); j=7 -> z, then multiply up
        f16x8 ur, ui;
        ur[7] = (_Float16)zR; ui[7] = (_Float16)zI;
#pragma unroll
        for (int j = 6; j >= 0; --j) {
            cmul(zR, zI, wR, wI);
            ur[j] = (_Float16)zR; ui[j] = (_Float16)zI;
        }
        const int sb = n * 128 + ((oct ^ (n & 7)) << 4);
        *(f16x8*)(sm + MR0 + sb) = ur;
        *(f16x8*)(sm + MI0 + sb) = ui;
    }

    // ---- generate M1 (tril Toeplitz of K) into swizzled LDS ----
    {
        const int t = tid >> 3, oct = tid & 7;
        f16x8 m1;
#pragma unroll
        for (int i = 0; i < 8; ++i) {
            const int j = oct * 8 + i;
            float v = 0.0f;
            if (j <= t) v = ktab[h * 64 + (t - j)];
            m1[i] = (_Float16)v;
        }
        const int sb = t * 128 + ((oct ^ (t & 7)) << 4);
        *(f16x8*)(sm + MM1 + sb) = m1;
    }

    // ---- generate P (Ct * w^(t+1), geometric in t) into swizzled LDS ----
    // thread (n = tid&63, k = tid>>6) owns t in [8k, 8k+8). Byte offset
    // t*128 + (n*2 ^ ((t&7)<<4)) == pre-R15's swz layout (MFRAG-compatible).
    {
        const int n = tid & 63, k = tid >> 6;
        const float wR = w1R[h * 64 + n], wI = w1I[h * 64 + n];
        const float w2R = fmaf(wR, wR, -wI * wI),     w2I = 2.0f * wR * wI;
        const float w4R = fmaf(w2R, w2R, -w2I * w2I), w4I = 2.0f * w2R * w2I;
        const float w8R = fmaf(w4R, w4R, -w4I * w4I), w8I = 2.0f * w4R * w4I;
        float zR = 1.0f, zI = 0.0f;                   // w^(8k)
        if (k & 1) cmul(zR, zI, w8R, w8I);
        const float w16R = fmaf(w8R, w8R, -w8I * w8I), w16I = 2.0f * w8R * w8I;
        if (k & 2) cmul(zR, zI, w16R, w16I);
        const float w32R = fmaf(w16R, w16R, -w16I * w16I),
                    w32I = 2.0f * w16R * w16I;
        if (k & 4) cmul(zR, zI, w32R, w32I);
        float pR = cRt[h * 64 + n], pI = cIt[h * 64 + n];   // Ct
        cmul(pR, pI, zR, zI);                         // Ct * w^(8k)
        cmul(pR, pI, wR, wI);                         // Ct * w^(8k+1)
#pragma unroll
        for (int j = 0; j < 8; ++j) {
            const int t = k * 8 + j;
            const int off = t * 128 + ((n * 2) ^ (j << 4));
            *(_Float16*)(sm + MPR + off) = (_Float16)pR;
            *(_Float16*)(sm + MPI + off) = (_Float16)(-pI);
            cmul(pR, pI, wR, wI);
        }
    }
    __syncthreads();  // U/M1/P in LDS + x loads ready

    // ---- phase 1: u = X @ U^T (complex) + hoisted X@M1 ----
    f32x4v aR[4] = {}, aI[4] = {};
    f32x4v acc[4] = {};
    __builtin_amdgcn_s_setprio(1);
#pragma unroll
    for (int kh2 = 0; kh2 < 2; ++kh2) {
        const int kk = kh2 * 32;
#pragma unroll
        for (int nt = 0; nt < 4; ++nt) {
            aR[nt] = __builtin_amdgcn_mfma_f32_16x16x32_f16(
                axk[kh2], MFRAG(MR0, nt * 16, kk), aR[nt], 0, 0, 0);
            aI[nt] = __builtin_amdgcn_mfma_f32_16x16x32_f16(
                axk[kh2], MFRAG(MI0, nt * 16, kk), aI[nt], 0, 0, 0);
        }
    }
    // X@M1 hoisted: results not consumed until epilogue, so the matrix pipe
    // chews on it across the barriers + scan below
#pragma unroll
    for (int kh2 = 0; kh2 < 2; ++kh2) {
        const int kk = kh2 * 32;
#pragma unroll
        for (int tt = 0; tt < 4; ++tt)
            acc[tt] = __builtin_amdgcn_mfma_f32_16x16x32_f16(
                axk[kh2], MFRAG(MM1, tt * 16, kk), acc[tt], 0, 0, 0);
    }
    __builtin_amdgcn_s_setprio(0);
    __syncthreads();  // ALL waves' U/M1 fragment reads complete -> safe clobber

    // u write: column rotated by 16*wb (= 16*((cc>>4)&3), wave-uniform)
#pragma unroll
    for (int nt = 0; nt < 4; ++nt)
#pragma unroll
        for (int rg = 0; rg < 4; ++rg) {
            const int cc = band + qd * 4 + rg;
            const int ncol = ((nt * 16 + col) + wb * 16) & 63;
            *(_Float16*)(sm + uRo + cc * 136 + ncol * 2) = (_Float16)aR[nt][rg];
            *(_Float16*)(sm + uIo + cc * 136 + ncol * 2) = (_Float16)aI[nt][rg];
        }
    __syncthreads();  // u visible

    // ---- phase 2: 64-lane 3-step scan; lane owns (cg = lane>>4 chunk
    //      group, nn = lane&15 -> n = band+nn). Exclusive S in-place.
    //      Column rotation (16*cg) puts each cg group on its own 8-bank set.
    {
        const int nn = lane & 15, cg = lane >> 4;
        const int n = band + nn;
        const int ncol = (n + cg * 16) & 63;          // rotation for this cg
        const int c0 = cg * 16;
        // W16 = ww^16, W32 = ww^32 (4-5 squarings)
        const float W2R = fmaf(swR, swR, -swI * swI), W2I = 2.0f * swR * swI;
        const float W4R = fmaf(W2R, W2R, -W2I * W2I), W4I = 2.0f * W2R * W2I;
        const float W8R = fmaf(W4R, W4R, -W4I * W4I), W8I = 2.0f * W4R * W4I;
        const float W16R = fmaf(W8R, W8R, -W8I * W8I), W16I = 2.0f * W8R * W8I;
        const float W32R = fmaf(W16R, W16R, -W16I * W16I),
                    W32I = 2.0f * W16R * W16I;
        // step 1: group total (read-only)
        float tRv = 0.0f, tIv = 0.0f;
#pragma unroll
        for (int i = 0; i < 16; ++i) {
            const int c = c0 + i;
            const float uRv = (float)*(const _Float16*)(sm + uRo + c * 136 + ncol * 2);
            const float uIv = (float)*(const _Float16*)(sm + uIo + c * 136 + ncol * 2);
            const float nR = fmaf(swR, tRv, fmaf(-swI, tIv, uRv));
            tIv = fmaf(swR, tIv, fmaf(swI, tRv, uIv));
            tRv = nR;
        }
        // step 2: weighted KS across cg groups (within this wave)
        float GR = tRv, GI = tIv;
        float xR = __shfl_up(GR, 16), xI = __shfl_up(GI, 16);
        if (cg >= 1) {
            const float t2 = fmaf(W16R, xR, fmaf(-W16I, xI, GR));
            GI = fmaf(W16R, xI, fmaf(W16I, xR, GI));
            GR = t2;
        }
        xR = __shfl_up(GR, 32); xI = __shfl_up(GI, 32);
        if (cg >= 2) {
            const float t2 = fmaf(W32R, xR, fmaf(-W32I, xI, GR));
            GI = fmaf(W32R, xI, fmaf(W32I, xR, GI));
            GR = t2;
        }
        const float pR = __shfl_up(GR, 16), pI = __shfl_up(GI, 16);
        float sR = (cg == 0) ? 0.0f : pR;
        float sI = (cg == 0) ? 0.0f : pI;
        // step 3: exclusive write + advance (each element owned by this lane)
#pragma unroll
        for (int i = 0; i < 16; ++i) {
            const int c = c0 + i;
            _Float16* qR = (_Float16*)(sm + uRo + c * 136 + ncol * 2);
            _Float16* qI = (_Float16*)(sm + uIo + c * 136 + ncol * 2);
            const float uRv = (float)*qR;
            const float uIv = (float)*qI;
            *qR = (_Float16)sR;
            *qI = (_Float16)sI;
            const float nR = fmaf(swR, sR, fmaf(-swI, sI, uRv));
            sI = fmaf(swR, sI, fmaf(swI, sR, uIv));
            sR = nR;
        }
    }
    __syncthreads();  // S visible

    // ---- phase 3: acc += SR@PR^T + SI@PIneg^T (rotated unit index) ----
    __builtin_amdgcn_s_setprio(1);
#pragma unroll
    for (int kh2 = 0; kh2 < 2; ++kh2) {
        const int kk = kh2 * 32;
        const int ubase = ((kk + qd * 8) + wb * 16) & 63;   // rotation = 16*wb
        const f16x8 as = ufrag(sm, uRo + (band + col) * 136 + ubase * 2);
#pragma unroll
        for (int tt = 0; tt < 4; ++tt)
            acc[tt] = __builtin_amdgcn_mfma_f32_16x16x32_f16(
                as, MFRAG(MPR, tt * 16, kk), acc[tt], 0, 0, 0);
    }
#pragma unroll
    for (int kh2 = 0; kh2 < 2; ++kh2) {
        const int kk = kh2 * 32;
        const int ubase = ((kk + qd * 8) + wb * 16) & 63;
        const f16x8 az = ufrag(sm, uIo + (band + col) * 136 + ubase * 2);
#pragma unroll
        for (int tt = 0; tt < 4; ++tt)
            acc[tt] = __builtin_amdgcn_mfma_f32_16x16x32_f16(
                az, MFRAG(MPI, tt * 16, kk), acc[tt], 0, 0, 0);
    }
    __builtin_amdgcn_s_setprio(0);

    // ---- epilogue via LDS bounce (wave-local; reuses own S slice):
    // f32 staging rows 0..7 in S_R slice, rows 8..15 in S_I slice,
    // stride 272B. Read-back mapped to the axk lane assignment:
    // lane (col,qd), kh2 reads row=col, taus kh2*32+qd*8..+7 — the exact
    // elements this lane holds in axk[kh2] — fusing r = x*(1+D) + y with
    // ZERO extra global reads. ----
#pragma unroll
    for (int tt = 0; tt < 4; ++tt)
#pragma unroll
        for (int rg = 0; rg < 4; ++rg) {
            const int row = qd * 4 + rg;
            const int base = (row < 8) ? uRo + band * 136 + row * 272
                                       : uIo + band * 136 + (row - 8) * 272;
            *(float*)(sm + base + (tt * 16 + col) * 4) = acc[tt][rg];
        }
#pragma unroll
    for (int kh2 = 0; kh2 < 2; ++kh2) {
        const int tau0 = kh2 * 32 + qd * 8;
        const int base = (col < 8) ? uRo + band * 136 + col * 272
                                   : uIo + band * 136 + (col - 8) * 272;
        const float4 y0 = *(const float4*)(sm + base + tau0 * 4);
        const float4 y1 = *(const float4*)(sm + base + tau0 * 4 + 16);
        const f16x8 xv = axk[kh2];
        f16x8 o;
        o[0] = (_Float16)fmaf((float)xv[0], Dp1, y0.x);
        o[1] = (_Float16)fmaf((float)xv[1], Dp1, y0.y);
        o[2] = (_Float16)fmaf((float)xv[2], Dp1, y0.z);
        o[3] = (_Float16)fmaf((float)xv[3], Dp1, y0.w);
        o[4] = (_Float16)fmaf((float)xv[4], Dp1, y1.x);
        o[5] = (_Float16)fmaf((float)xv[5], Dp1, y1.y);
        o[6] = (_Float16)fmaf((float)xv[6], Dp1, y1.z);
        o[7] = (_Float16)fmaf((float)xv[7], Dp1, y1.w);
        // l = (band+col)*64 + tau0 -> lt2 = (band+col)*2 + kh2, li = qd*8
        const int lt2 = (band + col) * 2 + kh2;
        const int li = qd * 8;
        *(f16x8*)(rt + (((size_t)b * 128 + lt2) * 1024 + h) * 32 + li) = o;
    }
}

// ---------------------------------------------------------------------------
// K3: LayerNorm + transpose back from l-tiled rt [B][L/32][H][32] f16.
// Pass 1: fully-coalesced reads (1KB contiguous per wave), stage LDS tile
// [l][h] + 8 per-l register sums, shfl_xor(4..32) reduce. Pass 2: f16x4 LDS
// reads along h, normalize, 256B-contiguous float4 writes. 2 blocks/CU.
// ---------------------------------------------------------------------------
#define HPAD 1032
__global__ __launch_bounds__(512, 2) void k_ln(const _Float16* __restrict__ rt,
                                               float* __restrict__ out,
                                               const float* __restrict__ lnw,
                                               const float* __restrict__ lnb) {
    __shared__ _Float16 tile[32 * HPAD];          // [l][h], 66048B
    __shared__ float ps[8][32], pq[8][32];
    __shared__ float mm[32], rs[32];
    const int b  = blockIdx.y;
    const int lt = blockIdx.x;                    // 32-l tile index
    const int tid = threadIdx.x;
    const int lane = tid & 63, wvv = tid >> 6;
    const int oct = tid & 3;                      // li-octet: li = oct*8..+7
    const int hloc = tid >> 2;                    // 0..127

    const _Float16* base = rt + ((size_t)b * 128 + lt) * 1024 * 32;

    float s[8] = {}, q[8] = {};
#pragma unroll
    for (int p = 0; p < 8; ++p) {
        const int h = p * 128 + hloc;
        const f16x8 v = *(const f16x8*)(base + h * 32 + oct * 8);
#pragma unroll
        for (int j = 0; j < 8; ++j) {
            const float f = (float)v[j];
            tile[(oct * 8 + j) * HPAD + h] = v[j];
            s[j] += f;
            q[j] = fmaf(f, f, q[j]);
        }
    }
    // reduce across lanes sharing oct (stride 4): d = 4,8,16,32
#pragma unroll
    for (int d = 4; d <= 32; d <<= 1) {
#pragma unroll
        for (int j = 0; j < 8; ++j) {
            s[j] += __shfl_xor(s[j], d);
            q[j] += __shfl_xor(q[j], d);
        }
    }
    if ((lane >> 2) == 0) {   // lanes 0..3, one per oct
#pragma unroll
        for (int j = 0; j < 8; ++j) {
            ps[wvv][oct * 8 + j] = s[j];
            pq[wvv][oct * 8 + j] = q[j];
        }
    }
    __syncthreads();
    if (tid < 32) {
        float ss = 0.f, qq = 0.f;
#pragma unroll
        for (int w = 0; w < 8; ++w) { ss += ps[w][tid]; qq += pq[w][tid]; }
        const float mu  = ss * (1.0f / Hh);
        const float var = fmaf(-mu, mu, qq * (1.0f / Hh));
        mm[tid] = mu;
        rs[tid] = rsqrtf(var + LN_EPS);
    }
    __syncthreads();

    // pass 2: thread t -> l = t>>4 (0..31), hq0 = t&15
    const int l = tid >> 4, hq0 = tid & 15;
    const float mu = mm[l], rsg = rs[l];
    float* obase = out + ((size_t)(b * Lseq + lt * 32 + l)) * Hh;
#pragma unroll
    for (int p = 0; p < 16; ++p) {
        const int hh = (p * 16 + hq0) * 4;
        const f16x4 v = *(const f16x4*)(&tile[l * HPAD + hh]);
        const float4 w4 = *(const float4*)(lnw + hh);
        const float4 b4 = *(const float4*)(lnb + hh);
        float4 o;
        o.x = fmaf(((float)v[0] - mu) * rsg, w4.x, b4.x);
        o.y = fmaf(((float)v[1] - mu) * rsg, w4.y, b4.y);
        o.z = fmaf(((float)v[2] - mu) * rsg, w4.z, b4.z);
        o.w = fmaf(((float)v[3] - mu) * rsg, w4.w, b4.w);
        *(float4*)(obase + hh) = o;
    }
}

// ---------------------------------------------------------------------------
extern "C" void kernel_launch(void* const* d_in, const int* in_sizes, int n_in,
                              void* d_out, int out_size, void* d_ws, size_t ws_size,
                              hipStream_t stream) {
    const float* x     = (const float*)d_in[0];
    const float* logA  = (const float*)d_in[1];
    const float* Aim   = (const float*)d_in[2];
    const float* Cre   = (const float*)d_in[3];
    const float* Cim   = (const float*)d_in[4];
    const float* logdt = (const float*)d_in[5];
    const float* Dp    = (const float*)d_in[6];
    const float* lnw   = (const float*)d_in[7];
    const float* lnb   = (const float*)d_in[8];
    float* out = (float*)d_out;

    _Float16* xt = (_Float16*)d_ws;                        // 32 MiB f16 [B,H,L]
    _Float16* rt = xt + (size_t)Bb * Hh * Lseq;            // 32 MiB f16 tiled

    char* tb = (char*)d_out;                               // 7 x 256 KiB tables
    float* wwR  = (float*)(tb);
    float* wwI  = (float*)(tb + 262144);
    float* w1R  = (float*)(tb + 2 * 262144);
    float* w1I  = (float*)(tb + 3 * 262144);
    float* cRt  = (float*)(tb + 4 * 262144);
    float* cIt  = (float*)(tb + 5 * 262144);
    float* ktab = (float*)(tb + 6 * 262144);

    // precompute blocks (0..1023) overlap transpose blocks (1024..5119)
    k_pre_trans<<<dim3(Hh + (Hh / 64) * (Lseq / 64) * Bb), 256, 0, stream>>>(
        x, xt, logA, Aim, Cre, Cim, logdt, wwR, wwI, w1R, w1I, cRt, cIt, ktab);
    k_chunk<<<dim3(2, Hh), 512, 0, stream>>>(xt, rt, wwR, wwI,
                                             w1R, w1I, cRt, cIt, ktab, Dp);
    k_ln<<<dim3(Lseq / 32, Bb), 512, 0, stream>>>(rt, out, lnw, lnb);
}